// Round 2
// baseline (758.062 us; speedup 1.0000x reference)
//
#include <hip/hip_runtime.h>
#include <hip/hip_bf16.h>
#include <math.h>

// SS1D (Mamba-like selective scan), all-f32 baseline.
// B=8, L=2048, DM=192, DI=384, N=16, R=12. Rows = B*L = 16384.

#define ROWS 16384

// ---------------- K1: xz = silu(x @ W_in^T) -> u, z ----------------
// M=16384, N=768, K=192. BM=128, BN=128, BK=32. 8x8 micro-tile (2x2 float4 quadrants).
__global__ __launch_bounds__(256) void k1_gemm_silu(
    const float* __restrict__ x, const float* __restrict__ Win,
    float* __restrict__ u, float* __restrict__ z)
{
    __shared__ float As[32 * 132];
    __shared__ float Bs[32 * 132];
    const int tid = threadIdx.x;
    const int ty = tid >> 4, tx = tid & 15;
    const int bm = blockIdx.x * 128;
    const int bn = blockIdx.y * 128;

    float acc[2][2][4][4];
#pragma unroll
    for (int a = 0; a < 2; ++a)
#pragma unroll
        for (int b = 0; b < 2; ++b)
#pragma unroll
            for (int i = 0; i < 4; ++i)
#pragma unroll
                for (int j = 0; j < 4; ++j) acc[a][b][i][j] = 0.f;

    for (int k0 = 0; k0 < 192; k0 += 32) {
#pragma unroll
        for (int i = 0; i < 4; ++i) {
            int p = tid + i * 256;            // 0..1023
            int m = p >> 3;                   // 0..127
            int kk = (p & 7) * 4;             // 0..28
            float4 av = *(const float4*)(x + (size_t)(bm + m) * 192 + k0 + kk);
            As[(kk + 0) * 132 + m] = av.x;
            As[(kk + 1) * 132 + m] = av.y;
            As[(kk + 2) * 132 + m] = av.z;
            As[(kk + 3) * 132 + m] = av.w;
            float4 bv = *(const float4*)(Win + (size_t)(bn + m) * 192 + k0 + kk);
            Bs[(kk + 0) * 132 + m] = bv.x;
            Bs[(kk + 1) * 132 + m] = bv.y;
            Bs[(kk + 2) * 132 + m] = bv.z;
            Bs[(kk + 3) * 132 + m] = bv.w;
        }
        __syncthreads();
        const float4* As4 = (const float4*)As;
        const float4* Bs4 = (const float4*)Bs;
#pragma unroll
        for (int kk = 0; kk < 32; ++kk) {
            float4 a0 = As4[kk * 33 + ty];
            float4 a1 = As4[kk * 33 + 16 + ty];
            float4 b0 = Bs4[kk * 33 + tx];
            float4 b1 = Bs4[kk * 33 + 16 + tx];
            float ar[2][4] = {{a0.x, a0.y, a0.z, a0.w}, {a1.x, a1.y, a1.z, a1.w}};
            float br[2][4] = {{b0.x, b0.y, b0.z, b0.w}, {b1.x, b1.y, b1.z, b1.w}};
#pragma unroll
            for (int a = 0; a < 2; ++a)
#pragma unroll
                for (int i = 0; i < 4; ++i)
#pragma unroll
                    for (int b = 0; b < 2; ++b)
#pragma unroll
                        for (int j = 0; j < 4; ++j)
                            acc[a][b][i][j] = fmaf(ar[a][i], br[b][j], acc[a][b][i][j]);
        }
        __syncthreads();
    }
    // epilogue: silu then split into u / z
#pragma unroll
    for (int a = 0; a < 2; ++a)
#pragma unroll
        for (int i = 0; i < 4; ++i) {
            int row = bm + a * 64 + ty * 4 + i;
#pragma unroll
            for (int b = 0; b < 2; ++b) {
                int col = bn + b * 64 + tx * 4;
                float4 v;
                float* pv = &v.x;
#pragma unroll
                for (int j = 0; j < 4; ++j) {
                    float s = acc[a][b][i][j];
                    pv[j] = s / (1.f + __expf(-s));
                }
                if (col < 384) *(float4*)(u + (size_t)row * 384 + col) = v;
                else           *(float4*)(z + (size_t)row * 384 + (col - 384)) = v;
            }
        }
}

// ------- K2: dbl = u @ xpw^T (44 cols); delta = softplus(dbl[:,:12] @ dtw^T + b); B, C -------
__global__ __launch_bounds__(256) void k2_proj(
    const float* __restrict__ u, const float* __restrict__ xpw,
    const float* __restrict__ dtw, const float* __restrict__ dtb,
    float* __restrict__ delta, float* __restrict__ Bso, float* __restrict__ Cso)
{
    __shared__ float ut[16 * 388];
    __shared__ float dblS[16 * 48];
    const int tid = threadIdx.x;
    const int row0 = blockIdx.x * 16;

    // load 16x384 tile of u
#pragma unroll
    for (int i = 0; i < 6; ++i) {
        int p = tid + i * 256;      // 0..1535 float4s
        int r = p / 96, c4 = p % 96;
        float4 v = *(const float4*)(u + (size_t)(row0 + r) * 384 + c4 * 4);
        *(float4*)(ut + r * 388 + c4 * 4) = v;
    }
    __syncthreads();

    // phase A: 16 rows x 44 cols
    {
        const int r = tid >> 4, ci = tid & 15;
        const float4* u4 = (const float4*)(ut + r * 388);
        for (int pass = 0; pass < 3; ++pass) {
            int c = pass * 16 + ci;
            if (c < 44) {
                const float4* w4 = (const float4*)(xpw + (size_t)c * 384);
                float s = 0.f;
#pragma unroll 4
                for (int k4 = 0; k4 < 96; ++k4) {
                    float4 uv = u4[k4];
                    float4 wv = w4[k4];
                    s = fmaf(uv.x, wv.x, s);
                    s = fmaf(uv.y, wv.y, s);
                    s = fmaf(uv.z, wv.z, s);
                    s = fmaf(uv.w, wv.w, s);
                }
                dblS[r * 48 + c] = s;
                int row = row0 + r;
                if (c >= 28)      Cso[(size_t)row * 16 + (c - 28)] = s;
                else if (c >= 12) Bso[(size_t)row * 16 + (c - 12)] = s;
            }
        }
    }
    __syncthreads();

    // phase B: delta (16 x 384)
    for (int i = 0; i < 24; ++i) {
        int o = i * 256 + tid;        // 0..6143
        int r = o / 384, d = o - r * 384;
        const float* w = dtw + d * 12;
        const float* db = dblS + r * 48;
        float s = dtb[d];
#pragma unroll
        for (int j = 0; j < 12; ++j) s = fmaf(db[j], w[j], s);
        float sp = (s > 20.f) ? s : log1pf(__expf(s));
        delta[(size_t)(row0 + r) * 384 + d] = sp;
    }
}

// ---------------- K3: selective scan. dy holds delta on entry, y on exit ----------------
// block = 256 = 16 d-channels x 16 states. grid = (DI/16, B)
__global__ __launch_bounds__(256) void k3_scan(
    float* __restrict__ dy, const float* __restrict__ u,
    const float* Bsv, const float* Csv,
    const float* __restrict__ A_logs, const float* __restrict__ Ds)
{
    const int tid = threadIdx.x;
    const int n = tid & 15, dl = tid >> 4;
    const int d = blockIdx.x * 16 + dl;
    const int b = blockIdx.y;
    const float Acoef = -__expf(A_logs[d * 16 + n]);
    const float Dd = Ds[d];
    const float* dp = dy + (size_t)b * 2048 * 384 + d;
    const float* up = u + (size_t)b * 2048 * 384 + d;
    const float* Bp = Bsv + (size_t)b * 2048 * 16 + n;
    const float* Cp = Csv + (size_t)b * 2048 * 16 + n;
    float* yp = dy + (size_t)b * 2048 * 384 + d;

    float h = 0.f;
    float pdt[4], put[4], pB[4], pC[4];
#pragma unroll
    for (int i = 0; i < 4; ++i) {
        pdt[i] = dp[i * 384]; put[i] = up[i * 384];
        pB[i] = Bp[i * 16];   pC[i] = Cp[i * 16];
    }
    for (int t0 = 0; t0 < 2048; t0 += 4) {
        float cdt[4], cut[4], cB[4], cC[4];
#pragma unroll
        for (int i = 0; i < 4; ++i) { cdt[i] = pdt[i]; cut[i] = put[i]; cB[i] = pB[i]; cC[i] = pC[i]; }
        dp += 4 * 384; up += 4 * 384; Bp += 64; Cp += 64;
        if (t0 + 4 < 2048) {
#pragma unroll
            for (int i = 0; i < 4; ++i) {
                pdt[i] = dp[i * 384]; put[i] = up[i * 384];
                pB[i] = Bp[i * 16];   pC[i] = Cp[i * 16];
            }
        }
#pragma unroll
        for (int i = 0; i < 4; ++i) {
            float dt = cdt[i];
            float dA = __expf(dt * Acoef);
            float dbu = dt * cut[i] * cB[i];
            h = fmaf(dA, h, dbu);
            float p = h * cC[i];
            p += __shfl_xor(p, 1);
            p += __shfl_xor(p, 2);
            p += __shfl_xor(p, 4);
            p += __shfl_xor(p, 8);
            if (n == 0) yp[(size_t)(t0 + i) * 384] = fmaf(Dd, cut[i], p);
        }
    }
}

// ---------------- K4: LayerNorm over DI, then * z (in place on y) ----------------
__global__ __launch_bounds__(256) void k4_ln_mul(
    float* __restrict__ y, const float* __restrict__ z,
    const float* __restrict__ gamma, const float* __restrict__ beta)
{
    const int tid = threadIdx.x;
    const int lane = tid & 63;
    const int w = tid >> 6;
    const size_t row = (size_t)blockIdx.x * 4 + w;
    float* yr = y + row * 384;
    const float* zr = z + row * 384;
    float v[6];
    float s1 = 0.f, s2 = 0.f;
#pragma unroll
    for (int j = 0; j < 6; ++j) {
        v[j] = yr[lane + j * 64];
        s1 += v[j];
        s2 = fmaf(v[j], v[j], s2);
    }
#pragma unroll
    for (int off = 32; off > 0; off >>= 1) {
        s1 += __shfl_xor(s1, off);
        s2 += __shfl_xor(s2, off);
    }
    float mu = s1 * (1.f / 384.f);
    float var = s2 * (1.f / 384.f) - mu * mu;
    float rs = rsqrtf(var + 1e-5f);
#pragma unroll
    for (int j = 0; j < 6; ++j) {
        int d = lane + j * 64;
        float o = (v[j] - mu) * rs * gamma[d] + beta[d];
        yr[d] = o * zr[d];
    }
}

// ---------------- K5: out = yn @ W_out^T. M=16384, N=192, K=384 ----------------
// BM=64, BN=192, BK=32. micro: 4 rows x (3 x float4) cols.
__global__ __launch_bounds__(256) void k5_gemm_out(
    const float* __restrict__ yn, const float* __restrict__ Wout,
    float* __restrict__ out)
{
    __shared__ float As[32 * 68];
    __shared__ float Bs[32 * 196];
    const int tid = threadIdx.x;
    const int ty = tid >> 4, tx = tid & 15;
    const int bm = blockIdx.x * 64;

    float acc[3][4][4];
#pragma unroll
    for (int g = 0; g < 3; ++g)
#pragma unroll
        for (int i = 0; i < 4; ++i)
#pragma unroll
            for (int j = 0; j < 4; ++j) acc[g][i][j] = 0.f;

    for (int k0 = 0; k0 < 384; k0 += 32) {
#pragma unroll
        for (int i = 0; i < 2; ++i) {
            int p = tid + i * 256;     // 0..511
            int m = p >> 3, kk = (p & 7) * 4;
            float4 av = *(const float4*)(yn + (size_t)(bm + m) * 384 + k0 + kk);
            As[(kk + 0) * 68 + m] = av.x;
            As[(kk + 1) * 68 + m] = av.y;
            As[(kk + 2) * 68 + m] = av.z;
            As[(kk + 3) * 68 + m] = av.w;
        }
#pragma unroll
        for (int i = 0; i < 6; ++i) {
            int p = tid + i * 256;     // 0..1535
            int nn = p >> 3, kk = (p & 7) * 4;
            float4 bv = *(const float4*)(Wout + (size_t)nn * 384 + k0 + kk);
            Bs[(kk + 0) * 196 + nn] = bv.x;
            Bs[(kk + 1) * 196 + nn] = bv.y;
            Bs[(kk + 2) * 196 + nn] = bv.z;
            Bs[(kk + 3) * 196 + nn] = bv.w;
        }
        __syncthreads();
        const float4* As4 = (const float4*)As;
        const float4* Bs4 = (const float4*)Bs;
#pragma unroll
        for (int kk = 0; kk < 32; ++kk) {
            float4 a = As4[kk * 17 + ty];
            float ar[4] = {a.x, a.y, a.z, a.w};
#pragma unroll
            for (int g = 0; g < 3; ++g) {
                float4 bq = Bs4[kk * 49 + g * 16 + tx];
                float br[4] = {bq.x, bq.y, bq.z, bq.w};
#pragma unroll
                for (int i = 0; i < 4; ++i)
#pragma unroll
                    for (int j = 0; j < 4; ++j)
                        acc[g][i][j] = fmaf(ar[i], br[j], acc[g][i][j]);
            }
        }
        __syncthreads();
    }
#pragma unroll
    for (int i = 0; i < 4; ++i) {
        int row = bm + ty * 4 + i;
#pragma unroll
        for (int g = 0; g < 3; ++g) {
            float4 v = make_float4(acc[g][i][0], acc[g][i][1], acc[g][i][2], acc[g][i][3]);
            *(float4*)(out + (size_t)row * 192 + g * 64 + tx * 4) = v;
        }
    }
}

extern "C" void kernel_launch(void* const* d_in, const int* in_sizes, int n_in,
                              void* d_out, int out_size, void* d_ws, size_t ws_size,
                              hipStream_t stream) {
    const float* x    = (const float*)d_in[0];
    const float* Win  = (const float*)d_in[1];
    const float* xpw  = (const float*)d_in[2];
    const float* dtw  = (const float*)d_in[3];
    const float* dtb  = (const float*)d_in[4];
    const float* Alog = (const float*)d_in[5];
    const float* Dsv  = (const float*)d_in[6];
    const float* lng  = (const float*)d_in[7];
    const float* lnb  = (const float*)d_in[8];
    const float* Wout = (const float*)d_in[9];
    float* out = (float*)d_out;

    // workspace layout (floats): u, z, dl (delta->y->yn in place), Bsv, Csv
    const size_t need = ((size_t)ROWS * 384 * 3 + (size_t)ROWS * 16 * 2) * sizeof(float);
    if (ws_size < need) return;   // fail visibly (absmax) instead of faulting

    float* u   = (float*)d_ws;                       // 16384*384
    float* z   = u + (size_t)ROWS * 384;             // 16384*384
    float* dl  = z + (size_t)ROWS * 384;             // delta -> y -> yn (in place)
    float* Bsv = dl + (size_t)ROWS * 384;            // 16384*16
    float* Csv = Bsv + (size_t)ROWS * 16;            // 16384*16

    k1_gemm_silu<<<dim3(128, 6), 256, 0, stream>>>(x, Win, u, z);
    k2_proj<<<1024, 256, 0, stream>>>(u, xpw, dtw, dtb, dl, Bsv, Csv);
    k3_scan<<<dim3(24, 8), 256, 0, stream>>>(dl, u, Bsv, Csv, Alog, Dsv);
    k4_ln_mul<<<4096, 256, 0, stream>>>(dl, z, lng, lnb);
    k5_gemm_out<<<256, 256, 0, stream>>>(dl, Wout, out);
}

// Round 3
// 490.291 us; speedup vs baseline: 1.5461x; 1.5461x over previous
//
#include <hip/hip_runtime.h>
#include <hip/hip_bf16.h>
#include <math.h>

// SS1D (Mamba-like selective scan), f32 pipeline, chunked 2-pass scan.
// B=8, L=2048, DM=192, DI=384, N=16, R=12. Rows = B*L = 16384.

#define ROWS 16384
#define NCHUNK 16
#define CLEN 128

// ---------------- K1: xz = silu(x @ W_in^T) -> u, z ----------------
__global__ __launch_bounds__(256) void k1_gemm_silu(
    const float* __restrict__ x, const float* __restrict__ Win,
    float* __restrict__ u, float* __restrict__ z)
{
    __shared__ float As[32 * 132];
    __shared__ float Bs[32 * 132];
    const int tid = threadIdx.x;
    const int ty = tid >> 4, tx = tid & 15;
    const int bm = blockIdx.x * 128;
    const int bn = blockIdx.y * 128;

    float acc[2][2][4][4];
#pragma unroll
    for (int a = 0; a < 2; ++a)
#pragma unroll
        for (int b = 0; b < 2; ++b)
#pragma unroll
            for (int i = 0; i < 4; ++i)
#pragma unroll
                for (int j = 0; j < 4; ++j) acc[a][b][i][j] = 0.f;

    for (int k0 = 0; k0 < 192; k0 += 32) {
#pragma unroll
        for (int i = 0; i < 4; ++i) {
            int p = tid + i * 256;
            int m = p >> 3;
            int kk = (p & 7) * 4;
            float4 av = *(const float4*)(x + (size_t)(bm + m) * 192 + k0 + kk);
            As[(kk + 0) * 132 + m] = av.x;
            As[(kk + 1) * 132 + m] = av.y;
            As[(kk + 2) * 132 + m] = av.z;
            As[(kk + 3) * 132 + m] = av.w;
            float4 bv = *(const float4*)(Win + (size_t)(bn + m) * 192 + k0 + kk);
            Bs[(kk + 0) * 132 + m] = bv.x;
            Bs[(kk + 1) * 132 + m] = bv.y;
            Bs[(kk + 2) * 132 + m] = bv.z;
            Bs[(kk + 3) * 132 + m] = bv.w;
        }
        __syncthreads();
        const float4* As4 = (const float4*)As;
        const float4* Bs4 = (const float4*)Bs;
#pragma unroll
        for (int kk = 0; kk < 32; ++kk) {
            float4 a0 = As4[kk * 33 + ty];
            float4 a1 = As4[kk * 33 + 16 + ty];
            float4 b0 = Bs4[kk * 33 + tx];
            float4 b1 = Bs4[kk * 33 + 16 + tx];
            float ar[2][4] = {{a0.x, a0.y, a0.z, a0.w}, {a1.x, a1.y, a1.z, a1.w}};
            float br[2][4] = {{b0.x, b0.y, b0.z, b0.w}, {b1.x, b1.y, b1.z, b1.w}};
#pragma unroll
            for (int a = 0; a < 2; ++a)
#pragma unroll
                for (int i = 0; i < 4; ++i)
#pragma unroll
                    for (int b = 0; b < 2; ++b)
#pragma unroll
                        for (int j = 0; j < 4; ++j)
                            acc[a][b][i][j] = fmaf(ar[a][i], br[b][j], acc[a][b][i][j]);
        }
        __syncthreads();
    }
#pragma unroll
    for (int a = 0; a < 2; ++a)
#pragma unroll
        for (int i = 0; i < 4; ++i) {
            int row = bm + a * 64 + ty * 4 + i;
#pragma unroll
            for (int b = 0; b < 2; ++b) {
                int col = bn + b * 64 + tx * 4;
                float4 v;
                float* pv = &v.x;
#pragma unroll
                for (int j = 0; j < 4; ++j) {
                    float s = acc[a][b][i][j];
                    pv[j] = s / (1.f + __expf(-s));
                }
                if (col < 384) *(float4*)(u + (size_t)row * 384 + col) = v;
                else           *(float4*)(z + (size_t)row * 384 + (col - 384)) = v;
            }
        }
}

// ------- K2: dbl = u @ xpw^T (44 cols); delta = softplus(dbl[:,:12] @ dtw^T + b); B, C -------
__global__ __launch_bounds__(256) void k2_proj(
    const float* __restrict__ u, const float* __restrict__ xpw,
    const float* __restrict__ dtw, const float* __restrict__ dtb,
    float* __restrict__ delta, float* __restrict__ Bso, float* __restrict__ Cso)
{
    __shared__ float ut[16 * 388];
    __shared__ float dblS[16 * 48];
    const int tid = threadIdx.x;
    const int row0 = blockIdx.x * 16;

#pragma unroll
    for (int i = 0; i < 6; ++i) {
        int p = tid + i * 256;
        int r = p / 96, c4 = p % 96;
        float4 v = *(const float4*)(u + (size_t)(row0 + r) * 384 + c4 * 4);
        *(float4*)(ut + r * 388 + c4 * 4) = v;
    }
    __syncthreads();

    {
        const int r = tid >> 4, ci = tid & 15;
        const float4* u4 = (const float4*)(ut + r * 388);
        for (int pass = 0; pass < 3; ++pass) {
            int c = pass * 16 + ci;
            if (c < 44) {
                const float4* w4 = (const float4*)(xpw + (size_t)c * 384);
                float s = 0.f;
#pragma unroll 4
                for (int k4 = 0; k4 < 96; ++k4) {
                    float4 uv = u4[k4];
                    float4 wv = w4[k4];
                    s = fmaf(uv.x, wv.x, s);
                    s = fmaf(uv.y, wv.y, s);
                    s = fmaf(uv.z, wv.z, s);
                    s = fmaf(uv.w, wv.w, s);
                }
                dblS[r * 48 + c] = s;
                int row = row0 + r;
                if (c >= 28)      Cso[(size_t)row * 16 + (c - 28)] = s;
                else if (c >= 12) Bso[(size_t)row * 16 + (c - 12)] = s;
            }
        }
    }
    __syncthreads();

    for (int i = 0; i < 24; ++i) {
        int o = i * 256 + tid;
        int r = o / 384, d = o - r * 384;
        const float* w = dtw + d * 12;
        const float* db = dblS + r * 48;
        float s = dtb[d];
#pragma unroll
        for (int j = 0; j < 12; ++j) s = fmaf(db[j], w[j], s);
        float sp = (s > 20.f) ? s : log1pf(__expf(s));
        delta[(size_t)(row0 + r) * 384 + d] = sp;
    }
}

// ---------------- K3a: scan pass 1 — per-chunk local scan summaries ----------------
// block = 256 = 16 d x 16 n. grid = (24 dtiles * 16 chunks, B)
// Emits hf[b][d][c][n] (local final state) and Ssum[b][d][c] (sum of delta over chunk).
__global__ __launch_bounds__(256) void k3a_scan1(
    const float* __restrict__ delta, const float* __restrict__ u,
    const float* __restrict__ Bsv, const float* __restrict__ A_logs,
    float* __restrict__ hf, float* __restrict__ Ssum)
{
    const int tid = threadIdx.x;
    const int n = tid & 15, dl = tid >> 4;
    const int c  = blockIdx.x & 15;
    const int dt = blockIdx.x >> 4;
    const int b  = blockIdx.y;
    const int d  = dt * 16 + dl;
    const int t0 = c * CLEN;

    const float Acoef = -__expf(A_logs[d * 16 + n]);
    const float* dp = delta + ((size_t)b * 2048 + t0) * 384 + d;
    const float* up = u     + ((size_t)b * 2048 + t0) * 384 + d;
    const float* Bp = Bsv   + ((size_t)b * 2048 + t0) * 16 + n;

    float h = 0.f, S = 0.f;
#pragma unroll 4
    for (int s = 0; s < CLEN; ++s) {
        float dv = dp[(size_t)s * 384];
        float uv = up[(size_t)s * 384];
        float Bv = Bp[s * 16];
        float a = __expf(dv * Acoef);
        h = fmaf(a, h, dv * uv * Bv);
        S += dv;
    }
    hf[(((size_t)b * 384 + d) * NCHUNK + c) * 16 + n] = h;
    if (n == 0) Ssum[((size_t)b * 384 + d) * NCHUNK + c] = S;
}

// ---------------- K3b: scan pass 2 — combine summaries, rescan, emit y ----------------
// dy holds delta on entry, y on exit (in-place per (t,d), safe: read precedes write per wave).
__global__ __launch_bounds__(256) void k3b_scan2(
    float* __restrict__ dy, const float* __restrict__ u,
    const float* __restrict__ Bsv, const float* __restrict__ Csv,
    const float* __restrict__ A_logs, const float* __restrict__ Ds,
    const float* __restrict__ hf, const float* __restrict__ Ssum)
{
    const int tid = threadIdx.x;
    const int n = tid & 15, dl = tid >> 4;
    const int c  = blockIdx.x & 15;
    const int dt = blockIdx.x >> 4;
    const int b  = blockIdx.y;
    const int d  = dt * 16 + dl;
    const int t0 = c * CLEN;

    const float Acoef = -__expf(A_logs[d * 16 + n]);
    const float Dd = Ds[d];

    // h_init(c): fold predecessor chunk summaries
    float h = 0.f;
    {
        const float* hfp = hf + (((size_t)b * 384 + d) * NCHUNK) * 16 + n;
        const float* Sp  = Ssum + ((size_t)b * 384 + d) * NCHUNK;
        for (int j = 0; j < c; ++j) {
            float P = __expf(Acoef * Sp[j]);
            h = fmaf(P, h, hfp[j * 16]);
        }
    }

    float* yp       = dy  + ((size_t)b * 2048 + t0) * 384 + d;
    const float* up = u   + ((size_t)b * 2048 + t0) * 384 + d;
    const float* Bp = Bsv + ((size_t)b * 2048 + t0) * 16 + n;
    const float* Cp = Csv + ((size_t)b * 2048 + t0) * 16 + n;

#pragma unroll 4
    for (int s = 0; s < CLEN; ++s) {
        float dv = yp[(size_t)s * 384];
        float uv = up[(size_t)s * 384];
        float Bv = Bp[s * 16];
        float Cv = Cp[s * 16];
        float a = __expf(dv * Acoef);
        h = fmaf(a, h, dv * uv * Bv);
        float p = h * Cv;
        p += __shfl_xor(p, 1);
        p += __shfl_xor(p, 2);
        p += __shfl_xor(p, 4);
        p += __shfl_xor(p, 8);
        if (n == 0) yp[(size_t)s * 384] = fmaf(Dd, uv, p);
    }
}

// ---------------- K4: LayerNorm over DI, then * z (in place on y) ----------------
__global__ __launch_bounds__(256) void k4_ln_mul(
    float* __restrict__ y, const float* __restrict__ z,
    const float* __restrict__ gamma, const float* __restrict__ beta)
{
    const int tid = threadIdx.x;
    const int lane = tid & 63;
    const int w = tid >> 6;
    const size_t row = (size_t)blockIdx.x * 4 + w;
    float* yr = y + row * 384;
    const float* zr = z + row * 384;
    float v[6];
    float s1 = 0.f, s2 = 0.f;
#pragma unroll
    for (int j = 0; j < 6; ++j) {
        v[j] = yr[lane + j * 64];
        s1 += v[j];
        s2 = fmaf(v[j], v[j], s2);
    }
#pragma unroll
    for (int off = 32; off > 0; off >>= 1) {
        s1 += __shfl_xor(s1, off);
        s2 += __shfl_xor(s2, off);
    }
    float mu = s1 * (1.f / 384.f);
    float var = s2 * (1.f / 384.f) - mu * mu;
    float rs = rsqrtf(var + 1e-5f);
#pragma unroll
    for (int j = 0; j < 6; ++j) {
        int d = lane + j * 64;
        float o = (v[j] - mu) * rs * gamma[d] + beta[d];
        yr[d] = o * zr[d];
    }
}

// ---------------- K5: out = yn @ W_out^T. M=16384, N=192, K=384 ----------------
__global__ __launch_bounds__(256) void k5_gemm_out(
    const float* __restrict__ yn, const float* __restrict__ Wout,
    float* __restrict__ out)
{
    __shared__ float As[32 * 68];
    __shared__ float Bs[32 * 196];
    const int tid = threadIdx.x;
    const int ty = tid >> 4, tx = tid & 15;
    const int bm = blockIdx.x * 64;

    float acc[3][4][4];
#pragma unroll
    for (int g = 0; g < 3; ++g)
#pragma unroll
        for (int i = 0; i < 4; ++i)
#pragma unroll
            for (int j = 0; j < 4; ++j) acc[g][i][j] = 0.f;

    for (int k0 = 0; k0 < 384; k0 += 32) {
#pragma unroll
        for (int i = 0; i < 2; ++i) {
            int p = tid + i * 256;
            int m = p >> 3, kk = (p & 7) * 4;
            float4 av = *(const float4*)(yn + (size_t)(bm + m) * 384 + k0 + kk);
            As[(kk + 0) * 68 + m] = av.x;
            As[(kk + 1) * 68 + m] = av.y;
            As[(kk + 2) * 68 + m] = av.z;
            As[(kk + 3) * 68 + m] = av.w;
        }
#pragma unroll
        for (int i = 0; i < 6; ++i) {
            int p = tid + i * 256;
            int nn = p >> 3, kk = (p & 7) * 4;
            float4 bv = *(const float4*)(Wout + (size_t)nn * 384 + k0 + kk);
            Bs[(kk + 0) * 196 + nn] = bv.x;
            Bs[(kk + 1) * 196 + nn] = bv.y;
            Bs[(kk + 2) * 196 + nn] = bv.z;
            Bs[(kk + 3) * 196 + nn] = bv.w;
        }
        __syncthreads();
        const float4* As4 = (const float4*)As;
        const float4* Bs4 = (const float4*)Bs;
#pragma unroll
        for (int kk = 0; kk < 32; ++kk) {
            float4 a = As4[kk * 17 + ty];
            float ar[4] = {a.x, a.y, a.z, a.w};
#pragma unroll
            for (int g = 0; g < 3; ++g) {
                float4 bq = Bs4[kk * 49 + g * 16 + tx];
                float br[4] = {bq.x, bq.y, bq.z, bq.w};
#pragma unroll
                for (int i = 0; i < 4; ++i)
#pragma unroll
                    for (int j = 0; j < 4; ++j)
                        acc[g][i][j] = fmaf(ar[i], br[j], acc[g][i][j]);
            }
        }
        __syncthreads();
    }
#pragma unroll
    for (int i = 0; i < 4; ++i) {
        int row = bm + ty * 4 + i;
#pragma unroll
        for (int g = 0; g < 3; ++g) {
            float4 v = make_float4(acc[g][i][0], acc[g][i][1], acc[g][i][2], acc[g][i][3]);
            *(float4*)(out + (size_t)row * 192 + g * 64 + tx * 4) = v;
        }
    }
}

extern "C" void kernel_launch(void* const* d_in, const int* in_sizes, int n_in,
                              void* d_out, int out_size, void* d_ws, size_t ws_size,
                              hipStream_t stream) {
    const float* x    = (const float*)d_in[0];
    const float* Win  = (const float*)d_in[1];
    const float* xpw  = (const float*)d_in[2];
    const float* dtw  = (const float*)d_in[3];
    const float* dtb  = (const float*)d_in[4];
    const float* Alog = (const float*)d_in[5];
    const float* Dsv  = (const float*)d_in[6];
    const float* lng  = (const float*)d_in[7];
    const float* lnb  = (const float*)d_in[8];
    const float* Wout = (const float*)d_in[9];
    float* out = (float*)d_out;

    // workspace layout (floats): u, z, dl (delta->y->yn in place), Bsv, Csv, hf, Ssum
    const size_t nU  = (size_t)ROWS * 384;
    const size_t nBC = (size_t)ROWS * 16;
    const size_t nHF = (size_t)8 * 384 * NCHUNK * 16;
    const size_t nS  = (size_t)8 * 384 * NCHUNK;
    const size_t need = (nU * 3 + nBC * 2 + nHF + nS) * sizeof(float);
    if (ws_size < need) return;   // fail visibly (absmax) instead of faulting

    float* u    = (float*)d_ws;
    float* z    = u + nU;
    float* dl   = z + nU;          // delta -> y -> yn (in place)
    float* Bsv  = dl + nU;
    float* Csv  = Bsv + nBC;
    float* hf   = Csv + nBC;
    float* Ssum = hf + nHF;

    k1_gemm_silu<<<dim3(128, 6), 256, 0, stream>>>(x, Win, u, z);
    k2_proj<<<1024, 256, 0, stream>>>(u, xpw, dtw, dtb, dl, Bsv, Csv);
    k3a_scan1<<<dim3(24 * NCHUNK, 8), 256, 0, stream>>>(dl, u, Bsv, Alog, hf, Ssum);
    k3b_scan2<<<dim3(24 * NCHUNK, 8), 256, 0, stream>>>(dl, u, Bsv, Csv, Alog, Dsv, hf, Ssum);
    k4_ln_mul<<<4096, 256, 0, stream>>>(dl, z, lng, lnb);
    k5_gemm_out<<<256, 256, 0, stream>>>(dl, Wout, out);
}

// Round 5
// 419.364 us; speedup vs baseline: 1.8076x; 1.1691x over previous
//
#include <hip/hip_runtime.h>
#include <hip/hip_bf16.h>
#include <math.h>

// SS1D (Mamba-like selective scan), f32 pipeline, chunked 2-pass scan.
// B=8, L=2048, DM=192, DI=384, N=16, R=12. Rows = B*L = 16384.

#define ROWS 16384
#define NCHUNK 16
#define CLEN 128

// ---------------- K1: xz = silu(x @ W_in^T) -> u, z ----------------
__global__ __launch_bounds__(256) void k1_gemm_silu(
    const float* __restrict__ x, const float* __restrict__ Win,
    float* __restrict__ u, float* __restrict__ z)
{
    __shared__ float As[32 * 132];
    __shared__ float Bs[32 * 132];
    const int tid = threadIdx.x;
    const int ty = tid >> 4, tx = tid & 15;
    const int bm = blockIdx.x * 128;
    const int bn = blockIdx.y * 128;

    float acc[2][2][4][4];
#pragma unroll
    for (int a = 0; a < 2; ++a)
#pragma unroll
        for (int b = 0; b < 2; ++b)
#pragma unroll
            for (int i = 0; i < 4; ++i)
#pragma unroll
                for (int j = 0; j < 4; ++j) acc[a][b][i][j] = 0.f;

    for (int k0 = 0; k0 < 192; k0 += 32) {
#pragma unroll
        for (int i = 0; i < 4; ++i) {
            int p = tid + i * 256;
            int m = p >> 3;
            int kk = (p & 7) * 4;
            float4 av = *(const float4*)(x + (size_t)(bm + m) * 192 + k0 + kk);
            As[(kk + 0) * 132 + m] = av.x;
            As[(kk + 1) * 132 + m] = av.y;
            As[(kk + 2) * 132 + m] = av.z;
            As[(kk + 3) * 132 + m] = av.w;
            float4 bv = *(const float4*)(Win + (size_t)(bn + m) * 192 + k0 + kk);
            Bs[(kk + 0) * 132 + m] = bv.x;
            Bs[(kk + 1) * 132 + m] = bv.y;
            Bs[(kk + 2) * 132 + m] = bv.z;
            Bs[(kk + 3) * 132 + m] = bv.w;
        }
        __syncthreads();
        const float4* As4 = (const float4*)As;
        const float4* Bs4 = (const float4*)Bs;
#pragma unroll
        for (int kk = 0; kk < 32; ++kk) {
            float4 a0 = As4[kk * 33 + ty];
            float4 a1 = As4[kk * 33 + 16 + ty];
            float4 b0 = Bs4[kk * 33 + tx];
            float4 b1 = Bs4[kk * 33 + 16 + tx];
            float ar[2][4] = {{a0.x, a0.y, a0.z, a0.w}, {a1.x, a1.y, a1.z, a1.w}};
            float br[2][4] = {{b0.x, b0.y, b0.z, b0.w}, {b1.x, b1.y, b1.z, b1.w}};
#pragma unroll
            for (int a = 0; a < 2; ++a)
#pragma unroll
                for (int i = 0; i < 4; ++i)
#pragma unroll
                    for (int b = 0; b < 2; ++b)
#pragma unroll
                        for (int j = 0; j < 4; ++j)
                            acc[a][b][i][j] = fmaf(ar[a][i], br[b][j], acc[a][b][i][j]);
        }
        __syncthreads();
    }
#pragma unroll
    for (int a = 0; a < 2; ++a)
#pragma unroll
        for (int i = 0; i < 4; ++i) {
            int row = bm + a * 64 + ty * 4 + i;
#pragma unroll
            for (int b = 0; b < 2; ++b) {
                int col = bn + b * 64 + tx * 4;
                float4 v;
                float* pv = &v.x;
#pragma unroll
                for (int j = 0; j < 4; ++j) {
                    float s = acc[a][b][i][j];
                    pv[j] = s / (1.f + __expf(-s));
                }
                if (col < 384) *(float4*)(u + (size_t)row * 384 + col) = v;
                else           *(float4*)(z + (size_t)row * 384 + (col - 384)) = v;
            }
        }
}

// ------- K2: dbl = u @ xpw^T (44 cols); delta = softplus(dbl[:,:12] @ dtw^T + b); B, C -------
// Block = 64 rows. Phase A: tiled GEMM M=64,N=48(44),K=384, 4x3 micro-tile.
// Phase B: delta from LDS-staged dtw (pad-13 banking) + dblS.
__global__ __launch_bounds__(256) void k2_proj(
    const float* __restrict__ u, const float* __restrict__ xpw,
    const float* __restrict__ dtw, const float* __restrict__ dtb,
    float* __restrict__ delta, float* __restrict__ Bso, float* __restrict__ Cso)
{
    __shared__ float As[64 * 68];     // [kk][row], row-contig, 16B-aligned rows-of-68
    __shared__ float Bs[64 * 53];     // [kk][col], pad 53
    __shared__ float dtwS[384 * 13];  // [d][j], pad 13 (bijective mod 32)
    __shared__ float dblS[64 * 13];   // [row][j<12]
    const int tid = threadIdx.x;
    const int tx = tid & 15, ty = tid >> 4;
    const int row0 = blockIdx.x * 64;

    // stage dtw once (384x12 = 1152 float4s / 4)
#pragma unroll
    for (int i = 0; i < 5; ++i) {
        int p = tid + i * 256;
        if (p < 1152) {
            int dd = p / 3, q = (p % 3) * 4;
            float4 v = *(const float4*)(dtw + dd * 12 + q);
            dtwS[dd * 13 + q + 0] = v.x;
            dtwS[dd * 13 + q + 1] = v.y;
            dtwS[dd * 13 + q + 2] = v.z;
            dtwS[dd * 13 + q + 3] = v.w;
        }
    }

    float acc[4][3];
#pragma unroll
    for (int i = 0; i < 4; ++i)
#pragma unroll
        for (int g = 0; g < 3; ++g) acc[i][g] = 0.f;

    for (int k0 = 0; k0 < 384; k0 += 64) {
        // stage A: 64 rows x 64 K (1024 float4)
#pragma unroll
        for (int i = 0; i < 4; ++i) {
            int p = tid + i * 256;
            int r = p >> 4, k4 = (p & 15) * 4;
            float4 v = *(const float4*)(u + (size_t)(row0 + r) * 384 + k0 + k4);
            As[(k4 + 0) * 68 + r] = v.x;
            As[(k4 + 1) * 68 + r] = v.y;
            As[(k4 + 2) * 68 + r] = v.z;
            As[(k4 + 3) * 68 + r] = v.w;
        }
        // stage B: 48 cols x 64 K (768 float4), zero-pad cols >= 44
#pragma unroll
        for (int i = 0; i < 3; ++i) {
            int p = tid + i * 256;
            int c = p >> 4, k4 = (p & 15) * 4;
            float4 v = make_float4(0.f, 0.f, 0.f, 0.f);
            if (c < 44) v = *(const float4*)(xpw + (size_t)c * 384 + k0 + k4);
            Bs[(k4 + 0) * 53 + c] = v.x;
            Bs[(k4 + 1) * 53 + c] = v.y;
            Bs[(k4 + 2) * 53 + c] = v.z;
            Bs[(k4 + 3) * 53 + c] = v.w;
        }
        __syncthreads();
#pragma unroll 8
        for (int kk = 0; kk < 64; ++kk) {
            float4 a = *(const float4*)(As + kk * 68 + ty * 4);   // rows ty*4..+3
            float b0 = Bs[kk * 53 + tx];
            float b1 = Bs[kk * 53 + tx + 16];
            float b2 = Bs[kk * 53 + tx + 32];
            acc[0][0] = fmaf(a.x, b0, acc[0][0]);
            acc[1][0] = fmaf(a.y, b0, acc[1][0]);
            acc[2][0] = fmaf(a.z, b0, acc[2][0]);
            acc[3][0] = fmaf(a.w, b0, acc[3][0]);
            acc[0][1] = fmaf(a.x, b1, acc[0][1]);
            acc[1][1] = fmaf(a.y, b1, acc[1][1]);
            acc[2][1] = fmaf(a.z, b1, acc[2][1]);
            acc[3][1] = fmaf(a.w, b1, acc[3][1]);
            acc[0][2] = fmaf(a.x, b2, acc[0][2]);
            acc[1][2] = fmaf(a.y, b2, acc[1][2]);
            acc[2][2] = fmaf(a.z, b2, acc[2][2]);
            acc[3][2] = fmaf(a.w, b2, acc[3][2]);
        }
        __syncthreads();
    }

    // epilogue: route dbl cols -> dblS (j<12) / Bso (12..27) / Cso (28..43)
#pragma unroll
    for (int i = 0; i < 4; ++i) {
        int lr = ty * 4 + i;
        int row = row0 + lr;
#pragma unroll
        for (int g = 0; g < 3; ++g) {
            int c = g * 16 + tx;
            float s = acc[i][g];
            if (c < 12)      dblS[lr * 13 + c] = s;
            else if (c < 28) Bso[(size_t)row * 16 + (c - 12)] = s;
            else if (c < 44) Cso[(size_t)row * 16 + (c - 28)] = s;
        }
    }
    __syncthreads();

    // phase B: delta = softplus(dblS @ dtw^T + dtb), 64 rows x 384 d
    for (int it = 0; it < 96; ++it) {
        int o = it * 256 + tid;
        int r = o / 384, d = o - r * 384;
        float s = dtb[d];
        const float* wr = dtwS + d * 13;
        const float* db = dblS + r * 13;
#pragma unroll
        for (int j = 0; j < 12; ++j) s = fmaf(db[j], wr[j], s);
        float sp = (s > 20.f) ? s : log1pf(__expf(s));
        delta[(size_t)(row0 + r) * 384 + d] = sp;
    }
}

// ---------------- K3a: scan pass 1 — per-chunk local scan summaries ----------------
__global__ __launch_bounds__(256) void k3a_scan1(
    const float* __restrict__ delta, const float* __restrict__ u,
    const float* __restrict__ Bsv, const float* __restrict__ A_logs,
    float* __restrict__ hf, float* __restrict__ Ssum)
{
    const int tid = threadIdx.x;
    const int n = tid & 15, dl = tid >> 4;
    const int c  = blockIdx.x & 15;
    const int dt = blockIdx.x >> 4;
    const int b  = blockIdx.y;
    const int d  = dt * 16 + dl;
    const int t0 = c * CLEN;

    const float Acoef = -__expf(A_logs[d * 16 + n]);
    const float* dp = delta + ((size_t)b * 2048 + t0) * 384 + d;
    const float* up = u     + ((size_t)b * 2048 + t0) * 384 + d;
    const float* Bp = Bsv   + ((size_t)b * 2048 + t0) * 16 + n;

    float h = 0.f, S = 0.f;
#pragma unroll 4
    for (int s = 0; s < CLEN; ++s) {
        float dv = dp[(size_t)s * 384];
        float uv = up[(size_t)s * 384];
        float Bv = Bp[s * 16];
        float a = __expf(dv * Acoef);
        h = fmaf(a, h, dv * uv * Bv);
        S += dv;
    }
    hf[(((size_t)b * 384 + d) * NCHUNK + c) * 16 + n] = h;
    if (n == 0) Ssum[((size_t)b * 384 + d) * NCHUNK + c] = S;
}

// ---------------- K3b: scan pass 2 — combine summaries, rescan, emit y ----------------
__global__ __launch_bounds__(256) void k3b_scan2(
    float* __restrict__ dy, const float* __restrict__ u,
    const float* __restrict__ Bsv, const float* __restrict__ Csv,
    const float* __restrict__ A_logs, const float* __restrict__ Ds,
    const float* __restrict__ hf, const float* __restrict__ Ssum)
{
    const int tid = threadIdx.x;
    const int n = tid & 15, dl = tid >> 4;
    const int c  = blockIdx.x & 15;
    const int dt = blockIdx.x >> 4;
    const int b  = blockIdx.y;
    const int d  = dt * 16 + dl;
    const int t0 = c * CLEN;

    const float Acoef = -__expf(A_logs[d * 16 + n]);
    const float Dd = Ds[d];

    float h = 0.f;
    {
        const float* hfp = hf + (((size_t)b * 384 + d) * NCHUNK) * 16 + n;
        const float* Sp  = Ssum + ((size_t)b * 384 + d) * NCHUNK;
        for (int j = 0; j < c; ++j) {
            float P = __expf(Acoef * Sp[j]);
            h = fmaf(P, h, hfp[j * 16]);
        }
    }

    float* yp       = dy  + ((size_t)b * 2048 + t0) * 384 + d;
    const float* up = u   + ((size_t)b * 2048 + t0) * 384 + d;
    const float* Bp = Bsv + ((size_t)b * 2048 + t0) * 16 + n;
    const float* Cp = Csv + ((size_t)b * 2048 + t0) * 16 + n;

#pragma unroll 4
    for (int s = 0; s < CLEN; ++s) {
        float dv = yp[(size_t)s * 384];
        float uv = up[(size_t)s * 384];
        float Bv = Bp[s * 16];
        float Cv = Cp[s * 16];
        float a = __expf(dv * Acoef);
        h = fmaf(a, h, dv * uv * Bv);
        float p = h * Cv;
        p += __shfl_xor(p, 1);
        p += __shfl_xor(p, 2);
        p += __shfl_xor(p, 4);
        p += __shfl_xor(p, 8);
        if (n == 0) yp[(size_t)s * 384] = fmaf(Dd, uv, p);
    }
}

// ---------------- K4: LayerNorm over DI, then * z (in place on y) ----------------
__global__ __launch_bounds__(256) void k4_ln_mul(
    float* __restrict__ y, const float* __restrict__ z,
    const float* __restrict__ gamma, const float* __restrict__ beta)
{
    const int tid = threadIdx.x;
    const int lane = tid & 63;
    const int w = tid >> 6;
    const size_t row = (size_t)blockIdx.x * 4 + w;
    float* yr = y + row * 384;
    const float* zr = z + row * 384;
    float v[6];
    float s1 = 0.f, s2 = 0.f;
#pragma unroll
    for (int j = 0; j < 6; ++j) {
        v[j] = yr[lane + j * 64];
        s1 += v[j];
        s2 = fmaf(v[j], v[j], s2);
    }
#pragma unroll
    for (int off = 32; off > 0; off >>= 1) {
        s1 += __shfl_xor(s1, off);
        s2 += __shfl_xor(s2, off);
    }
    float mu = s1 * (1.f / 384.f);
    float var = s2 * (1.f / 384.f) - mu * mu;
    float rs = rsqrtf(var + 1e-5f);
#pragma unroll
    for (int j = 0; j < 6; ++j) {
        int d = lane + j * 64;
        float o = (v[j] - mu) * rs * gamma[d] + beta[d];
        yr[d] = o * zr[d];
    }
}

// ---------------- K5: out = yn @ W_out^T. M=16384, N=192, K=384 ----------------
__global__ __launch_bounds__(256) void k5_gemm_out(
    const float* __restrict__ yn, const float* __restrict__ Wout,
    float* __restrict__ out)
{
    __shared__ float As[32 * 68];
    __shared__ float Bs[32 * 196];
    const int tid = threadIdx.x;
    const int ty = tid >> 4, tx = tid & 15;
    const int bm = blockIdx.x * 64;

    float acc[3][4][4];
#pragma unroll
    for (int g = 0; g < 3; ++g)
#pragma unroll
        for (int i = 0; i < 4; ++i)
#pragma unroll
            for (int j = 0; j < 4; ++j) acc[g][i][j] = 0.f;

    for (int k0 = 0; k0 < 384; k0 += 32) {
#pragma unroll
        for (int i = 0; i < 2; ++i) {
            int p = tid + i * 256;
            int m = p >> 3, kk = (p & 7) * 4;
            float4 av = *(const float4*)(yn + (size_t)(bm + m) * 384 + k0 + kk);
            As[(kk + 0) * 68 + m] = av.x;
            As[(kk + 1) * 68 + m] = av.y;
            As[(kk + 2) * 68 + m] = av.z;
            As[(kk + 3) * 68 + m] = av.w;
        }
#pragma unroll
        for (int i = 0; i < 6; ++i) {
            int p = tid + i * 256;
            int nn = p >> 3, kk = (p & 7) * 4;
            float4 bv = *(const float4*)(Wout + (size_t)nn * 384 + k0 + kk);
            Bs[(kk + 0) * 196 + nn] = bv.x;
            Bs[(kk + 1) * 196 + nn] = bv.y;
            Bs[(kk + 2) * 196 + nn] = bv.z;
            Bs[(kk + 3) * 196 + nn] = bv.w;
        }
        __syncthreads();
        const float4* As4 = (const float4*)As;
        const float4* Bs4 = (const float4*)Bs;
#pragma unroll
        for (int kk = 0; kk < 32; ++kk) {
            float4 a = As4[kk * 17 + ty];
            float ar[4] = {a.x, a.y, a.z, a.w};
#pragma unroll
            for (int g = 0; g < 3; ++g) {
                float4 bq = Bs4[kk * 49 + g * 16 + tx];
                float br[4] = {bq.x, bq.y, bq.z, bq.w};
#pragma unroll
                for (int i = 0; i < 4; ++i)
#pragma unroll
                    for (int j = 0; j < 4; ++j)
                        acc[g][i][j] = fmaf(ar[i], br[j], acc[g][i][j]);
            }
        }
        __syncthreads();
    }
#pragma unroll
    for (int i = 0; i < 4; ++i) {
        int row = bm + ty * 4 + i;
#pragma unroll
        for (int g = 0; g < 3; ++g) {
            float4 v = make_float4(acc[g][i][0], acc[g][i][1], acc[g][i][2], acc[g][i][3]);
            *(float4*)(out + (size_t)row * 192 + g * 64 + tx * 4) = v;
        }
    }
}

extern "C" void kernel_launch(void* const* d_in, const int* in_sizes, int n_in,
                              void* d_out, int out_size, void* d_ws, size_t ws_size,
                              hipStream_t stream) {
    const float* x    = (const float*)d_in[0];
    const float* Win  = (const float*)d_in[1];
    const float* xpw  = (const float*)d_in[2];
    const float* dtw  = (const float*)d_in[3];
    const float* dtb  = (const float*)d_in[4];
    const float* Alog = (const float*)d_in[5];
    const float* Dsv  = (const float*)d_in[6];
    const float* lng  = (const float*)d_in[7];
    const float* lnb  = (const float*)d_in[8];
    const float* Wout = (const float*)d_in[9];
    float* out = (float*)d_out;

    const size_t nU  = (size_t)ROWS * 384;
    const size_t nBC = (size_t)ROWS * 16;
    const size_t nHF = (size_t)8 * 384 * NCHUNK * 16;
    const size_t nS  = (size_t)8 * 384 * NCHUNK;
    const size_t need = (nU * 3 + nBC * 2 + nHF + nS) * sizeof(float);
    if (ws_size < need) return;   // fail visibly (absmax) instead of faulting

    float* u    = (float*)d_ws;
    float* z    = u + nU;
    float* dl   = z + nU;          // delta -> y -> yn (in place)
    float* Bsv  = dl + nU;
    float* Csv  = Bsv + nBC;
    float* hf   = Csv + nBC;
    float* Ssum = hf + nHF;

    k1_gemm_silu<<<dim3(128, 6), 256, 0, stream>>>(x, Win, u, z);
    k2_proj<<<256, 256, 0, stream>>>(u, xpw, dtw, dtb, dl, Bsv, Csv);
    k3a_scan1<<<dim3(24 * NCHUNK, 8), 256, 0, stream>>>(dl, u, Bsv, Alog, hf, Ssum);
    k3b_scan2<<<dim3(24 * NCHUNK, 8), 256, 0, stream>>>(dl, u, Bsv, Csv, Alog, Dsv, hf, Ssum);
    k4_ln_mul<<<4096, 256, 0, stream>>>(dl, z, lng, lnb);
    k5_gemm_out<<<256, 256, 0, stream>>>(dl, Wout, out);
}

// Round 6
// 370.312 us; speedup vs baseline: 2.0471x; 1.1325x over previous
//
#include <hip/hip_runtime.h>
#include <hip/hip_bf16.h>
#include <math.h>

// SS1D (Mamba-like selective scan), f32 pipeline, chunked 2-pass scan.
// B=8, L=2048, DM=192, DI=384, N=16, R=12. Rows = B*L = 16384.

#define ROWS 16384
#define NCHUNK 16
#define CLEN 128

// DPP row-rotate-add: after ror8/4/2/1 chain, every lane holds the sum of its
// 16-lane row (CDNA DPP "row" = 16 lanes = one n-group here). Full-rate VALU.
template <int CTRL>
__device__ __forceinline__ float ror_add(float x) {
    int y = __builtin_amdgcn_update_dpp(0, __float_as_int(x), CTRL, 0xF, 0xF, true);
    return x + __int_as_float(y);
}
__device__ __forceinline__ float row16_sum(float p) {
    p = ror_add<0x128>(p);   // row_ror:8
    p = ror_add<0x124>(p);   // row_ror:4
    p = ror_add<0x122>(p);   // row_ror:2
    p = ror_add<0x121>(p);   // row_ror:1
    return p;
}

// ---------------- K1: xz = silu(x @ W_in^T) -> u, z ----------------
__global__ __launch_bounds__(256) void k1_gemm_silu(
    const float* __restrict__ x, const float* __restrict__ Win,
    float* __restrict__ u, float* __restrict__ z)
{
    __shared__ float As[32 * 132];
    __shared__ float Bs[32 * 132];
    const int tid = threadIdx.x;
    const int ty = tid >> 4, tx = tid & 15;
    const int bm = blockIdx.x * 128;
    const int bn = blockIdx.y * 128;

    float acc[2][2][4][4];
#pragma unroll
    for (int a = 0; a < 2; ++a)
#pragma unroll
        for (int b = 0; b < 2; ++b)
#pragma unroll
            for (int i = 0; i < 4; ++i)
#pragma unroll
                for (int j = 0; j < 4; ++j) acc[a][b][i][j] = 0.f;

    for (int k0 = 0; k0 < 192; k0 += 32) {
#pragma unroll
        for (int i = 0; i < 4; ++i) {
            int p = tid + i * 256;
            int m = p >> 3;
            int kk = (p & 7) * 4;
            float4 av = *(const float4*)(x + (size_t)(bm + m) * 192 + k0 + kk);
            As[(kk + 0) * 132 + m] = av.x;
            As[(kk + 1) * 132 + m] = av.y;
            As[(kk + 2) * 132 + m] = av.z;
            As[(kk + 3) * 132 + m] = av.w;
            float4 bv = *(const float4*)(Win + (size_t)(bn + m) * 192 + k0 + kk);
            Bs[(kk + 0) * 132 + m] = bv.x;
            Bs[(kk + 1) * 132 + m] = bv.y;
            Bs[(kk + 2) * 132 + m] = bv.z;
            Bs[(kk + 3) * 132 + m] = bv.w;
        }
        __syncthreads();
        const float4* As4 = (const float4*)As;
        const float4* Bs4 = (const float4*)Bs;
#pragma unroll
        for (int kk = 0; kk < 32; ++kk) {
            float4 a0 = As4[kk * 33 + ty];
            float4 a1 = As4[kk * 33 + 16 + ty];
            float4 b0 = Bs4[kk * 33 + tx];
            float4 b1 = Bs4[kk * 33 + 16 + tx];
            float ar[2][4] = {{a0.x, a0.y, a0.z, a0.w}, {a1.x, a1.y, a1.z, a1.w}};
            float br[2][4] = {{b0.x, b0.y, b0.z, b0.w}, {b1.x, b1.y, b1.z, b1.w}};
#pragma unroll
            for (int a = 0; a < 2; ++a)
#pragma unroll
                for (int i = 0; i < 4; ++i)
#pragma unroll
                    for (int b = 0; b < 2; ++b)
#pragma unroll
                        for (int j = 0; j < 4; ++j)
                            acc[a][b][i][j] = fmaf(ar[a][i], br[b][j], acc[a][b][i][j]);
        }
        __syncthreads();
    }
#pragma unroll
    for (int a = 0; a < 2; ++a)
#pragma unroll
        for (int i = 0; i < 4; ++i) {
            int row = bm + a * 64 + ty * 4 + i;
#pragma unroll
            for (int b = 0; b < 2; ++b) {
                int col = bn + b * 64 + tx * 4;
                float4 v;
                float* pv = &v.x;
#pragma unroll
                for (int j = 0; j < 4; ++j) {
                    float s = acc[a][b][i][j];
                    pv[j] = s / (1.f + __expf(-s));
                }
                if (col < 384) *(float4*)(u + (size_t)row * 384 + col) = v;
                else           *(float4*)(z + (size_t)row * 384 + (col - 384)) = v;
            }
        }
}

// ------- K2: dbl = u @ xpw^T (44 cols); delta = softplus(dbl[:,:12] @ dtw^T + b); B, C -------
__global__ __launch_bounds__(256) void k2_proj(
    const float* __restrict__ u, const float* __restrict__ xpw,
    const float* __restrict__ dtw, const float* __restrict__ dtb,
    float* __restrict__ delta, float* __restrict__ Bso, float* __restrict__ Cso)
{
    __shared__ float As[64 * 68];
    __shared__ float Bs[64 * 53];
    __shared__ float dtwS[384 * 13];
    __shared__ float dblS[64 * 13];
    const int tid = threadIdx.x;
    const int tx = tid & 15, ty = tid >> 4;
    const int row0 = blockIdx.x * 64;

#pragma unroll
    for (int i = 0; i < 5; ++i) {
        int p = tid + i * 256;
        if (p < 1152) {
            int dd = p / 3, q = (p % 3) * 4;
            float4 v = *(const float4*)(dtw + dd * 12 + q);
            dtwS[dd * 13 + q + 0] = v.x;
            dtwS[dd * 13 + q + 1] = v.y;
            dtwS[dd * 13 + q + 2] = v.z;
            dtwS[dd * 13 + q + 3] = v.w;
        }
    }

    float acc[4][3];
#pragma unroll
    for (int i = 0; i < 4; ++i)
#pragma unroll
        for (int g = 0; g < 3; ++g) acc[i][g] = 0.f;

    for (int k0 = 0; k0 < 384; k0 += 64) {
#pragma unroll
        for (int i = 0; i < 4; ++i) {
            int p = tid + i * 256;
            int r = p >> 4, k4 = (p & 15) * 4;
            float4 v = *(const float4*)(u + (size_t)(row0 + r) * 384 + k0 + k4);
            As[(k4 + 0) * 68 + r] = v.x;
            As[(k4 + 1) * 68 + r] = v.y;
            As[(k4 + 2) * 68 + r] = v.z;
            As[(k4 + 3) * 68 + r] = v.w;
        }
#pragma unroll
        for (int i = 0; i < 3; ++i) {
            int p = tid + i * 256;
            int c = p >> 4, k4 = (p & 15) * 4;
            float4 v = make_float4(0.f, 0.f, 0.f, 0.f);
            if (c < 44) v = *(const float4*)(xpw + (size_t)c * 384 + k0 + k4);
            Bs[(k4 + 0) * 53 + c] = v.x;
            Bs[(k4 + 1) * 53 + c] = v.y;
            Bs[(k4 + 2) * 53 + c] = v.z;
            Bs[(k4 + 3) * 53 + c] = v.w;
        }
        __syncthreads();
#pragma unroll 8
        for (int kk = 0; kk < 64; ++kk) {
            float4 a = *(const float4*)(As + kk * 68 + ty * 4);
            float b0 = Bs[kk * 53 + tx];
            float b1 = Bs[kk * 53 + tx + 16];
            float b2 = Bs[kk * 53 + tx + 32];
            acc[0][0] = fmaf(a.x, b0, acc[0][0]);
            acc[1][0] = fmaf(a.y, b0, acc[1][0]);
            acc[2][0] = fmaf(a.z, b0, acc[2][0]);
            acc[3][0] = fmaf(a.w, b0, acc[3][0]);
            acc[0][1] = fmaf(a.x, b1, acc[0][1]);
            acc[1][1] = fmaf(a.y, b1, acc[1][1]);
            acc[2][1] = fmaf(a.z, b1, acc[2][1]);
            acc[3][1] = fmaf(a.w, b1, acc[3][1]);
            acc[0][2] = fmaf(a.x, b2, acc[0][2]);
            acc[1][2] = fmaf(a.y, b2, acc[1][2]);
            acc[2][2] = fmaf(a.z, b2, acc[2][2]);
            acc[3][2] = fmaf(a.w, b2, acc[3][2]);
        }
        __syncthreads();
    }

#pragma unroll
    for (int i = 0; i < 4; ++i) {
        int lr = ty * 4 + i;
        int row = row0 + lr;
#pragma unroll
        for (int g = 0; g < 3; ++g) {
            int c = g * 16 + tx;
            float s = acc[i][g];
            if (c < 12)      dblS[lr * 13 + c] = s;
            else if (c < 28) Bso[(size_t)row * 16 + (c - 12)] = s;
            else if (c < 44) Cso[(size_t)row * 16 + (c - 28)] = s;
        }
    }
    __syncthreads();

    for (int it = 0; it < 96; ++it) {
        int o = it * 256 + tid;
        int r = o / 384, d = o - r * 384;
        float s = dtb[d];
        const float* wr = dtwS + d * 13;
        const float* db = dblS + r * 13;
#pragma unroll
        for (int j = 0; j < 12; ++j) s = fmaf(db[j], wr[j], s);
        float sp = (s > 20.f) ? s : log1pf(__expf(s));
        delta[(size_t)(row0 + r) * 384 + d] = sp;
    }
}

// ---------------- K3a: scan pass 1 — per-chunk local scan summaries ----------------
// 8-step-deep double-buffered register pipeline; sched_barrier pins the prefetch.
__global__ __launch_bounds__(256) void k3a_scan1(
    const float* __restrict__ delta, const float* __restrict__ u,
    const float* __restrict__ Bsv, const float* __restrict__ A_logs,
    float* __restrict__ hf, float* __restrict__ Ssum)
{
    const int tid = threadIdx.x;
    const int n = tid & 15, dl = tid >> 4;
    const int c  = blockIdx.x & 15;
    const int dt = blockIdx.x >> 4;
    const int b  = blockIdx.y;
    const int d  = dt * 16 + dl;
    const int t0 = c * CLEN;

    const float Acoef = -__expf(A_logs[d * 16 + n]);
    const float* dp = delta + ((size_t)b * 2048 + t0) * 384 + d;
    const float* up = u     + ((size_t)b * 2048 + t0) * 384 + d;
    const float* Bp = Bsv   + ((size_t)b * 2048 + t0) * 16 + n;

    float pdt[8], put[8], pB[8];
#pragma unroll
    for (int i = 0; i < 8; ++i) {
        pdt[i] = dp[(size_t)i * 384]; put[i] = up[(size_t)i * 384]; pB[i] = Bp[i * 16];
    }

    float h = 0.f, S = 0.f;
    for (int g = 0; g < CLEN; g += 8) {
        float cdt[8], cut[8], cB[8];
#pragma unroll
        for (int i = 0; i < 8; ++i) { cdt[i] = pdt[i]; cut[i] = put[i]; cB[i] = pB[i]; }
        dp += 8 * 384; up += 8 * 384; Bp += 8 * 16;
        if (g + 8 < CLEN) {
#pragma unroll
            for (int i = 0; i < 8; ++i) {
                pdt[i] = dp[(size_t)i * 384]; put[i] = up[(size_t)i * 384]; pB[i] = Bp[i * 16];
            }
        }
        __builtin_amdgcn_sched_barrier(0);   // prefetch must issue before compute
#pragma unroll
        for (int i = 0; i < 8; ++i) {
            float dv = cdt[i];
            float a = __expf(dv * Acoef);
            h = fmaf(a, h, dv * cut[i] * cB[i]);
            S += dv;
        }
    }
    hf[(((size_t)b * 384 + d) * NCHUNK + c) * 16 + n] = h;
    if (n == 0) Ssum[((size_t)b * 384 + d) * NCHUNK + c] = S;
}

// ---------------- K3b: scan pass 2 — combine summaries, rescan, emit y ----------------
__global__ __launch_bounds__(256) void k3b_scan2(
    float* __restrict__ dy, const float* __restrict__ u,
    const float* __restrict__ Bsv, const float* __restrict__ Csv,
    const float* __restrict__ A_logs, const float* __restrict__ Ds,
    const float* __restrict__ hf, const float* __restrict__ Ssum)
{
    const int tid = threadIdx.x;
    const int n = tid & 15, dl = tid >> 4;
    const int c  = blockIdx.x & 15;
    const int dt = blockIdx.x >> 4;
    const int b  = blockIdx.y;
    const int d  = dt * 16 + dl;
    const int t0 = c * CLEN;

    const float Acoef = -__expf(A_logs[d * 16 + n]);
    const float Dd = Ds[d];

    float h = 0.f;
    {
        const float* hfp = hf + (((size_t)b * 384 + d) * NCHUNK) * 16 + n;
        const float* Sp  = Ssum + ((size_t)b * 384 + d) * NCHUNK;
        for (int j = 0; j < c; ++j) {
            float P = __expf(Acoef * Sp[j]);
            h = fmaf(P, h, hfp[j * 16]);
        }
    }

    float* yp       = dy  + ((size_t)b * 2048 + t0) * 384 + d;
    const float* up = u   + ((size_t)b * 2048 + t0) * 384 + d;
    const float* Bp = Bsv + ((size_t)b * 2048 + t0) * 16 + n;
    const float* Cp = Csv + ((size_t)b * 2048 + t0) * 16 + n;

    float pdt[8], put[8], pB[8], pC[8];
#pragma unroll
    for (int i = 0; i < 8; ++i) {
        pdt[i] = yp[(size_t)i * 384]; put[i] = up[(size_t)i * 384];
        pB[i] = Bp[i * 16];           pC[i] = Cp[i * 16];
    }
    const float* dp = yp + 8 * 384;   // next-group load cursor (delta source)
    float* yq = yp;                   // store cursor

    for (int g = 0; g < CLEN; g += 8) {
        float cdt[8], cut[8], cB[8], cC[8];
#pragma unroll
        for (int i = 0; i < 8; ++i) { cdt[i] = pdt[i]; cut[i] = put[i]; cB[i] = pB[i]; cC[i] = pC[i]; }
        up += 8 * 384; Bp += 8 * 16; Cp += 8 * 16;
        if (g + 8 < CLEN) {
#pragma unroll
            for (int i = 0; i < 8; ++i) {
                pdt[i] = dp[(size_t)i * 384]; put[i] = up[(size_t)i * 384];
                pB[i] = Bp[i * 16];           pC[i] = Cp[i * 16];
            }
        }
        dp += 8 * 384;
        __builtin_amdgcn_sched_barrier(0);   // prefetch must issue before compute
#pragma unroll
        for (int i = 0; i < 8; ++i) {
            float dv = cdt[i];
            float a = __expf(dv * Acoef);
            h = fmaf(a, h, dv * cut[i] * cB[i]);
            float p = row16_sum(h * cC[i]);
            if (n == 0) yq[(size_t)i * 384] = fmaf(Dd, cut[i], p);
        }
        yq += 8 * 384;
    }
}

// ---------------- K4: LayerNorm over DI, then * z (in place on y) ----------------
__global__ __launch_bounds__(256) void k4_ln_mul(
    float* __restrict__ y, const float* __restrict__ z,
    const float* __restrict__ gamma, const float* __restrict__ beta)
{
    const int tid = threadIdx.x;
    const int lane = tid & 63;
    const int w = tid >> 6;
    const size_t row = (size_t)blockIdx.x * 4 + w;
    float* yr = y + row * 384;
    const float* zr = z + row * 384;
    float v[6];
    float s1 = 0.f, s2 = 0.f;
#pragma unroll
    for (int j = 0; j < 6; ++j) {
        v[j] = yr[lane + j * 64];
        s1 += v[j];
        s2 = fmaf(v[j], v[j], s2);
    }
#pragma unroll
    for (int off = 32; off > 0; off >>= 1) {
        s1 += __shfl_xor(s1, off);
        s2 += __shfl_xor(s2, off);
    }
    float mu = s1 * (1.f / 384.f);
    float var = s2 * (1.f / 384.f) - mu * mu;
    float rs = rsqrtf(var + 1e-5f);
#pragma unroll
    for (int j = 0; j < 6; ++j) {
        int d = lane + j * 64;
        float o = (v[j] - mu) * rs * gamma[d] + beta[d];
        yr[d] = o * zr[d];
    }
}

// ---------------- K5: out = yn @ W_out^T. M=16384, N=192, K=384 ----------------
__global__ __launch_bounds__(256) void k5_gemm_out(
    const float* __restrict__ yn, const float* __restrict__ Wout,
    float* __restrict__ out)
{
    __shared__ float As[32 * 68];
    __shared__ float Bs[32 * 196];
    const int tid = threadIdx.x;
    const int ty = tid >> 4, tx = tid & 15;
    const int bm = blockIdx.x * 64;

    float acc[3][4][4];
#pragma unroll
    for (int g = 0; g < 3; ++g)
#pragma unroll
        for (int i = 0; i < 4; ++i)
#pragma unroll
            for (int j = 0; j < 4; ++j) acc[g][i][j] = 0.f;

    for (int k0 = 0; k0 < 384; k0 += 32) {
#pragma unroll
        for (int i = 0; i < 2; ++i) {
            int p = tid + i * 256;
            int m = p >> 3, kk = (p & 7) * 4;
            float4 av = *(const float4*)(yn + (size_t)(bm + m) * 384 + k0 + kk);
            As[(kk + 0) * 68 + m] = av.x;
            As[(kk + 1) * 68 + m] = av.y;
            As[(kk + 2) * 68 + m] = av.z;
            As[(kk + 3) * 68 + m] = av.w;
        }
#pragma unroll
        for (int i = 0; i < 6; ++i) {
            int p = tid + i * 256;
            int nn = p >> 3, kk = (p & 7) * 4;
            float4 bv = *(const float4*)(Wout + (size_t)nn * 384 + k0 + kk);
            Bs[(kk + 0) * 196 + nn] = bv.x;
            Bs[(kk + 1) * 196 + nn] = bv.y;
            Bs[(kk + 2) * 196 + nn] = bv.z;
            Bs[(kk + 3) * 196 + nn] = bv.w;
        }
        __syncthreads();
        const float4* As4 = (const float4*)As;
        const float4* Bs4 = (const float4*)Bs;
#pragma unroll
        for (int kk = 0; kk < 32; ++kk) {
            float4 a = As4[kk * 17 + ty];
            float ar[4] = {a.x, a.y, a.z, a.w};
#pragma unroll
            for (int g = 0; g < 3; ++g) {
                float4 bq = Bs4[kk * 49 + g * 16 + tx];
                float br[4] = {bq.x, bq.y, bq.z, bq.w};
#pragma unroll
                for (int i = 0; i < 4; ++i)
#pragma unroll
                    for (int j = 0; j < 4; ++j)
                        acc[g][i][j] = fmaf(ar[i], br[j], acc[g][i][j]);
            }
        }
        __syncthreads();
    }
#pragma unroll
    for (int i = 0; i < 4; ++i) {
        int row = bm + ty * 4 + i;
#pragma unroll
        for (int g = 0; g < 3; ++g) {
            float4 v = make_float4(acc[g][i][0], acc[g][i][1], acc[g][i][2], acc[g][i][3]);
            *(float4*)(out + (size_t)row * 192 + g * 64 + tx * 4) = v;
        }
    }
}

extern "C" void kernel_launch(void* const* d_in, const int* in_sizes, int n_in,
                              void* d_out, int out_size, void* d_ws, size_t ws_size,
                              hipStream_t stream) {
    const float* x    = (const float*)d_in[0];
    const float* Win  = (const float*)d_in[1];
    const float* xpw  = (const float*)d_in[2];
    const float* dtw  = (const float*)d_in[3];
    const float* dtb  = (const float*)d_in[4];
    const float* Alog = (const float*)d_in[5];
    const float* Dsv  = (const float*)d_in[6];
    const float* lng  = (const float*)d_in[7];
    const float* lnb  = (const float*)d_in[8];
    const float* Wout = (const float*)d_in[9];
    float* out = (float*)d_out;

    const size_t nU  = (size_t)ROWS * 384;
    const size_t nBC = (size_t)ROWS * 16;
    const size_t nHF = (size_t)8 * 384 * NCHUNK * 16;
    const size_t nS  = (size_t)8 * 384 * NCHUNK;
    const size_t need = (nU * 3 + nBC * 2 + nHF + nS) * sizeof(float);
    if (ws_size < need) return;   // fail visibly (absmax) instead of faulting

    float* u    = (float*)d_ws;
    float* z    = u + nU;
    float* dl   = z + nU;          // delta -> y -> yn (in place)
    float* Bsv  = dl + nU;
    float* Csv  = Bsv + nBC;
    float* hf   = Csv + nBC;
    float* Ssum = hf + nHF;

    k1_gemm_silu<<<dim3(128, 6), 256, 0, stream>>>(x, Win, u, z);
    k2_proj<<<256, 256, 0, stream>>>(u, xpw, dtw, dtb, dl, Bsv, Csv);
    k3a_scan1<<<dim3(24 * NCHUNK, 8), 256, 0, stream>>>(dl, u, Bsv, Alog, hf, Ssum);
    k3b_scan2<<<dim3(24 * NCHUNK, 8), 256, 0, stream>>>(dl, u, Bsv, Csv, Alog, Dsv, hf, Ssum);
    k4_ln_mul<<<4096, 256, 0, stream>>>(dl, z, lng, lnb);
    k5_gemm_out<<<256, 256, 0, stream>>>(dl, Wout, out);
}

// Round 8
// 318.521 us; speedup vs baseline: 2.3799x; 1.1626x over previous
//
#include <hip/hip_runtime.h>
#include <hip/hip_bf16.h>
#include <math.h>

// SS1D (Mamba-like selective scan). GEMMs via split-bf16 MFMA (hi/lo, 3 MFMA).
// B=8, L=2048, DM=192, DI=384, N=16, R=12. Rows = B*L = 16384.

#define ROWS 16384
#define NCHUNK 16
#define CLEN 128

typedef short bf16x8 __attribute__((ext_vector_type(8)));
typedef float f32x4 __attribute__((ext_vector_type(4)));

__device__ __forceinline__ unsigned short f2bf(float f) {
    unsigned u = __float_as_uint(f);
    return (unsigned short)((u + 0x7fffu + ((u >> 16) & 1u)) >> 16);
}
__device__ __forceinline__ float bf2f(unsigned short h) {
    return __uint_as_float(((unsigned)h) << 16);
}

// DPP row-rotate-add: 16-lane row sum (one n-group). Full-rate VALU.
template <int CTRL>
__device__ __forceinline__ float ror_add(float x) {
    int y = __builtin_amdgcn_update_dpp(0, __float_as_int(x), CTRL, 0xF, 0xF, true);
    return x + __int_as_float(y);
}
__device__ __forceinline__ float row16_sum(float p) {
    p = ror_add<0x128>(p);
    p = ror_add<0x124>(p);
    p = ror_add<0x122>(p);
    p = ror_add<0x121>(p);
    return p;
}

// ---------------- K1: xz = silu(x @ W_in^T) -> u, z (split-bf16 MFMA) ----------------
// M=16384, N=768, K=192. BM=128, BN=128, BK=32. 4 waves 2x2, wave tile 64x64.
#define LDK 40   // padded row length in shorts (80B stride: 16B-aligned, 2-way banks)
__global__ __launch_bounds__(256) void k1_gemm_silu(
    const float* __restrict__ x, const float* __restrict__ Win,
    float* __restrict__ u, float* __restrict__ z)
{
    __shared__ short Ah[128 * LDK];
    __shared__ short Al[128 * LDK];
    __shared__ short Bh[128 * LDK];
    __shared__ short Bl[128 * LDK];
    const int tid = threadIdx.x;
    const int lane = tid & 63;
    const int w = tid >> 6;
    const int wr = w >> 1, wc = w & 1;
    const int bm = blockIdx.x * 128;
    const int bn = blockIdx.y * 128;   // 0..255 -> u, 384.. -> z (128 | 384)

    f32x4 acc[4][4];
#pragma unroll
    for (int i = 0; i < 4; ++i)
#pragma unroll
        for (int j = 0; j < 4; ++j) acc[i][j] = (f32x4)0.f;

    const int r16 = lane & 15, q4 = lane >> 4;

    for (int k0 = 0; k0 < 192; k0 += 32) {
        // stage A and B tiles as hi/lo bf16, [row][k] with LDK pad
#pragma unroll
        for (int i = 0; i < 4; ++i) {
            int p = tid + i * 256;           // 0..1023 float4s
            int r = p >> 3, k4 = (p & 7) * 4;
            float4 av = *(const float4*)(x + (size_t)(bm + r) * 192 + k0 + k4);
            unsigned short hx = f2bf(av.x), hy = f2bf(av.y), hz = f2bf(av.z), hw = f2bf(av.w);
            unsigned hi0 = (unsigned)hx | ((unsigned)hy << 16);
            unsigned hi1 = (unsigned)hz | ((unsigned)hw << 16);
            unsigned short lx = f2bf(av.x - bf2f(hx)), ly = f2bf(av.y - bf2f(hy));
            unsigned short lz = f2bf(av.z - bf2f(hz)), lw = f2bf(av.w - bf2f(hw));
            unsigned lo0 = (unsigned)lx | ((unsigned)ly << 16);
            unsigned lo1 = (unsigned)lz | ((unsigned)lw << 16);
            int wi = r * (LDK / 2) + (k4 >> 1);
            ((unsigned*)Ah)[wi] = hi0; ((unsigned*)Ah)[wi + 1] = hi1;
            ((unsigned*)Al)[wi] = lo0; ((unsigned*)Al)[wi + 1] = lo1;

            float4 bv = *(const float4*)(Win + (size_t)(bn + r) * 192 + k0 + k4);
            hx = f2bf(bv.x); hy = f2bf(bv.y); hz = f2bf(bv.z); hw = f2bf(bv.w);
            hi0 = (unsigned)hx | ((unsigned)hy << 16);
            hi1 = (unsigned)hz | ((unsigned)hw << 16);
            lx = f2bf(bv.x - bf2f(hx)); ly = f2bf(bv.y - bf2f(hy));
            lz = f2bf(bv.z - bf2f(hz)); lw = f2bf(bv.w - bf2f(hw));
            lo0 = (unsigned)lx | ((unsigned)ly << 16);
            lo1 = (unsigned)lz | ((unsigned)lw << 16);
            ((unsigned*)Bh)[wi] = hi0; ((unsigned*)Bh)[wi + 1] = hi1;
            ((unsigned*)Bl)[wi] = lo0; ((unsigned*)Bl)[wi + 1] = lo1;
        }
        __syncthreads();

        // A fragments (hoisted): rows wr*64 + mt*16 + r16, k = q4*8..+7
        bf16x8 ah[4], al[4];
#pragma unroll
        for (int mt = 0; mt < 4; ++mt) {
            int off = (wr * 64 + mt * 16 + r16) * LDK + q4 * 8;
            ah[mt] = *(const bf16x8*)(Ah + off);
            al[mt] = *(const bf16x8*)(Al + off);
        }
#pragma unroll
        for (int nt = 0; nt < 4; ++nt) {
            int off = (wc * 64 + nt * 16 + r16) * LDK + q4 * 8;
            bf16x8 bh = *(const bf16x8*)(Bh + off);
            bf16x8 bl = *(const bf16x8*)(Bl + off);
#pragma unroll
            for (int mt = 0; mt < 4; ++mt) {
                acc[mt][nt] = __builtin_amdgcn_mfma_f32_16x16x32_bf16(ah[mt], bh, acc[mt][nt], 0, 0, 0);
                acc[mt][nt] = __builtin_amdgcn_mfma_f32_16x16x32_bf16(ah[mt], bl, acc[mt][nt], 0, 0, 0);
                acc[mt][nt] = __builtin_amdgcn_mfma_f32_16x16x32_bf16(al[mt], bh, acc[mt][nt], 0, 0, 0);
            }
        }
        __syncthreads();
    }

    // epilogue: silu, split u/z. C/D: col=lane&15, row=(lane>>4)*4+reg.
    float* dst = (bn < 384) ? u : z;
    const int col0 = (bn < 384) ? bn : (bn - 384);
#pragma unroll
    for (int mt = 0; mt < 4; ++mt) {
#pragma unroll
        for (int nt = 0; nt < 4; ++nt) {
            int col = col0 + wc * 64 + nt * 16 + r16;
#pragma unroll
            for (int r = 0; r < 4; ++r) {
                int row = bm + wr * 64 + mt * 16 + q4 * 4 + r;
                float s = acc[mt][nt][r];
                dst[(size_t)row * 384 + col] = s / (1.f + __expf(-s));
            }
        }
    }
}

// ------- K2: dbl = u @ xpw^T (44 cols); delta = softplus(dbl[:,:12] @ dtw^T + b); B, C -------
__global__ __launch_bounds__(256) void k2_proj(
    const float* __restrict__ u, const float* __restrict__ xpw,
    const float* __restrict__ dtw, const float* __restrict__ dtb,
    float* __restrict__ delta, float* __restrict__ Bso, float* __restrict__ Cso)
{
    __shared__ float As[64 * 68];
    __shared__ float Bs[64 * 53];
    __shared__ float dtwS[384 * 13];
    __shared__ float dblS[64 * 13];
    const int tid = threadIdx.x;
    const int tx = tid & 15, ty = tid >> 4;
    const int row0 = blockIdx.x * 64;

#pragma unroll
    for (int i = 0; i < 5; ++i) {
        int p = tid + i * 256;
        if (p < 1152) {
            int dd = p / 3, q = (p % 3) * 4;
            float4 v = *(const float4*)(dtw + dd * 12 + q);
            dtwS[dd * 13 + q + 0] = v.x;
            dtwS[dd * 13 + q + 1] = v.y;
            dtwS[dd * 13 + q + 2] = v.z;
            dtwS[dd * 13 + q + 3] = v.w;
        }
    }

    float acc[4][3];
#pragma unroll
    for (int i = 0; i < 4; ++i)
#pragma unroll
        for (int g = 0; g < 3; ++g) acc[i][g] = 0.f;

    for (int k0 = 0; k0 < 384; k0 += 64) {
#pragma unroll
        for (int i = 0; i < 4; ++i) {
            int p = tid + i * 256;
            int r = p >> 4, k4 = (p & 15) * 4;
            float4 v = *(const float4*)(u + (size_t)(row0 + r) * 384 + k0 + k4);
            As[(k4 + 0) * 68 + r] = v.x;
            As[(k4 + 1) * 68 + r] = v.y;
            As[(k4 + 2) * 68 + r] = v.z;
            As[(k4 + 3) * 68 + r] = v.w;
        }
#pragma unroll
        for (int i = 0; i < 3; ++i) {
            int p = tid + i * 256;
            int c = p >> 4, k4 = (p & 15) * 4;
            float4 v = make_float4(0.f, 0.f, 0.f, 0.f);
            if (c < 44) v = *(const float4*)(xpw + (size_t)c * 384 + k0 + k4);
            Bs[(k4 + 0) * 53 + c] = v.x;
            Bs[(k4 + 1) * 53 + c] = v.y;
            Bs[(k4 + 2) * 53 + c] = v.z;
            Bs[(k4 + 3) * 53 + c] = v.w;
        }
        __syncthreads();
#pragma unroll 8
        for (int kk = 0; kk < 64; ++kk) {
            float4 a = *(const float4*)(As + kk * 68 + ty * 4);
            float b0 = Bs[kk * 53 + tx];
            float b1 = Bs[kk * 53 + tx + 16];
            float b2 = Bs[kk * 53 + tx + 32];
            acc[0][0] = fmaf(a.x, b0, acc[0][0]);
            acc[1][0] = fmaf(a.y, b0, acc[1][0]);
            acc[2][0] = fmaf(a.z, b0, acc[2][0]);
            acc[3][0] = fmaf(a.w, b0, acc[3][0]);
            acc[0][1] = fmaf(a.x, b1, acc[0][1]);
            acc[1][1] = fmaf(a.y, b1, acc[1][1]);
            acc[2][1] = fmaf(a.z, b1, acc[2][1]);
            acc[3][1] = fmaf(a.w, b1, acc[3][1]);
            acc[0][2] = fmaf(a.x, b2, acc[0][2]);
            acc[1][2] = fmaf(a.y, b2, acc[1][2]);
            acc[2][2] = fmaf(a.z, b2, acc[2][2]);
            acc[3][2] = fmaf(a.w, b2, acc[3][2]);
        }
        __syncthreads();
    }

#pragma unroll
    for (int i = 0; i < 4; ++i) {
        int lr = ty * 4 + i;
        int row = row0 + lr;
#pragma unroll
        for (int g = 0; g < 3; ++g) {
            int c = g * 16 + tx;
            float s = acc[i][g];
            if (c < 12)      dblS[lr * 13 + c] = s;
            else if (c < 28) Bso[(size_t)row * 16 + (c - 12)] = s;
            else if (c < 44) Cso[(size_t)row * 16 + (c - 28)] = s;
        }
    }
    __syncthreads();

    for (int it = 0; it < 96; ++it) {
        int o = it * 256 + tid;
        int r = o / 384, d = o - r * 384;
        float s = dtb[d];
        const float* wr = dtwS + d * 13;
        const float* db = dblS + r * 13;
#pragma unroll
        for (int j = 0; j < 12; ++j) s = fmaf(db[j], wr[j], s);
        float sp = (s > 20.f) ? s : log1pf(__expf(s));
        delta[(size_t)(row0 + r) * 384 + d] = sp;
    }
}

// ---------------- K3a: scan pass 1 — per-chunk local scan summaries ----------------
__global__ __launch_bounds__(256) void k3a_scan1(
    const float* __restrict__ delta, const float* __restrict__ u,
    const float* __restrict__ Bsv, const float* __restrict__ A_logs,
    float* __restrict__ hf, float* __restrict__ Ssum)
{
    const int tid = threadIdx.x;
    const int n = tid & 15, dl = tid >> 4;
    const int c  = blockIdx.x & 15;
    const int dt = blockIdx.x >> 4;
    const int b  = blockIdx.y;
    const int d  = dt * 16 + dl;
    const int t0 = c * CLEN;

    const float Acoef = -__expf(A_logs[d * 16 + n]);
    const float* dp = delta + ((size_t)b * 2048 + t0) * 384 + d;
    const float* up = u     + ((size_t)b * 2048 + t0) * 384 + d;
    const float* Bp = Bsv   + ((size_t)b * 2048 + t0) * 16 + n;

    float pdt[8], put[8], pB[8];
#pragma unroll
    for (int i = 0; i < 8; ++i) {
        pdt[i] = dp[(size_t)i * 384]; put[i] = up[(size_t)i * 384]; pB[i] = Bp[i * 16];
    }

    float h = 0.f, S = 0.f;
    for (int g = 0; g < CLEN; g += 8) {
        float cdt[8], cut[8], cB[8];
#pragma unroll
        for (int i = 0; i < 8; ++i) { cdt[i] = pdt[i]; cut[i] = put[i]; cB[i] = pB[i]; }
        dp += 8 * 384; up += 8 * 384; Bp += 8 * 16;
        if (g + 8 < CLEN) {
#pragma unroll
            for (int i = 0; i < 8; ++i) {
                pdt[i] = dp[(size_t)i * 384]; put[i] = up[(size_t)i * 384]; pB[i] = Bp[i * 16];
            }
        }
        __builtin_amdgcn_sched_barrier(0);   // prefetch must issue before compute
#pragma unroll
        for (int i = 0; i < 8; ++i) {
            float dv = cdt[i];
            float a = __expf(dv * Acoef);
            h = fmaf(a, h, dv * cut[i] * cB[i]);
            S += dv;
        }
    }
    hf[(((size_t)b * 384 + d) * NCHUNK + c) * 16 + n] = h;
    if (n == 0) Ssum[((size_t)b * 384 + d) * NCHUNK + c] = S;
}

// ---------------- K3b: scan pass 2 — combine summaries, rescan, emit y ----------------
__global__ __launch_bounds__(256) void k3b_scan2(
    float* __restrict__ dy, const float* __restrict__ u,
    const float* __restrict__ Bsv, const float* __restrict__ Csv,
    const float* __restrict__ A_logs, const float* __restrict__ Ds,
    const float* __restrict__ hf, const float* __restrict__ Ssum)
{
    const int tid = threadIdx.x;
    const int n = tid & 15, dl = tid >> 4;
    const int c  = blockIdx.x & 15;
    const int dt = blockIdx.x >> 4;
    const int b  = blockIdx.y;
    const int d  = dt * 16 + dl;
    const int t0 = c * CLEN;

    const float Acoef = -__expf(A_logs[d * 16 + n]);
    const float Dd = Ds[d];

    float h = 0.f;
    {
        const float* hfp = hf + (((size_t)b * 384 + d) * NCHUNK) * 16 + n;
        const float* Sp  = Ssum + ((size_t)b * 384 + d) * NCHUNK;
        for (int j = 0; j < c; ++j) {
            float P = __expf(Acoef * Sp[j]);
            h = fmaf(P, h, hfp[j * 16]);
        }
    }

    float* yp       = dy  + ((size_t)b * 2048 + t0) * 384 + d;
    const float* up = u   + ((size_t)b * 2048 + t0) * 384 + d;
    const float* Bp = Bsv + ((size_t)b * 2048 + t0) * 16 + n;
    const float* Cp = Csv + ((size_t)b * 2048 + t0) * 16 + n;

    float pdt[8], put[8], pB[8], pC[8];
#pragma unroll
    for (int i = 0; i < 8; ++i) {
        pdt[i] = yp[(size_t)i * 384]; put[i] = up[(size_t)i * 384];
        pB[i] = Bp[i * 16];           pC[i] = Cp[i * 16];
    }
    const float* dp = yp + 8 * 384;
    float* yq = yp;

    for (int g = 0; g < CLEN; g += 8) {
        float cdt[8], cut[8], cB[8], cC[8];
#pragma unroll
        for (int i = 0; i < 8; ++i) { cdt[i] = pdt[i]; cut[i] = put[i]; cB[i] = pB[i]; cC[i] = pC[i]; }
        up += 8 * 384; Bp += 8 * 16; Cp += 8 * 16;
        if (g + 8 < CLEN) {
#pragma unroll
            for (int i = 0; i < 8; ++i) {
                pdt[i] = dp[(size_t)i * 384]; put[i] = up[(size_t)i * 384];
                pB[i] = Bp[i * 16];           pC[i] = Cp[i * 16];
            }
        }
        dp += 8 * 384;
        __builtin_amdgcn_sched_barrier(0);   // prefetch must issue before compute
#pragma unroll
        for (int i = 0; i < 8; ++i) {
            float dv = cdt[i];
            float a = __expf(dv * Acoef);
            h = fmaf(a, h, dv * cut[i] * cB[i]);
            float p = row16_sum(h * cC[i]);
            if (n == 0) yq[(size_t)i * 384] = fmaf(Dd, cut[i], p);
        }
        yq += 8 * 384;
    }
}

// ---------------- K4: LayerNorm over DI, then * z (in place on y) ----------------
__global__ __launch_bounds__(256) void k4_ln_mul(
    float* __restrict__ y, const float* __restrict__ z,
    const float* __restrict__ gamma, const float* __restrict__ beta)
{
    const int tid = threadIdx.x;
    const int lane = tid & 63;
    const int w = tid >> 6;
    const size_t row = (size_t)blockIdx.x * 4 + w;
    float* yr = y + row * 384;
    const float* zr = z + row * 384;
    float v[6];
    float s1 = 0.f, s2 = 0.f;
#pragma unroll
    for (int j = 0; j < 6; ++j) {
        v[j] = yr[lane + j * 64];
        s1 += v[j];
        s2 = fmaf(v[j], v[j], s2);
    }
#pragma unroll
    for (int off = 32; off > 0; off >>= 1) {
        s1 += __shfl_xor(s1, off);
        s2 += __shfl_xor(s2, off);
    }
    float mu = s1 * (1.f / 384.f);
    float var = s2 * (1.f / 384.f) - mu * mu;
    float rs = rsqrtf(var + 1e-5f);
#pragma unroll
    for (int j = 0; j < 6; ++j) {
        int d = lane + j * 64;
        float o = (v[j] - mu) * rs * gamma[d] + beta[d];
        yr[d] = o * zr[d];
    }
}

// ---------------- K5: out = yn @ W_out^T (split-bf16 MFMA) ----------------
// M=16384, N=192, K=384. BM=128, BN=64, BK=32. 4 waves 2x2, wave tile 64x32.
// grid = dim3(M/128 = 128, N/64 = 3)
__global__ __launch_bounds__(256) void k5_gemm_out(
    const float* __restrict__ yn, const float* __restrict__ Wout,
    float* __restrict__ out)
{
    __shared__ short Ah[128 * LDK];
    __shared__ short Al[128 * LDK];
    __shared__ short Bh[64 * LDK];
    __shared__ short Bl[64 * LDK];
    const int tid = threadIdx.x;
    const int lane = tid & 63;
    const int w = tid >> 6;
    const int wr = w >> 1, wc = w & 1;
    const int bm = blockIdx.x * 128;
    const int bn = blockIdx.y * 64;

    f32x4 acc[4][2];
#pragma unroll
    for (int i = 0; i < 4; ++i)
#pragma unroll
        for (int j = 0; j < 2; ++j) acc[i][j] = (f32x4)0.f;

    const int r16 = lane & 15, q4 = lane >> 4;

    for (int k0 = 0; k0 < 384; k0 += 32) {
#pragma unroll
        for (int i = 0; i < 4; ++i) {
            int p = tid + i * 256;           // 0..1023: A tile 128x32
            int r = p >> 3, k4 = (p & 7) * 4;
            float4 av = *(const float4*)(yn + (size_t)(bm + r) * 384 + k0 + k4);
            unsigned short hx = f2bf(av.x), hy = f2bf(av.y), hz = f2bf(av.z), hw = f2bf(av.w);
            unsigned hi0 = (unsigned)hx | ((unsigned)hy << 16);
            unsigned hi1 = (unsigned)hz | ((unsigned)hw << 16);
            unsigned short lx = f2bf(av.x - bf2f(hx)), ly = f2bf(av.y - bf2f(hy));
            unsigned short lz = f2bf(av.z - bf2f(hz)), lw = f2bf(av.w - bf2f(hw));
            unsigned lo0 = (unsigned)lx | ((unsigned)ly << 16);
            unsigned lo1 = (unsigned)lz | ((unsigned)lw << 16);
            int wi = r * (LDK / 2) + (k4 >> 1);
            ((unsigned*)Ah)[wi] = hi0; ((unsigned*)Ah)[wi + 1] = hi1;
            ((unsigned*)Al)[wi] = lo0; ((unsigned*)Al)[wi + 1] = lo1;
        }
#pragma unroll
        for (int i = 0; i < 2; ++i) {
            int p = tid + i * 256;           // 0..511: B tile 64x32
            int r = p >> 3, k4 = (p & 7) * 4;
            float4 bv = *(const float4*)(Wout + (size_t)(bn + r) * 384 + k0 + k4);
            unsigned short hx = f2bf(bv.x), hy = f2bf(bv.y), hz = f2bf(bv.z), hw = f2bf(bv.w);
            unsigned hi0 = (unsigned)hx | ((unsigned)hy << 16);
            unsigned hi1 = (unsigned)hz | ((unsigned)hw << 16);
            unsigned short lx = f2bf(bv.x - bf2f(hx)), ly = f2bf(bv.y - bf2f(hy));
            unsigned short lz = f2bf(bv.z - bf2f(hz)), lw = f2bf(bv.w - bf2f(hw));
            unsigned lo0 = (unsigned)lx | ((unsigned)ly << 16);
            unsigned lo1 = (unsigned)lz | ((unsigned)lw << 16);
            int wi = r * (LDK / 2) + (k4 >> 1);
            ((unsigned*)Bh)[wi] = hi0; ((unsigned*)Bh)[wi + 1] = hi1;
            ((unsigned*)Bl)[wi] = lo0; ((unsigned*)Bl)[wi + 1] = lo1;
        }
        __syncthreads();

        bf16x8 ah[4], al[4];
#pragma unroll
        for (int mt = 0; mt < 4; ++mt) {
            int off = (wr * 64 + mt * 16 + r16) * LDK + q4 * 8;
            ah[mt] = *(const bf16x8*)(Ah + off);
            al[mt] = *(const bf16x8*)(Al + off);
        }
#pragma unroll
        for (int nt = 0; nt < 2; ++nt) {
            int off = (wc * 32 + nt * 16 + r16) * LDK + q4 * 8;
            bf16x8 bh = *(const bf16x8*)(Bh + off);
            bf16x8 bl = *(const bf16x8*)(Bl + off);
#pragma unroll
            for (int mt = 0; mt < 4; ++mt) {
                acc[mt][nt] = __builtin_amdgcn_mfma_f32_16x16x32_bf16(ah[mt], bh, acc[mt][nt], 0, 0, 0);
                acc[mt][nt] = __builtin_amdgcn_mfma_f32_16x16x32_bf16(ah[mt], bl, acc[mt][nt], 0, 0, 0);
                acc[mt][nt] = __builtin_amdgcn_mfma_f32_16x16x32_bf16(al[mt], bh, acc[mt][nt], 0, 0, 0);
            }
        }
        __syncthreads();
    }

#pragma unroll
    for (int mt = 0; mt < 4; ++mt) {
#pragma unroll
        for (int nt = 0; nt < 2; ++nt) {
            int col = bn + wc * 32 + nt * 16 + r16;
#pragma unroll
            for (int r = 0; r < 4; ++r) {
                int row = bm + wr * 64 + mt * 16 + q4 * 4 + r;
                out[(size_t)row * 192 + col] = acc[mt][nt][r];
            }
        }
    }
}

extern "C" void kernel_launch(void* const* d_in, const int* in_sizes, int n_in,
                              void* d_out, int out_size, void* d_ws, size_t ws_size,
                              hipStream_t stream) {
    const float* x    = (const float*)d_in[0];
    const float* Win  = (const float*)d_in[1];
    const float* xpw  = (const float*)d_in[2];
    const float* dtw  = (const float*)d_in[3];
    const float* dtb  = (const float*)d_in[4];
    const float* Alog = (const float*)d_in[5];
    const float* Dsv  = (const float*)d_in[6];
    const float* lng  = (const float*)d_in[7];
    const float* lnb  = (const float*)d_in[8];
    const float* Wout = (const float*)d_in[9];
    float* out = (float*)d_out;

    const size_t nU  = (size_t)ROWS * 384;
    const size_t nBC = (size_t)ROWS * 16;
    const size_t nHF = (size_t)8 * 384 * NCHUNK * 16;
    const size_t nS  = (size_t)8 * 384 * NCHUNK;
    const size_t need = (nU * 3 + nBC * 2 + nHF + nS) * sizeof(float);
    if (ws_size < need) return;   // fail visibly (absmax) instead of faulting

    float* u    = (float*)d_ws;
    float* z    = u + nU;
    float* dl   = z + nU;          // delta -> y -> yn (in place)
    float* Bsv  = dl + nU;
    float* Csv  = Bsv + nBC;
    float* hf   = Csv + nBC;
    float* Ssum = hf + nHF;

    k1_gemm_silu<<<dim3(128, 6), 256, 0, stream>>>(x, Win, u, z);
    k2_proj<<<256, 256, 0, stream>>>(u, xpw, dtw, dtb, dl, Bsv, Csv);
    k3a_scan1<<<dim3(24 * NCHUNK, 8), 256, 0, stream>>>(dl, u, Bsv, Alog, hf, Ssum);
    k3b_scan2<<<dim3(24 * NCHUNK, 8), 256, 0, stream>>>(dl, u, Bsv, Csv, Alog, Dsv, hf, Ssum);
    k4_ln_mul<<<4096, 256, 0, stream>>>(dl, z, lng, lnb);
    k5_gemm_out<<<dim3(128, 3), 256, 0, stream>>>(dl, Wout, out);
}

// Round 9
// 300.915 us; speedup vs baseline: 2.5192x; 1.0585x over previous
//
#include <hip/hip_runtime.h>
#include <hip/hip_bf16.h>
#include <math.h>

// SS1D (Mamba-like selective scan). GEMMs via split-bf16 MFMA (hi/lo, 3 MFMA).
// Scan: lane=channel packing, 16 states in registers, 64 chunks of 32 steps.
// B=8, L=2048, DM=192, DI=384, N=16, R=12. Rows = B*L = 16384.

#define ROWS 16384
#define NCHUNK 64
#define CLEN 32

typedef short bf16x8 __attribute__((ext_vector_type(8)));
typedef float f32x4 __attribute__((ext_vector_type(4)));

__device__ __forceinline__ unsigned short f2bf(float f) {
    unsigned u = __float_as_uint(f);
    return (unsigned short)((u + 0x7fffu + ((u >> 16) & 1u)) >> 16);
}
__device__ __forceinline__ float bf2f(unsigned short h) {
    return __uint_as_float(((unsigned)h) << 16);
}

#define LOG2E 1.44269504088896f

// ---------------- K1: xz = silu(x @ W_in^T) -> u, z (split-bf16 MFMA) ----------------
// M=16384, N=768, K=192. BM=128, BN=128, BK=32. 4 waves 2x2, wave tile 64x64.
#define LDK 40   // padded row length in shorts (80B stride: 16B-aligned, 2-way banks)
__global__ __launch_bounds__(256) void k1_gemm_silu(
    const float* __restrict__ x, const float* __restrict__ Win,
    float* __restrict__ u, float* __restrict__ z)
{
    __shared__ short Ah[128 * LDK];
    __shared__ short Al[128 * LDK];
    __shared__ short Bh[128 * LDK];
    __shared__ short Bl[128 * LDK];
    const int tid = threadIdx.x;
    const int lane = tid & 63;
    const int w = tid >> 6;
    const int wr = w >> 1, wc = w & 1;
    const int bm = blockIdx.x * 128;
    const int bn = blockIdx.y * 128;

    f32x4 acc[4][4];
#pragma unroll
    for (int i = 0; i < 4; ++i)
#pragma unroll
        for (int j = 0; j < 4; ++j) acc[i][j] = (f32x4)0.f;

    const int r16 = lane & 15, q4 = lane >> 4;

    for (int k0 = 0; k0 < 192; k0 += 32) {
#pragma unroll
        for (int i = 0; i < 4; ++i) {
            int p = tid + i * 256;
            int r = p >> 3, k4 = (p & 7) * 4;
            float4 av = *(const float4*)(x + (size_t)(bm + r) * 192 + k0 + k4);
            unsigned short hx = f2bf(av.x), hy = f2bf(av.y), hz = f2bf(av.z), hw = f2bf(av.w);
            unsigned hi0 = (unsigned)hx | ((unsigned)hy << 16);
            unsigned hi1 = (unsigned)hz | ((unsigned)hw << 16);
            unsigned short lx = f2bf(av.x - bf2f(hx)), ly = f2bf(av.y - bf2f(hy));
            unsigned short lz = f2bf(av.z - bf2f(hz)), lw = f2bf(av.w - bf2f(hw));
            unsigned lo0 = (unsigned)lx | ((unsigned)ly << 16);
            unsigned lo1 = (unsigned)lz | ((unsigned)lw << 16);
            int wi = r * (LDK / 2) + (k4 >> 1);
            ((unsigned*)Ah)[wi] = hi0; ((unsigned*)Ah)[wi + 1] = hi1;
            ((unsigned*)Al)[wi] = lo0; ((unsigned*)Al)[wi + 1] = lo1;

            float4 bv = *(const float4*)(Win + (size_t)(bn + r) * 192 + k0 + k4);
            hx = f2bf(bv.x); hy = f2bf(bv.y); hz = f2bf(bv.z); hw = f2bf(bv.w);
            hi0 = (unsigned)hx | ((unsigned)hy << 16);
            hi1 = (unsigned)hz | ((unsigned)hw << 16);
            lx = f2bf(bv.x - bf2f(hx)); ly = f2bf(bv.y - bf2f(hy));
            lz = f2bf(bv.z - bf2f(hz)); lw = f2bf(bv.w - bf2f(hw));
            lo0 = (unsigned)lx | ((unsigned)ly << 16);
            lo1 = (unsigned)lz | ((unsigned)lw << 16);
            ((unsigned*)Bh)[wi] = hi0; ((unsigned*)Bh)[wi + 1] = hi1;
            ((unsigned*)Bl)[wi] = lo0; ((unsigned*)Bl)[wi + 1] = lo1;
        }
        __syncthreads();

        bf16x8 ah[4], al[4];
#pragma unroll
        for (int mt = 0; mt < 4; ++mt) {
            int off = (wr * 64 + mt * 16 + r16) * LDK + q4 * 8;
            ah[mt] = *(const bf16x8*)(Ah + off);
            al[mt] = *(const bf16x8*)(Al + off);
        }
#pragma unroll
        for (int nt = 0; nt < 4; ++nt) {
            int off = (wc * 64 + nt * 16 + r16) * LDK + q4 * 8;
            bf16x8 bh = *(const bf16x8*)(Bh + off);
            bf16x8 bl = *(const bf16x8*)(Bl + off);
#pragma unroll
            for (int mt = 0; mt < 4; ++mt) {
                acc[mt][nt] = __builtin_amdgcn_mfma_f32_16x16x32_bf16(ah[mt], bh, acc[mt][nt], 0, 0, 0);
                acc[mt][nt] = __builtin_amdgcn_mfma_f32_16x16x32_bf16(ah[mt], bl, acc[mt][nt], 0, 0, 0);
                acc[mt][nt] = __builtin_amdgcn_mfma_f32_16x16x32_bf16(al[mt], bh, acc[mt][nt], 0, 0, 0);
            }
        }
        __syncthreads();
    }

    float* dst = (bn < 384) ? u : z;
    const int col0 = (bn < 384) ? bn : (bn - 384);
#pragma unroll
    for (int mt = 0; mt < 4; ++mt) {
#pragma unroll
        for (int nt = 0; nt < 4; ++nt) {
            int col = col0 + wc * 64 + nt * 16 + r16;
#pragma unroll
            for (int r = 0; r < 4; ++r) {
                int row = bm + wr * 64 + mt * 16 + q4 * 4 + r;
                float s = acc[mt][nt][r];
                dst[(size_t)row * 384 + col] = s / (1.f + __expf(-s));
            }
        }
    }
}

// ------- K2: dbl = u @ xpw^T (44 cols); delta = softplus(dbl[:,:12] @ dtw^T + b); B, C -------
__global__ __launch_bounds__(256) void k2_proj(
    const float* __restrict__ u, const float* __restrict__ xpw,
    const float* __restrict__ dtw, const float* __restrict__ dtb,
    float* __restrict__ delta, float* __restrict__ Bso, float* __restrict__ Cso)
{
    __shared__ float As[64 * 68];
    __shared__ float Bs[64 * 53];
    __shared__ float dtwS[384 * 13];
    __shared__ float dblS[64 * 13];
    const int tid = threadIdx.x;
    const int tx = tid & 15, ty = tid >> 4;
    const int row0 = blockIdx.x * 64;

#pragma unroll
    for (int i = 0; i < 5; ++i) {
        int p = tid + i * 256;
        if (p < 1152) {
            int dd = p / 3, q = (p % 3) * 4;
            float4 v = *(const float4*)(dtw + dd * 12 + q);
            dtwS[dd * 13 + q + 0] = v.x;
            dtwS[dd * 13 + q + 1] = v.y;
            dtwS[dd * 13 + q + 2] = v.z;
            dtwS[dd * 13 + q + 3] = v.w;
        }
    }

    float acc[4][3];
#pragma unroll
    for (int i = 0; i < 4; ++i)
#pragma unroll
        for (int g = 0; g < 3; ++g) acc[i][g] = 0.f;

    for (int k0 = 0; k0 < 384; k0 += 64) {
#pragma unroll
        for (int i = 0; i < 4; ++i) {
            int p = tid + i * 256;
            int r = p >> 4, k4 = (p & 15) * 4;
            float4 v = *(const float4*)(u + (size_t)(row0 + r) * 384 + k0 + k4);
            As[(k4 + 0) * 68 + r] = v.x;
            As[(k4 + 1) * 68 + r] = v.y;
            As[(k4 + 2) * 68 + r] = v.z;
            As[(k4 + 3) * 68 + r] = v.w;
        }
#pragma unroll
        for (int i = 0; i < 3; ++i) {
            int p = tid + i * 256;
            int c = p >> 4, k4 = (p & 15) * 4;
            float4 v = make_float4(0.f, 0.f, 0.f, 0.f);
            if (c < 44) v = *(const float4*)(xpw + (size_t)c * 384 + k0 + k4);
            Bs[(k4 + 0) * 53 + c] = v.x;
            Bs[(k4 + 1) * 53 + c] = v.y;
            Bs[(k4 + 2) * 53 + c] = v.z;
            Bs[(k4 + 3) * 53 + c] = v.w;
        }
        __syncthreads();
#pragma unroll 8
        for (int kk = 0; kk < 64; ++kk) {
            float4 a = *(const float4*)(As + kk * 68 + ty * 4);
            float b0 = Bs[kk * 53 + tx];
            float b1 = Bs[kk * 53 + tx + 16];
            float b2 = Bs[kk * 53 + tx + 32];
            acc[0][0] = fmaf(a.x, b0, acc[0][0]);
            acc[1][0] = fmaf(a.y, b0, acc[1][0]);
            acc[2][0] = fmaf(a.z, b0, acc[2][0]);
            acc[3][0] = fmaf(a.w, b0, acc[3][0]);
            acc[0][1] = fmaf(a.x, b1, acc[0][1]);
            acc[1][1] = fmaf(a.y, b1, acc[1][1]);
            acc[2][1] = fmaf(a.z, b1, acc[2][1]);
            acc[3][1] = fmaf(a.w, b1, acc[3][1]);
            acc[0][2] = fmaf(a.x, b2, acc[0][2]);
            acc[1][2] = fmaf(a.y, b2, acc[1][2]);
            acc[2][2] = fmaf(a.z, b2, acc[2][2]);
            acc[3][2] = fmaf(a.w, b2, acc[3][2]);
        }
        __syncthreads();
    }

#pragma unroll
    for (int i = 0; i < 4; ++i) {
        int lr = ty * 4 + i;
        int row = row0 + lr;
#pragma unroll
        for (int g = 0; g < 3; ++g) {
            int c = g * 16 + tx;
            float s = acc[i][g];
            if (c < 12)      dblS[lr * 13 + c] = s;
            else if (c < 28) Bso[(size_t)row * 16 + (c - 12)] = s;
            else if (c < 44) Cso[(size_t)row * 16 + (c - 28)] = s;
        }
    }
    __syncthreads();

    for (int it = 0; it < 96; ++it) {
        int o = it * 256 + tid;
        int r = o / 384, d = o - r * 384;
        float s = dtb[d];
        const float* wr = dtwS + d * 13;
        const float* db = dblS + r * 13;
#pragma unroll
        for (int j = 0; j < 12; ++j) s = fmaf(db[j], wr[j], s);
        float sp = (s > 20.f) ? s : log1pf(__expf(s));
        delta[(size_t)(row0 + r) * 384 + d] = sp;
    }
}

// ---------------- K3a: per-chunk local scan, lane=d, h[16] in registers ----------------
// block = 384 thr = 6 waves (one per 64-d tile). grid = (NCHUNK, B).
// Writes hf[b][c][d][0..15] (local final state) and Ssum[b][c][d].
__global__ __launch_bounds__(384) void k3a_scan1(
    const float* __restrict__ delta, const float* __restrict__ u,
    const float* __restrict__ Bsv, const float* __restrict__ A_logs,
    float* __restrict__ hf, float* __restrict__ Ssum)
{
    const int tid = threadIdx.x;
    const int lane = tid & 63;
    const int wv = tid >> 6;          // dtile 0..5
    const int c = blockIdx.x;
    const int b = blockIdx.y;
    const int d = wv * 64 + lane;
    const int t0 = c * CLEN;

    // Acoef[n] * log2(e), loop-invariant
    float Ac[16];
    {
#pragma unroll
        for (int q = 0; q < 4; ++q) {
            float4 v = *(const float4*)(A_logs + d * 16 + q * 4);
            Ac[q * 4 + 0] = -__expf(v.x) * LOG2E;
            Ac[q * 4 + 1] = -__expf(v.y) * LOG2E;
            Ac[q * 4 + 2] = -__expf(v.z) * LOG2E;
            Ac[q * 4 + 3] = -__expf(v.w) * LOG2E;
        }
    }

    const float* dp = delta + ((size_t)b * 2048 + t0) * 384 + d;
    const float* up = u     + ((size_t)b * 2048 + t0) * 384 + d;
    const float* Bp = Bsv   + ((size_t)b * 2048 + t0) * 16;   // wave-uniform

    float h[16];
#pragma unroll
    for (int n = 0; n < 16; ++n) h[n] = 0.f;
    float S = 0.f;

    // prefetch step 0
    float dv_n = dp[0], uv_n = up[0];
    float4 B0n = *(const float4*)(Bp + 0);
    float4 B1n = *(const float4*)(Bp + 4);
    float4 B2n = *(const float4*)(Bp + 8);
    float4 B3n = *(const float4*)(Bp + 12);

    for (int s = 0; s < CLEN; ++s) {
        float dv = dv_n, uv = uv_n;
        float4 B0 = B0n, B1 = B1n, B2 = B2n, B3 = B3n;
        if (s + 1 < CLEN) {
            dp += 384; up += 384; Bp += 16;
            dv_n = dp[0]; uv_n = up[0];
            B0n = *(const float4*)(Bp + 0);
            B1n = *(const float4*)(Bp + 4);
            B2n = *(const float4*)(Bp + 8);
            B3n = *(const float4*)(Bp + 12);
        }
        __builtin_amdgcn_sched_barrier(0);
        S += dv;
        float dvu = dv * uv;
        float Br[16] = {B0.x, B0.y, B0.z, B0.w, B1.x, B1.y, B1.z, B1.w,
                        B2.x, B2.y, B2.z, B2.w, B3.x, B3.y, B3.z, B3.w};
#pragma unroll
        for (int n = 0; n < 16; ++n) {
            float a = exp2f(dv * Ac[n]);
            h[n] = fmaf(a, h[n], dvu * Br[n]);
        }
    }

    const size_t ho = (((size_t)b * NCHUNK + c) * 384 + d) * 16;
#pragma unroll
    for (int q = 0; q < 4; ++q)
        *(float4*)(hf + ho + q * 4) = make_float4(h[q*4+0], h[q*4+1], h[q*4+2], h[q*4+3]);
    Ssum[((size_t)b * NCHUNK + c) * 384 + d] = S;
}

// ---------------- K3c: exclusive scan over chunk summaries (in-place hf -> hinit) ----------------
// block = 256 = 16 d x 16 n. grid = (24, B).
__global__ __launch_bounds__(256) void k3c_combine(
    float* __restrict__ hf, const float* __restrict__ Ssum,
    const float* __restrict__ A_logs)
{
    const int tid = threadIdx.x;
    const int n = tid & 15, dl = tid >> 4;
    const int d = blockIdx.x * 16 + dl;
    const int b = blockIdx.y;
    const float Ac = -__expf(A_logs[d * 16 + n]) * LOG2E;

    float h = 0.f;
    for (int c = 0; c < NCHUNK; ++c) {
        const size_t idx = (((size_t)b * NCHUNK + c) * 384 + d) * 16 + n;
        float hfv = hf[idx];
        float Sv  = Ssum[((size_t)b * NCHUNK + c) * 384 + d];
        hf[idx] = h;                       // hinit for chunk c (exclusive)
        float P = exp2f(Ac * Sv);
        h = fmaf(P, h, hfv);
    }
}

// ---------------- K3b: rescan with correct h_init, emit y (in-place on delta) ----------------
__global__ __launch_bounds__(384) void k3b_scan2(
    float* __restrict__ dy, const float* __restrict__ u,
    const float* __restrict__ Bsv, const float* __restrict__ Csv,
    const float* __restrict__ A_logs, const float* __restrict__ Ds,
    const float* __restrict__ hf)
{
    const int tid = threadIdx.x;
    const int lane = tid & 63;
    const int wv = tid >> 6;
    const int c = blockIdx.x;
    const int b = blockIdx.y;
    const int d = wv * 64 + lane;
    const int t0 = c * CLEN;

    float Ac[16];
#pragma unroll
    for (int q = 0; q < 4; ++q) {
        float4 v = *(const float4*)(A_logs + d * 16 + q * 4);
        Ac[q * 4 + 0] = -__expf(v.x) * LOG2E;
        Ac[q * 4 + 1] = -__expf(v.y) * LOG2E;
        Ac[q * 4 + 2] = -__expf(v.z) * LOG2E;
        Ac[q * 4 + 3] = -__expf(v.w) * LOG2E;
    }
    const float Dd = Ds[d];

    float h[16];
    {
        const size_t ho = (((size_t)b * NCHUNK + c) * 384 + d) * 16;
#pragma unroll
        for (int q = 0; q < 4; ++q) {
            float4 v = *(const float4*)(hf + ho + q * 4);
            h[q * 4 + 0] = v.x; h[q * 4 + 1] = v.y;
            h[q * 4 + 2] = v.z; h[q * 4 + 3] = v.w;
        }
    }

    float* yp       = dy  + ((size_t)b * 2048 + t0) * 384 + d;
    const float* up = u   + ((size_t)b * 2048 + t0) * 384 + d;
    const float* Bp = Bsv + ((size_t)b * 2048 + t0) * 16;
    const float* Cp = Csv + ((size_t)b * 2048 + t0) * 16;

    float dv_n = yp[0], uv_n = up[0];
    float4 B0n = *(const float4*)(Bp + 0);
    float4 B1n = *(const float4*)(Bp + 4);
    float4 B2n = *(const float4*)(Bp + 8);
    float4 B3n = *(const float4*)(Bp + 12);
    float4 C0n = *(const float4*)(Cp + 0);
    float4 C1n = *(const float4*)(Cp + 4);
    float4 C2n = *(const float4*)(Cp + 8);
    float4 C3n = *(const float4*)(Cp + 12);
    const float* dpn = yp + 384;

    for (int s = 0; s < CLEN; ++s) {
        float dv = dv_n, uv = uv_n;
        float4 B0 = B0n, B1 = B1n, B2 = B2n, B3 = B3n;
        float4 C0 = C0n, C1 = C1n, C2 = C2n, C3 = C3n;
        if (s + 1 < CLEN) {
            up += 384; Bp += 16; Cp += 16;
            dv_n = dpn[0]; uv_n = up[0];
            B0n = *(const float4*)(Bp + 0);
            B1n = *(const float4*)(Bp + 4);
            B2n = *(const float4*)(Bp + 8);
            B3n = *(const float4*)(Bp + 12);
            C0n = *(const float4*)(Cp + 0);
            C1n = *(const float4*)(Cp + 4);
            C2n = *(const float4*)(Cp + 8);
            C3n = *(const float4*)(Cp + 12);
            dpn += 384;
        }
        __builtin_amdgcn_sched_barrier(0);
        float dvu = dv * uv;
        float Br[16] = {B0.x, B0.y, B0.z, B0.w, B1.x, B1.y, B1.z, B1.w,
                        B2.x, B2.y, B2.z, B2.w, B3.x, B3.y, B3.z, B3.w};
        float Cr[16] = {C0.x, C0.y, C0.z, C0.w, C1.x, C1.y, C1.z, C1.w,
                        C2.x, C2.y, C2.z, C2.w, C3.x, C3.y, C3.z, C3.w};
        float y = Dd * uv;
#pragma unroll
        for (int n = 0; n < 16; ++n) {
            float a = exp2f(dv * Ac[n]);
            h[n] = fmaf(a, h[n], dvu * Br[n]);
            y = fmaf(Cr[n], h[n], y);
        }
        yp[0] = y;
        yp += 384;
    }
}

// ---------------- K4: LayerNorm over DI, then * z (in place on y) ----------------
__global__ __launch_bounds__(256) void k4_ln_mul(
    float* __restrict__ y, const float* __restrict__ z,
    const float* __restrict__ gamma, const float* __restrict__ beta)
{
    const int tid = threadIdx.x;
    const int lane = tid & 63;
    const int w = tid >> 6;
    const size_t row = (size_t)blockIdx.x * 4 + w;
    float* yr = y + row * 384;
    const float* zr = z + row * 384;
    float v[6];
    float s1 = 0.f, s2 = 0.f;
#pragma unroll
    for (int j = 0; j < 6; ++j) {
        v[j] = yr[lane + j * 64];
        s1 += v[j];
        s2 = fmaf(v[j], v[j], s2);
    }
#pragma unroll
    for (int off = 32; off > 0; off >>= 1) {
        s1 += __shfl_xor(s1, off);
        s2 += __shfl_xor(s2, off);
    }
    float mu = s1 * (1.f / 384.f);
    float var = s2 * (1.f / 384.f) - mu * mu;
    float rs = rsqrtf(var + 1e-5f);
#pragma unroll
    for (int j = 0; j < 6; ++j) {
        int d = lane + j * 64;
        float o = (v[j] - mu) * rs * gamma[d] + beta[d];
        yr[d] = o * zr[d];
    }
}

// ---------------- K5: out = yn @ W_out^T (split-bf16 MFMA) ----------------
// grid = dim3(128, 3)
__global__ __launch_bounds__(256) void k5_gemm_out(
    const float* __restrict__ yn, const float* __restrict__ Wout,
    float* __restrict__ out)
{
    __shared__ short Ah[128 * LDK];
    __shared__ short Al[128 * LDK];
    __shared__ short Bh[64 * LDK];
    __shared__ short Bl[64 * LDK];
    const int tid = threadIdx.x;
    const int lane = tid & 63;
    const int w = tid >> 6;
    const int wr = w >> 1, wc = w & 1;
    const int bm = blockIdx.x * 128;
    const int bn = blockIdx.y * 64;

    f32x4 acc[4][2];
#pragma unroll
    for (int i = 0; i < 4; ++i)
#pragma unroll
        for (int j = 0; j < 2; ++j) acc[i][j] = (f32x4)0.f;

    const int r16 = lane & 15, q4 = lane >> 4;

    for (int k0 = 0; k0 < 384; k0 += 32) {
#pragma unroll
        for (int i = 0; i < 4; ++i) {
            int p = tid + i * 256;
            int r = p >> 3, k4 = (p & 7) * 4;
            float4 av = *(const float4*)(yn + (size_t)(bm + r) * 384 + k0 + k4);
            unsigned short hx = f2bf(av.x), hy = f2bf(av.y), hz = f2bf(av.z), hw = f2bf(av.w);
            unsigned hi0 = (unsigned)hx | ((unsigned)hy << 16);
            unsigned hi1 = (unsigned)hz | ((unsigned)hw << 16);
            unsigned short lx = f2bf(av.x - bf2f(hx)), ly = f2bf(av.y - bf2f(hy));
            unsigned short lz = f2bf(av.z - bf2f(hz)), lw = f2bf(av.w - bf2f(hw));
            unsigned lo0 = (unsigned)lx | ((unsigned)ly << 16);
            unsigned lo1 = (unsigned)lz | ((unsigned)lw << 16);
            int wi = r * (LDK / 2) + (k4 >> 1);
            ((unsigned*)Ah)[wi] = hi0; ((unsigned*)Ah)[wi + 1] = hi1;
            ((unsigned*)Al)[wi] = lo0; ((unsigned*)Al)[wi + 1] = lo1;
        }
#pragma unroll
        for (int i = 0; i < 2; ++i) {
            int p = tid + i * 256;
            int r = p >> 3, k4 = (p & 7) * 4;
            float4 bv = *(const float4*)(Wout + (size_t)(bn + r) * 384 + k0 + k4);
            unsigned short hx = f2bf(bv.x), hy = f2bf(bv.y), hz = f2bf(bv.z), hw = f2bf(bv.w);
            unsigned hi0 = (unsigned)hx | ((unsigned)hy << 16);
            unsigned hi1 = (unsigned)hz | ((unsigned)hw << 16);
            unsigned short lx = f2bf(bv.x - bf2f(hx)), ly = f2bf(bv.y - bf2f(hy));
            unsigned short lz = f2bf(bv.z - bf2f(hz)), lw = f2bf(bv.w - bf2f(hw));
            unsigned lo0 = (unsigned)lx | ((unsigned)ly << 16);
            unsigned lo1 = (unsigned)lz | ((unsigned)lw << 16);
            int wi = r * (LDK / 2) + (k4 >> 1);
            ((unsigned*)Bh)[wi] = hi0; ((unsigned*)Bh)[wi + 1] = hi1;
            ((unsigned*)Bl)[wi] = lo0; ((unsigned*)Bl)[wi + 1] = lo1;
        }
        __syncthreads();

        bf16x8 ah[4], al[4];
#pragma unroll
        for (int mt = 0; mt < 4; ++mt) {
            int off = (wr * 64 + mt * 16 + r16) * LDK + q4 * 8;
            ah[mt] = *(const bf16x8*)(Ah + off);
            al[mt] = *(const bf16x8*)(Al + off);
        }
#pragma unroll
        for (int nt = 0; nt < 2; ++nt) {
            int off = (wc * 32 + nt * 16 + r16) * LDK + q4 * 8;
            bf16x8 bh = *(const bf16x8*)(Bh + off);
            bf16x8 bl = *(const bf16x8*)(Bl + off);
#pragma unroll
            for (int mt = 0; mt < 4; ++mt) {
                acc[mt][nt] = __builtin_amdgcn_mfma_f32_16x16x32_bf16(ah[mt], bh, acc[mt][nt], 0, 0, 0);
                acc[mt][nt] = __builtin_amdgcn_mfma_f32_16x16x32_bf16(ah[mt], bl, acc[mt][nt], 0, 0, 0);
                acc[mt][nt] = __builtin_amdgcn_mfma_f32_16x16x32_bf16(al[mt], bh, acc[mt][nt], 0, 0, 0);
            }
        }
        __syncthreads();
    }

#pragma unroll
    for (int mt = 0; mt < 4; ++mt) {
#pragma unroll
        for (int nt = 0; nt < 2; ++nt) {
            int col = bn + wc * 32 + nt * 16 + r16;
#pragma unroll
            for (int r = 0; r < 4; ++r) {
                int row = bm + wr * 64 + mt * 16 + q4 * 4 + r;
                out[(size_t)row * 192 + col] = acc[mt][nt][r];
            }
        }
    }
}

extern "C" void kernel_launch(void* const* d_in, const int* in_sizes, int n_in,
                              void* d_out, int out_size, void* d_ws, size_t ws_size,
                              hipStream_t stream) {
    const float* x    = (const float*)d_in[0];
    const float* Win  = (const float*)d_in[1];
    const float* xpw  = (const float*)d_in[2];
    const float* dtw  = (const float*)d_in[3];
    const float* dtb  = (const float*)d_in[4];
    const float* Alog = (const float*)d_in[5];
    const float* Dsv  = (const float*)d_in[6];
    const float* lng  = (const float*)d_in[7];
    const float* lnb  = (const float*)d_in[8];
    const float* Wout = (const float*)d_in[9];
    float* out = (float*)d_out;

    const size_t nU  = (size_t)ROWS * 384;
    const size_t nBC = (size_t)ROWS * 16;
    const size_t nHF = (size_t)8 * NCHUNK * 384 * 16;
    const size_t nS  = (size_t)8 * NCHUNK * 384;
    const size_t need = (nU * 3 + nBC * 2 + nHF + nS) * sizeof(float);
    if (ws_size < need) return;   // fail visibly (absmax) instead of faulting

    float* u    = (float*)d_ws;
    float* z    = u + nU;
    float* dl   = z + nU;          // delta -> y -> yn (in place)
    float* Bsv  = dl + nU;
    float* Csv  = Bsv + nBC;
    float* hf   = Csv + nBC;       // hf -> hinit (in place, k3c)
    float* Ssum = hf + nHF;

    k1_gemm_silu<<<dim3(128, 6), 256, 0, stream>>>(x, Win, u, z);
    k2_proj<<<256, 256, 0, stream>>>(u, xpw, dtw, dtb, dl, Bsv, Csv);
    k3a_scan1<<<dim3(NCHUNK, 8), 384, 0, stream>>>(dl, u, Bsv, Alog, hf, Ssum);
    k3c_combine<<<dim3(24, 8), 256, 0, stream>>>(hf, Ssum, Alog);
    k3b_scan2<<<dim3(NCHUNK, 8), 384, 0, stream>>>(dl, u, Bsv, Csv, Alog, Dsv, hf);
    k4_ln_mul<<<4096, 256, 0, stream>>>(dl, z, lng, lnb);
    k5_gemm_out<<<dim3(128, 3), 256, 0, stream>>>(dl, Wout, out);
}

// Round 10
// 295.345 us; speedup vs baseline: 2.5667x; 1.0189x over previous
//
#include <hip/hip_runtime.h>
#include <hip/hip_bf16.h>
#include <math.h>

// SS1D (Mamba-like selective scan). GEMMs via split-bf16 MFMA (hi/lo, 3 MFMA).
// Scan: lane=channel packing, 16 states in registers, 64 chunks of 32 steps.
// B=8, L=2048, DM=192, DI=384, N=16, R=12. Rows = B*L = 16384.

#define ROWS 16384
#define NCHUNK 64
#define CLEN 32

typedef short bf16x8 __attribute__((ext_vector_type(8)));
typedef float f32x4 __attribute__((ext_vector_type(4)));

__device__ __forceinline__ unsigned short f2bf(float f) {
    unsigned u = __float_as_uint(f);
    return (unsigned short)((u + 0x7fffu + ((u >> 16) & 1u)) >> 16);
}
__device__ __forceinline__ float bf2f(unsigned short h) {
    return __uint_as_float(((unsigned)h) << 16);
}

#define LOG2E 1.44269504088896f

// ---------------- K1: xz = silu(x @ W_in^T) -> u, z (split-bf16 MFMA) ----------------
// M=16384, N=768, K=192. BM=128, BN=128, BK=32. 4 waves 2x2, wave tile 64x64.
#define LDK 40   // padded row length in shorts (80B stride: 16B-aligned, 2-way banks)
__global__ __launch_bounds__(256) void k1_gemm_silu(
    const float* __restrict__ x, const float* __restrict__ Win,
    float* __restrict__ u, float* __restrict__ z)
{
    __shared__ short Ah[128 * LDK];
    __shared__ short Al[128 * LDK];
    __shared__ short Bh[128 * LDK];
    __shared__ short Bl[128 * LDK];
    const int tid = threadIdx.x;
    const int lane = tid & 63;
    const int w = tid >> 6;
    const int wr = w >> 1, wc = w & 1;
    const int bm = blockIdx.x * 128;
    const int bn = blockIdx.y * 128;

    f32x4 acc[4][4];
#pragma unroll
    for (int i = 0; i < 4; ++i)
#pragma unroll
        for (int j = 0; j < 4; ++j) acc[i][j] = (f32x4)0.f;

    const int r16 = lane & 15, q4 = lane >> 4;

    for (int k0 = 0; k0 < 192; k0 += 32) {
#pragma unroll
        for (int i = 0; i < 4; ++i) {
            int p = tid + i * 256;
            int r = p >> 3, k4 = (p & 7) * 4;
            float4 av = *(const float4*)(x + (size_t)(bm + r) * 192 + k0 + k4);
            unsigned short hx = f2bf(av.x), hy = f2bf(av.y), hz = f2bf(av.z), hw = f2bf(av.w);
            unsigned hi0 = (unsigned)hx | ((unsigned)hy << 16);
            unsigned hi1 = (unsigned)hz | ((unsigned)hw << 16);
            unsigned short lx = f2bf(av.x - bf2f(hx)), ly = f2bf(av.y - bf2f(hy));
            unsigned short lz = f2bf(av.z - bf2f(hz)), lw = f2bf(av.w - bf2f(hw));
            unsigned lo0 = (unsigned)lx | ((unsigned)ly << 16);
            unsigned lo1 = (unsigned)lz | ((unsigned)lw << 16);
            int wi = r * (LDK / 2) + (k4 >> 1);
            ((unsigned*)Ah)[wi] = hi0; ((unsigned*)Ah)[wi + 1] = hi1;
            ((unsigned*)Al)[wi] = lo0; ((unsigned*)Al)[wi + 1] = lo1;

            float4 bv = *(const float4*)(Win + (size_t)(bn + r) * 192 + k0 + k4);
            hx = f2bf(bv.x); hy = f2bf(bv.y); hz = f2bf(bv.z); hw = f2bf(bv.w);
            hi0 = (unsigned)hx | ((unsigned)hy << 16);
            hi1 = (unsigned)hz | ((unsigned)hw << 16);
            lx = f2bf(bv.x - bf2f(hx)); ly = f2bf(bv.y - bf2f(hy));
            lz = f2bf(bv.z - bf2f(hz)); lw = f2bf(bv.w - bf2f(hw));
            lo0 = (unsigned)lx | ((unsigned)ly << 16);
            lo1 = (unsigned)lz | ((unsigned)lw << 16);
            ((unsigned*)Bh)[wi] = hi0; ((unsigned*)Bh)[wi + 1] = hi1;
            ((unsigned*)Bl)[wi] = lo0; ((unsigned*)Bl)[wi + 1] = lo1;
        }
        __syncthreads();

        bf16x8 ah[4], al[4];
#pragma unroll
        for (int mt = 0; mt < 4; ++mt) {
            int off = (wr * 64 + mt * 16 + r16) * LDK + q4 * 8;
            ah[mt] = *(const bf16x8*)(Ah + off);
            al[mt] = *(const bf16x8*)(Al + off);
        }
#pragma unroll
        for (int nt = 0; nt < 4; ++nt) {
            int off = (wc * 64 + nt * 16 + r16) * LDK + q4 * 8;
            bf16x8 bh = *(const bf16x8*)(Bh + off);
            bf16x8 bl = *(const bf16x8*)(Bl + off);
#pragma unroll
            for (int mt = 0; mt < 4; ++mt) {
                acc[mt][nt] = __builtin_amdgcn_mfma_f32_16x16x32_bf16(ah[mt], bh, acc[mt][nt], 0, 0, 0);
                acc[mt][nt] = __builtin_amdgcn_mfma_f32_16x16x32_bf16(ah[mt], bl, acc[mt][nt], 0, 0, 0);
                acc[mt][nt] = __builtin_amdgcn_mfma_f32_16x16x32_bf16(al[mt], bh, acc[mt][nt], 0, 0, 0);
            }
        }
        __syncthreads();
    }

    float* dst = (bn < 384) ? u : z;
    const int col0 = (bn < 384) ? bn : (bn - 384);
#pragma unroll
    for (int mt = 0; mt < 4; ++mt) {
#pragma unroll
        for (int nt = 0; nt < 4; ++nt) {
            int col = col0 + wc * 64 + nt * 16 + r16;
#pragma unroll
            for (int r = 0; r < 4; ++r) {
                int row = bm + wr * 64 + mt * 16 + q4 * 4 + r;
                float s = acc[mt][nt][r];
                dst[(size_t)row * 384 + col] = s / (1.f + __expf(-s));
            }
        }
    }
}

// ------- K2: dbl = u @ xpw^T (44 cols, split-bf16 MFMA); delta = softplus(...) -------
// BM=64, N=48 (44 live), BK=64. 4 waves, wave w -> m-tile w, 3 n-tiles.
// Reg-prefetch pipeline: write LDS -> barrier -> load next chunk -> MFMA -> barrier.
#define LDK2 72   // padded row length in shorts for BK=64 (144B stride, 2-way banks)
__global__ __launch_bounds__(256) void k2_proj(
    const float* __restrict__ u, const float* __restrict__ xpw,
    const float* __restrict__ dtw, const float* __restrict__ dtb,
    float* __restrict__ delta, float* __restrict__ Bso, float* __restrict__ Cso)
{
    __shared__ __align__(16) short Ah[64 * LDK2];
    __shared__ __align__(16) short Al[64 * LDK2];
    __shared__ __align__(16) short Bh[48 * LDK2];
    __shared__ __align__(16) short Bl[48 * LDK2];
    __shared__ float dtwS[384 * 13];
    __shared__ float dblS[64 * 13];
    const int tid = threadIdx.x;
    const int lane = tid & 63;
    const int w = tid >> 6;          // wave = m-tile
    const int r16 = lane & 15, q4 = lane >> 4;
    const int row0 = blockIdx.x * 64;

    // stage dtw once (384x12 = 1152 float4)
#pragma unroll
    for (int i = 0; i < 5; ++i) {
        int p = tid + i * 256;
        if (p < 1152) {
            int dd = p / 3, q = (p % 3) * 4;
            float4 v = *(const float4*)(dtw + dd * 12 + q);
            dtwS[dd * 13 + q + 0] = v.x;
            dtwS[dd * 13 + q + 1] = v.y;
            dtwS[dd * 13 + q + 2] = v.z;
            dtwS[dd * 13 + q + 3] = v.w;
        }
    }

    f32x4 acc[3];
#pragma unroll
    for (int j = 0; j < 3; ++j) acc[j] = (f32x4)0.f;

    // prefetch chunk 0: A = u[64 x 64], B = xpw[48 x 64] (rows >=44 zero)
    float4 aReg[4], bReg[3];
#pragma unroll
    for (int i = 0; i < 4; ++i) {
        int p = tid + i * 256;
        int r = p >> 4, k4 = (p & 15) * 4;
        aReg[i] = *(const float4*)(u + (size_t)(row0 + r) * 384 + k4);
    }
#pragma unroll
    for (int i = 0; i < 3; ++i) {
        int p = tid + i * 256;
        int c = p >> 4, k4 = (p & 15) * 4;
        bReg[i] = (c < 44) ? *(const float4*)(xpw + (size_t)c * 384 + k4)
                           : make_float4(0.f, 0.f, 0.f, 0.f);
    }

    for (int ck = 0; ck < 6; ++ck) {
        // convert & write regs -> LDS
#pragma unroll
        for (int i = 0; i < 4; ++i) {
            int p = tid + i * 256;
            int r = p >> 4, k4 = (p & 15) * 4;
            float4 av = aReg[i];
            unsigned short hx = f2bf(av.x), hy = f2bf(av.y), hz = f2bf(av.z), hw = f2bf(av.w);
            unsigned short lx = f2bf(av.x - bf2f(hx)), ly = f2bf(av.y - bf2f(hy));
            unsigned short lz = f2bf(av.z - bf2f(hz)), lw = f2bf(av.w - bf2f(hw));
            int wi = r * (LDK2 / 2) + (k4 >> 1);
            ((unsigned*)Ah)[wi]     = (unsigned)hx | ((unsigned)hy << 16);
            ((unsigned*)Ah)[wi + 1] = (unsigned)hz | ((unsigned)hw << 16);
            ((unsigned*)Al)[wi]     = (unsigned)lx | ((unsigned)ly << 16);
            ((unsigned*)Al)[wi + 1] = (unsigned)lz | ((unsigned)lw << 16);
        }
#pragma unroll
        for (int i = 0; i < 3; ++i) {
            int p = tid + i * 256;
            int c = p >> 4, k4 = (p & 15) * 4;
            float4 bv = bReg[i];
            unsigned short hx = f2bf(bv.x), hy = f2bf(bv.y), hz = f2bf(bv.z), hw = f2bf(bv.w);
            unsigned short lx = f2bf(bv.x - bf2f(hx)), ly = f2bf(bv.y - bf2f(hy));
            unsigned short lz = f2bf(bv.z - bf2f(hz)), lw = f2bf(bv.w - bf2f(hw));
            int wi = c * (LDK2 / 2) + (k4 >> 1);
            ((unsigned*)Bh)[wi]     = (unsigned)hx | ((unsigned)hy << 16);
            ((unsigned*)Bh)[wi + 1] = (unsigned)hz | ((unsigned)hw << 16);
            ((unsigned*)Bl)[wi]     = (unsigned)lx | ((unsigned)ly << 16);
            ((unsigned*)Bl)[wi + 1] = (unsigned)lz | ((unsigned)lw << 16);
        }
        __syncthreads();

        // issue next chunk's global loads (overlap with MFMA below)
        if (ck + 1 < 6) {
            int k0 = (ck + 1) * 64;
#pragma unroll
            for (int i = 0; i < 4; ++i) {
                int p = tid + i * 256;
                int r = p >> 4, k4 = (p & 15) * 4;
                aReg[i] = *(const float4*)(u + (size_t)(row0 + r) * 384 + k0 + k4);
            }
#pragma unroll
            for (int i = 0; i < 3; ++i) {
                int p = tid + i * 256;
                int c = p >> 4, k4 = (p & 15) * 4;
                bReg[i] = (c < 44) ? *(const float4*)(xpw + (size_t)c * 384 + k0 + k4)
                                   : make_float4(0.f, 0.f, 0.f, 0.f);
            }
        }
        __builtin_amdgcn_sched_barrier(0);   // loads issue before MFMA cluster

        // compute: 2 k-frag steps x 3 n-tiles x 3 split-MFMA
#pragma unroll
        for (int ks = 0; ks < 2; ++ks) {
            int aoff = (w * 16 + r16) * LDK2 + ks * 32 + q4 * 8;
            bf16x8 ah = *(const bf16x8*)(Ah + aoff);
            bf16x8 al = *(const bf16x8*)(Al + aoff);
#pragma unroll
            for (int nt = 0; nt < 3; ++nt) {
                int boff = (nt * 16 + r16) * LDK2 + ks * 32 + q4 * 8;
                bf16x8 bh = *(const bf16x8*)(Bh + boff);
                bf16x8 bl = *(const bf16x8*)(Bl + boff);
                acc[nt] = __builtin_amdgcn_mfma_f32_16x16x32_bf16(ah, bh, acc[nt], 0, 0, 0);
                acc[nt] = __builtin_amdgcn_mfma_f32_16x16x32_bf16(ah, bl, acc[nt], 0, 0, 0);
                acc[nt] = __builtin_amdgcn_mfma_f32_16x16x32_bf16(al, bh, acc[nt], 0, 0, 0);
            }
        }
        __syncthreads();
    }

    // epilogue: C/D layout col=nt*16+r16, row = w*16 + q4*4 + reg.
    // route c<12 -> dblS, 12..27 -> Bso, 28..43 -> Cso, >=44 drop.
#pragma unroll
    for (int nt = 0; nt < 3; ++nt) {
        int c = nt * 16 + r16;
#pragma unroll
        for (int r = 0; r < 4; ++r) {
            int lr = w * 16 + q4 * 4 + r;
            int row = row0 + lr;
            float s = acc[nt][r];
            if (c < 12)      dblS[lr * 13 + c] = s;
            else if (c < 28) Bso[(size_t)row * 16 + (c - 12)] = s;
            else if (c < 44) Cso[(size_t)row * 16 + (c - 28)] = s;
        }
    }
    __syncthreads();

    // phase B: delta = softplus(dblS @ dtw^T + dtb), 64 rows x 384 d
    for (int it = 0; it < 96; ++it) {
        int o = it * 256 + tid;
        int r = o / 384, d = o - r * 384;
        float s = dtb[d];
        const float* wr = dtwS + d * 13;
        const float* db = dblS + r * 13;
#pragma unroll
        for (int j = 0; j < 12; ++j) s = fmaf(db[j], wr[j], s);
        float sp = (s > 20.f) ? s : log1pf(__expf(s));
        delta[(size_t)(row0 + r) * 384 + d] = sp;
    }
}

// ---------------- K3a: per-chunk local scan, lane=d, h[16] in registers ----------------
__global__ __launch_bounds__(384) void k3a_scan1(
    const float* __restrict__ delta, const float* __restrict__ u,
    const float* __restrict__ Bsv, const float* __restrict__ A_logs,
    float* __restrict__ hf, float* __restrict__ Ssum)
{
    const int tid = threadIdx.x;
    const int lane = tid & 63;
    const int wv = tid >> 6;
    const int c = blockIdx.x;
    const int b = blockIdx.y;
    const int d = wv * 64 + lane;
    const int t0 = c * CLEN;

    float Ac[16];
    {
#pragma unroll
        for (int q = 0; q < 4; ++q) {
            float4 v = *(const float4*)(A_logs + d * 16 + q * 4);
            Ac[q * 4 + 0] = -__expf(v.x) * LOG2E;
            Ac[q * 4 + 1] = -__expf(v.y) * LOG2E;
            Ac[q * 4 + 2] = -__expf(v.z) * LOG2E;
            Ac[q * 4 + 3] = -__expf(v.w) * LOG2E;
        }
    }

    const float* dp = delta + ((size_t)b * 2048 + t0) * 384 + d;
    const float* up = u     + ((size_t)b * 2048 + t0) * 384 + d;
    const float* Bp = Bsv   + ((size_t)b * 2048 + t0) * 16;

    float h[16];
#pragma unroll
    for (int n = 0; n < 16; ++n) h[n] = 0.f;
    float S = 0.f;

    float dv_n = dp[0], uv_n = up[0];
    float4 B0n = *(const float4*)(Bp + 0);
    float4 B1n = *(const float4*)(Bp + 4);
    float4 B2n = *(const float4*)(Bp + 8);
    float4 B3n = *(const float4*)(Bp + 12);

    for (int s = 0; s < CLEN; ++s) {
        float dv = dv_n, uv = uv_n;
        float4 B0 = B0n, B1 = B1n, B2 = B2n, B3 = B3n;
        if (s + 1 < CLEN) {
            dp += 384; up += 384; Bp += 16;
            dv_n = dp[0]; uv_n = up[0];
            B0n = *(const float4*)(Bp + 0);
            B1n = *(const float4*)(Bp + 4);
            B2n = *(const float4*)(Bp + 8);
            B3n = *(const float4*)(Bp + 12);
        }
        __builtin_amdgcn_sched_barrier(0);
        S += dv;
        float dvu = dv * uv;
        float Br[16] = {B0.x, B0.y, B0.z, B0.w, B1.x, B1.y, B1.z, B1.w,
                        B2.x, B2.y, B2.z, B2.w, B3.x, B3.y, B3.z, B3.w};
#pragma unroll
        for (int n = 0; n < 16; ++n) {
            float a = exp2f(dv * Ac[n]);
            h[n] = fmaf(a, h[n], dvu * Br[n]);
        }
    }

    const size_t ho = (((size_t)b * NCHUNK + c) * 384 + d) * 16;
#pragma unroll
    for (int q = 0; q < 4; ++q)
        *(float4*)(hf + ho + q * 4) = make_float4(h[q*4+0], h[q*4+1], h[q*4+2], h[q*4+3]);
    Ssum[((size_t)b * NCHUNK + c) * 384 + d] = S;
}

// ---------------- K3c: exclusive scan over chunk summaries (in-place hf -> hinit) ----------------
__global__ __launch_bounds__(256) void k3c_combine(
    float* __restrict__ hf, const float* __restrict__ Ssum,
    const float* __restrict__ A_logs)
{
    const int tid = threadIdx.x;
    const int n = tid & 15, dl = tid >> 4;
    const int d = blockIdx.x * 16 + dl;
    const int b = blockIdx.y;
    const float Ac = -__expf(A_logs[d * 16 + n]) * LOG2E;

    float h = 0.f;
    for (int c = 0; c < NCHUNK; ++c) {
        const size_t idx = (((size_t)b * NCHUNK + c) * 384 + d) * 16 + n;
        float hfv = hf[idx];
        float Sv  = Ssum[((size_t)b * NCHUNK + c) * 384 + d];
        hf[idx] = h;
        float P = exp2f(Ac * Sv);
        h = fmaf(P, h, hfv);
    }
}

// ---------------- K3b: rescan with correct h_init, emit y (in-place on delta) ----------------
__global__ __launch_bounds__(384) void k3b_scan2(
    float* __restrict__ dy, const float* __restrict__ u,
    const float* __restrict__ Bsv, const float* __restrict__ Csv,
    const float* __restrict__ A_logs, const float* __restrict__ Ds,
    const float* __restrict__ hf)
{
    const int tid = threadIdx.x;
    const int lane = tid & 63;
    const int wv = tid >> 6;
    const int c = blockIdx.x;
    const int b = blockIdx.y;
    const int d = wv * 64 + lane;
    const int t0 = c * CLEN;

    float Ac[16];
#pragma unroll
    for (int q = 0; q < 4; ++q) {
        float4 v = *(const float4*)(A_logs + d * 16 + q * 4);
        Ac[q * 4 + 0] = -__expf(v.x) * LOG2E;
        Ac[q * 4 + 1] = -__expf(v.y) * LOG2E;
        Ac[q * 4 + 2] = -__expf(v.z) * LOG2E;
        Ac[q * 4 + 3] = -__expf(v.w) * LOG2E;
    }
    const float Dd = Ds[d];

    float h[16];
    {
        const size_t ho = (((size_t)b * NCHUNK + c) * 384 + d) * 16;
#pragma unroll
        for (int q = 0; q < 4; ++q) {
            float4 v = *(const float4*)(hf + ho + q * 4);
            h[q * 4 + 0] = v.x; h[q * 4 + 1] = v.y;
            h[q * 4 + 2] = v.z; h[q * 4 + 3] = v.w;
        }
    }

    float* yp       = dy  + ((size_t)b * 2048 + t0) * 384 + d;
    const float* up = u   + ((size_t)b * 2048 + t0) * 384 + d;
    const float* Bp = Bsv + ((size_t)b * 2048 + t0) * 16;
    const float* Cp = Csv + ((size_t)b * 2048 + t0) * 16;

    float dv_n = yp[0], uv_n = up[0];
    float4 B0n = *(const float4*)(Bp + 0);
    float4 B1n = *(const float4*)(Bp + 4);
    float4 B2n = *(const float4*)(Bp + 8);
    float4 B3n = *(const float4*)(Bp + 12);
    float4 C0n = *(const float4*)(Cp + 0);
    float4 C1n = *(const float4*)(Cp + 4);
    float4 C2n = *(const float4*)(Cp + 8);
    float4 C3n = *(const float4*)(Cp + 12);
    const float* dpn = yp + 384;

    for (int s = 0; s < CLEN; ++s) {
        float dv = dv_n, uv = uv_n;
        float4 B0 = B0n, B1 = B1n, B2 = B2n, B3 = B3n;
        float4 C0 = C0n, C1 = C1n, C2 = C2n, C3 = C3n;
        if (s + 1 < CLEN) {
            up += 384; Bp += 16; Cp += 16;
            dv_n = dpn[0]; uv_n = up[0];
            B0n = *(const float4*)(Bp + 0);
            B1n = *(const float4*)(Bp + 4);
            B2n = *(const float4*)(Bp + 8);
            B3n = *(const float4*)(Bp + 12);
            C0n = *(const float4*)(Cp + 0);
            C1n = *(const float4*)(Cp + 4);
            C2n = *(const float4*)(Cp + 8);
            C3n = *(const float4*)(Cp + 12);
            dpn += 384;
        }
        __builtin_amdgcn_sched_barrier(0);
        float dvu = dv * uv;
        float Br[16] = {B0.x, B0.y, B0.z, B0.w, B1.x, B1.y, B1.z, B1.w,
                        B2.x, B2.y, B2.z, B2.w, B3.x, B3.y, B3.z, B3.w};
        float Cr[16] = {C0.x, C0.y, C0.z, C0.w, C1.x, C1.y, C1.z, C1.w,
                        C2.x, C2.y, C2.z, C2.w, C3.x, C3.y, C3.z, C3.w};
        float y = Dd * uv;
#pragma unroll
        for (int n = 0; n < 16; ++n) {
            float a = exp2f(dv * Ac[n]);
            h[n] = fmaf(a, h[n], dvu * Br[n]);
            y = fmaf(Cr[n], h[n], y);
        }
        yp[0] = y;
        yp += 384;
    }
}

// ---------------- K4: LayerNorm over DI, then * z (in place on y) ----------------
__global__ __launch_bounds__(256) void k4_ln_mul(
    float* __restrict__ y, const float* __restrict__ z,
    const float* __restrict__ gamma, const float* __restrict__ beta)
{
    const int tid = threadIdx.x;
    const int lane = tid & 63;
    const int w = tid >> 6;
    const size_t row = (size_t)blockIdx.x * 4 + w;
    float* yr = y + row * 384;
    const float* zr = z + row * 384;
    float v[6];
    float s1 = 0.f, s2 = 0.f;
#pragma unroll
    for (int j = 0; j < 6; ++j) {
        v[j] = yr[lane + j * 64];
        s1 += v[j];
        s2 = fmaf(v[j], v[j], s2);
    }
#pragma unroll
    for (int off = 32; off > 0; off >>= 1) {
        s1 += __shfl_xor(s1, off);
        s2 += __shfl_xor(s2, off);
    }
    float mu = s1 * (1.f / 384.f);
    float var = s2 * (1.f / 384.f) - mu * mu;
    float rs = rsqrtf(var + 1e-5f);
#pragma unroll
    for (int j = 0; j < 6; ++j) {
        int d = lane + j * 64;
        float o = (v[j] - mu) * rs * gamma[d] + beta[d];
        yr[d] = o * zr[d];
    }
}

// ---------------- K5: out = yn @ W_out^T (split-bf16 MFMA) ----------------
// grid = dim3(128, 3)
__global__ __launch_bounds__(256) void k5_gemm_out(
    const float* __restrict__ yn, const float* __restrict__ Wout,
    float* __restrict__ out)
{
    __shared__ short Ah[128 * LDK];
    __shared__ short Al[128 * LDK];
    __shared__ short Bh[64 * LDK];
    __shared__ short Bl[64 * LDK];
    const int tid = threadIdx.x;
    const int lane = tid & 63;
    const int w = tid >> 6;
    const int wr = w >> 1, wc = w & 1;
    const int bm = blockIdx.x * 128;
    const int bn = blockIdx.y * 64;

    f32x4 acc[4][2];
#pragma unroll
    for (int i = 0; i < 4; ++i)
#pragma unroll
        for (int j = 0; j < 2; ++j) acc[i][j] = (f32x4)0.f;

    const int r16 = lane & 15, q4 = lane >> 4;

    for (int k0 = 0; k0 < 384; k0 += 32) {
#pragma unroll
        for (int i = 0; i < 4; ++i) {
            int p = tid + i * 256;
            int r = p >> 3, k4 = (p & 7) * 4;
            float4 av = *(const float4*)(yn + (size_t)(bm + r) * 384 + k0 + k4);
            unsigned short hx = f2bf(av.x), hy = f2bf(av.y), hz = f2bf(av.z), hw = f2bf(av.w);
            unsigned hi0 = (unsigned)hx | ((unsigned)hy << 16);
            unsigned hi1 = (unsigned)hz | ((unsigned)hw << 16);
            unsigned short lx = f2bf(av.x - bf2f(hx)), ly = f2bf(av.y - bf2f(hy));
            unsigned short lz = f2bf(av.z - bf2f(hz)), lw = f2bf(av.w - bf2f(hw));
            unsigned lo0 = (unsigned)lx | ((unsigned)ly << 16);
            unsigned lo1 = (unsigned)lz | ((unsigned)lw << 16);
            int wi = r * (LDK / 2) + (k4 >> 1);
            ((unsigned*)Ah)[wi] = hi0; ((unsigned*)Ah)[wi + 1] = hi1;
            ((unsigned*)Al)[wi] = lo0; ((unsigned*)Al)[wi + 1] = lo1;
        }
#pragma unroll
        for (int i = 0; i < 2; ++i) {
            int p = tid + i * 256;
            int r = p >> 3, k4 = (p & 7) * 4;
            float4 bv = *(const float4*)(Wout + (size_t)(bn + r) * 384 + k0 + k4);
            unsigned short hx = f2bf(bv.x), hy = f2bf(bv.y), hz = f2bf(bv.z), hw = f2bf(bv.w);
            unsigned hi0 = (unsigned)hx | ((unsigned)hy << 16);
            unsigned hi1 = (unsigned)hz | ((unsigned)hw << 16);
            unsigned short lx = f2bf(bv.x - bf2f(hx)), ly = f2bf(bv.y - bf2f(hy));
            unsigned short lz = f2bf(bv.z - bf2f(hz)), lw = f2bf(bv.w - bf2f(hw));
            unsigned lo0 = (unsigned)lx | ((unsigned)ly << 16);
            unsigned lo1 = (unsigned)lz | ((unsigned)lw << 16);
            int wi = r * (LDK / 2) + (k4 >> 1);
            ((unsigned*)Bh)[wi] = hi0; ((unsigned*)Bh)[wi + 1] = hi1;
            ((unsigned*)Bl)[wi] = lo0; ((unsigned*)Bl)[wi + 1] = lo1;
        }
        __syncthreads();

        bf16x8 ah[4], al[4];
#pragma unroll
        for (int mt = 0; mt < 4; ++mt) {
            int off = (wr * 64 + mt * 16 + r16) * LDK + q4 * 8;
            ah[mt] = *(const bf16x8*)(Ah + off);
            al[mt] = *(const bf16x8*)(Al + off);
        }
#pragma unroll
        for (int nt = 0; nt < 2; ++nt) {
            int off = (wc * 32 + nt * 16 + r16) * LDK + q4 * 8;
            bf16x8 bh = *(const bf16x8*)(Bh + off);
            bf16x8 bl = *(const bf16x8*)(Bl + off);
#pragma unroll
            for (int mt = 0; mt < 4; ++mt) {
                acc[mt][nt] = __builtin_amdgcn_mfma_f32_16x16x32_bf16(ah[mt], bh, acc[mt][nt], 0, 0, 0);
                acc[mt][nt] = __builtin_amdgcn_mfma_f32_16x16x32_bf16(ah[mt], bl, acc[mt][nt], 0, 0, 0);
                acc[mt][nt] = __builtin_amdgcn_mfma_f32_16x16x32_bf16(al[mt], bh, acc[mt][nt], 0, 0, 0);
            }
        }
        __syncthreads();
    }

#pragma unroll
    for (int mt = 0; mt < 4; ++mt) {
#pragma unroll
        for (int nt = 0; nt < 2; ++nt) {
            int col = bn + wc * 32 + nt * 16 + r16;
#pragma unroll
            for (int r = 0; r < 4; ++r) {
                int row = bm + wr * 64 + mt * 16 + q4 * 4 + r;
                out[(size_t)row * 192 + col] = acc[mt][nt][r];
            }
        }
    }
}

extern "C" void kernel_launch(void* const* d_in, const int* in_sizes, int n_in,
                              void* d_out, int out_size, void* d_ws, size_t ws_size,
                              hipStream_t stream) {
    const float* x    = (const float*)d_in[0];
    const float* Win  = (const float*)d_in[1];
    const float* xpw  = (const float*)d_in[2];
    const float* dtw  = (const float*)d_in[3];
    const float* dtb  = (const float*)d_in[4];
    const float* Alog = (const float*)d_in[5];
    const float* Dsv  = (const float*)d_in[6];
    const float* lng  = (const float*)d_in[7];
    const float* lnb  = (const float*)d_in[8];
    const float* Wout = (const float*)d_in[9];
    float* out = (float*)d_out;

    const size_t nU  = (size_t)ROWS * 384;
    const size_t nBC = (size_t)ROWS * 16;
    const size_t nHF = (size_t)8 * NCHUNK * 384 * 16;
    const size_t nS  = (size_t)8 * NCHUNK * 384;
    const size_t need = (nU * 3 + nBC * 2 + nHF + nS) * sizeof(float);
    if (ws_size < need) return;   // fail visibly (absmax) instead of faulting

    float* u    = (float*)d_ws;
    float* z    = u + nU;
    float* dl   = z + nU;          // delta -> y -> yn (in place)
    float* Bsv  = dl + nU;
    float* Csv  = Bsv + nBC;
    float* hf   = Csv + nBC;       // hf -> hinit (in place, k3c)
    float* Ssum = hf + nHF;

    k1_gemm_silu<<<dim3(128, 6), 256, 0, stream>>>(x, Win, u, z);
    k2_proj<<<256, 256, 0, stream>>>(u, xpw, dtw, dtb, dl, Bsv, Csv);
    k3a_scan1<<<dim3(NCHUNK, 8), 384, 0, stream>>>(dl, u, Bsv, Alog, hf, Ssum);
    k3c_combine<<<dim3(24, 8), 256, 0, stream>>>(hf, Ssum, Alog);
    k3b_scan2<<<dim3(NCHUNK, 8), 384, 0, stream>>>(dl, u, Bsv, Csv, Alog, Dsv, hf);
    k4_ln_mul<<<4096, 256, 0, stream>>>(dl, z, lng, lnb);
    k5_gemm_out<<<dim3(128, 3), 256, 0, stream>>>(dl, Wout, out);
}

// Round 11
// 276.602 us; speedup vs baseline: 2.7406x; 1.0678x over previous
//
#include <hip/hip_runtime.h>
#include <hip/hip_bf16.h>
#include <math.h>

// SS1D (Mamba-like selective scan). GEMMs via split-bf16 MFMA (hi/lo, 3 MFMA).
// Scan: lane=channel packing, 16 states in registers, 64 chunks of 32 steps.
// B=8, L=2048, DM=192, DI=384, N=16, R=12. Rows = B*L = 16384.

#define ROWS 16384
#define NCHUNK 64
#define CLEN 32

typedef short bf16x8 __attribute__((ext_vector_type(8)));
typedef float f32x4 __attribute__((ext_vector_type(4)));

__device__ __forceinline__ unsigned short f2bf(float f) {
    unsigned u = __float_as_uint(f);
    return (unsigned short)((u + 0x7fffu + ((u >> 16) & 1u)) >> 16);
}
__device__ __forceinline__ float bf2f(unsigned short h) {
    return __uint_as_float(((unsigned)h) << 16);
}
__device__ __forceinline__ void cvt8(float4 a0, float4 a1, bf16x8& hi, bf16x8& lo) {
    float v[8] = {a0.x, a0.y, a0.z, a0.w, a1.x, a1.y, a1.z, a1.w};
#pragma unroll
    for (int j = 0; j < 8; ++j) {
        unsigned short h = f2bf(v[j]);
        hi[j] = (short)h;
        lo[j] = (short)f2bf(v[j] - bf2f(h));
    }
}

#define LOG2E 1.44269504088896f

// ---------------- K0: pre-split xpw (44x384, pad to 48) into bf16 hi/lo planes ----------------
// grid = 48 blocks x 384 threads. xpwH/L layout: [col][k], 384 shorts per col.
__global__ __launch_bounds__(384) void k0_split(
    const float* __restrict__ xpw, short* __restrict__ xpwH, short* __restrict__ xpwL)
{
    const int c = blockIdx.x, k = threadIdx.x;
    float v = (c < 44) ? xpw[(size_t)c * 384 + k] : 0.f;
    unsigned short h = f2bf(v);
    xpwH[(size_t)c * 384 + k] = (short)h;
    xpwL[(size_t)c * 384 + k] = (short)f2bf(v - bf2f(h));
}

// ---------------- K1: xz = silu(x @ W_in^T) -> u, z (split-bf16 MFMA) ----------------
// M=16384, N=768, K=192. BM=128, BN=128, BK=32. 4 waves 2x2, wave tile 64x64.
#define LDK 40   // padded row length in shorts (80B stride: 16B-aligned, 2-way banks)
__global__ __launch_bounds__(256) void k1_gemm_silu(
    const float* __restrict__ x, const float* __restrict__ Win,
    float* __restrict__ u, float* __restrict__ z)
{
    __shared__ short Ah[128 * LDK];
    __shared__ short Al[128 * LDK];
    __shared__ short Bh[128 * LDK];
    __shared__ short Bl[128 * LDK];
    const int tid = threadIdx.x;
    const int lane = tid & 63;
    const int w = tid >> 6;
    const int wr = w >> 1, wc = w & 1;
    const int bm = blockIdx.x * 128;
    const int bn = blockIdx.y * 128;

    f32x4 acc[4][4];
#pragma unroll
    for (int i = 0; i < 4; ++i)
#pragma unroll
        for (int j = 0; j < 4; ++j) acc[i][j] = (f32x4)0.f;

    const int r16 = lane & 15, q4 = lane >> 4;

    for (int k0 = 0; k0 < 192; k0 += 32) {
#pragma unroll
        for (int i = 0; i < 4; ++i) {
            int p = tid + i * 256;
            int r = p >> 3, k4 = (p & 7) * 4;
            float4 av = *(const float4*)(x + (size_t)(bm + r) * 192 + k0 + k4);
            unsigned short hx = f2bf(av.x), hy = f2bf(av.y), hz = f2bf(av.z), hw = f2bf(av.w);
            unsigned hi0 = (unsigned)hx | ((unsigned)hy << 16);
            unsigned hi1 = (unsigned)hz | ((unsigned)hw << 16);
            unsigned short lx = f2bf(av.x - bf2f(hx)), ly = f2bf(av.y - bf2f(hy));
            unsigned short lz = f2bf(av.z - bf2f(hz)), lw = f2bf(av.w - bf2f(hw));
            unsigned lo0 = (unsigned)lx | ((unsigned)ly << 16);
            unsigned lo1 = (unsigned)lz | ((unsigned)lw << 16);
            int wi = r * (LDK / 2) + (k4 >> 1);
            ((unsigned*)Ah)[wi] = hi0; ((unsigned*)Ah)[wi + 1] = hi1;
            ((unsigned*)Al)[wi] = lo0; ((unsigned*)Al)[wi + 1] = lo1;

            float4 bv = *(const float4*)(Win + (size_t)(bn + r) * 192 + k0 + k4);
            hx = f2bf(bv.x); hy = f2bf(bv.y); hz = f2bf(bv.z); hw = f2bf(bv.w);
            hi0 = (unsigned)hx | ((unsigned)hy << 16);
            hi1 = (unsigned)hz | ((unsigned)hw << 16);
            lx = f2bf(bv.x - bf2f(hx)); ly = f2bf(bv.y - bf2f(hy));
            lz = f2bf(bv.z - bf2f(hz)); lw = f2bf(bv.w - bf2f(hw));
            lo0 = (unsigned)lx | ((unsigned)ly << 16);
            lo1 = (unsigned)lz | ((unsigned)lw << 16);
            ((unsigned*)Bh)[wi] = hi0; ((unsigned*)Bh)[wi + 1] = hi1;
            ((unsigned*)Bl)[wi] = lo0; ((unsigned*)Bl)[wi + 1] = lo1;
        }
        __syncthreads();

        bf16x8 ah[4], al[4];
#pragma unroll
        for (int mt = 0; mt < 4; ++mt) {
            int off = (wr * 64 + mt * 16 + r16) * LDK + q4 * 8;
            ah[mt] = *(const bf16x8*)(Ah + off);
            al[mt] = *(const bf16x8*)(Al + off);
        }
#pragma unroll
        for (int nt = 0; nt < 4; ++nt) {
            int off = (wc * 64 + nt * 16 + r16) * LDK + q4 * 8;
            bf16x8 bh = *(const bf16x8*)(Bh + off);
            bf16x8 bl = *(const bf16x8*)(Bl + off);
#pragma unroll
            for (int mt = 0; mt < 4; ++mt) {
                acc[mt][nt] = __builtin_amdgcn_mfma_f32_16x16x32_bf16(ah[mt], bh, acc[mt][nt], 0, 0, 0);
                acc[mt][nt] = __builtin_amdgcn_mfma_f32_16x16x32_bf16(ah[mt], bl, acc[mt][nt], 0, 0, 0);
                acc[mt][nt] = __builtin_amdgcn_mfma_f32_16x16x32_bf16(al[mt], bh, acc[mt][nt], 0, 0, 0);
            }
        }
        __syncthreads();
    }

    float* dst = (bn < 384) ? u : z;
    const int col0 = (bn < 384) ? bn : (bn - 384);
#pragma unroll
    for (int mt = 0; mt < 4; ++mt) {
#pragma unroll
        for (int nt = 0; nt < 4; ++nt) {
            int col = col0 + wc * 64 + nt * 16 + r16;
#pragma unroll
            for (int r = 0; r < 4; ++r) {
                int row = bm + wr * 64 + mt * 16 + q4 * 4 + r;
                float s = acc[mt][nt][r];
                dst[(size_t)row * 384 + col] = s / (1.f + __expf(-s));
            }
        }
    }
}

// ------- K2: dbl = u @ xpw^T (44 cols, split-bf16 MFMA, no staging LDS) -------
// Block = 384 thr (6 waves), BM=32, grid=512. Wave (mt=w%2, ks=w/2): 16-row
// m-tile over K-slice ks*128..+127 (4 chunks of 32). A-fragments direct from
// global (reg convert); B-fragments from precomputed xpwH/L. LDS only for the
// 3-way K-reduction + dblS. Phase B: one d per thread.
__global__ __launch_bounds__(384) void k2_proj(
    const float* __restrict__ u, const short* __restrict__ xpwH,
    const short* __restrict__ xpwL,
    const float* __restrict__ dtw, const float* __restrict__ dtb,
    float* __restrict__ delta, float* __restrict__ Bso, float* __restrict__ Cso)
{
    __shared__ float red[2][2][16][49];   // [ks-1][mt][row][col(pad49)]
    __shared__ float dblS[32 * 13];
    const int tid = threadIdx.x;
    const int lane = tid & 63;
    const int w = tid >> 6;
    const int mt = w & 1, ks = w >> 1;    // mt 0/1, ks 0/1/2
    const int r16 = lane & 15, q4 = lane >> 4;
    const int row0 = blockIdx.x * 32;
    const int arow = row0 + mt * 16 + r16;

    f32x4 acc[3];
#pragma unroll
    for (int j = 0; j < 3; ++j) acc[j] = (f32x4)0.f;

#pragma unroll
    for (int ck = 0; ck < 4; ++ck) {
        const int kb = ks * 128 + ck * 32 + q4 * 8;
        const float* ap = u + (size_t)arow * 384 + kb;
        float4 a0 = *(const float4*)(ap);
        float4 a1 = *(const float4*)(ap + 4);
        bf16x8 ah, al;
        cvt8(a0, a1, ah, al);
#pragma unroll
        for (int nt = 0; nt < 3; ++nt) {
            const int col = nt * 16 + r16;
            bf16x8 bh = *(const bf16x8*)(xpwH + (size_t)col * 384 + kb);
            bf16x8 bl = *(const bf16x8*)(xpwL + (size_t)col * 384 + kb);
            acc[nt] = __builtin_amdgcn_mfma_f32_16x16x32_bf16(ah, bh, acc[nt], 0, 0, 0);
            acc[nt] = __builtin_amdgcn_mfma_f32_16x16x32_bf16(ah, bl, acc[nt], 0, 0, 0);
            acc[nt] = __builtin_amdgcn_mfma_f32_16x16x32_bf16(al, bh, acc[nt], 0, 0, 0);
        }
    }

    // K-reduce: slices 1,2 park partials in LDS; slice 0 accumulates.
    if (ks > 0) {
#pragma unroll
        for (int nt = 0; nt < 3; ++nt)
#pragma unroll
            for (int r = 0; r < 4; ++r)
                red[ks - 1][mt][q4 * 4 + r][nt * 16 + r16] = acc[nt][r];
    }
    __syncthreads();
    if (ks == 0) {
#pragma unroll
        for (int nt = 0; nt < 3; ++nt)
#pragma unroll
            for (int r = 0; r < 4; ++r)
                acc[nt][r] += red[0][mt][q4 * 4 + r][nt * 16 + r16]
                            + red[1][mt][q4 * 4 + r][nt * 16 + r16];

        // epilogue routing. C/D: col=nt*16+r16, row=q4*4+r.
#pragma unroll
        for (int nt = 0; nt < 3; ++nt) {
            int c = nt * 16 + r16;
#pragma unroll
            for (int r = 0; r < 4; ++r) {
                int lr = mt * 16 + q4 * 4 + r;
                int row = row0 + lr;
                float s = acc[nt][r];
                if (c < 12)      dblS[lr * 13 + c] = s;
                else if (c < 28) Bso[(size_t)row * 16 + (c - 12)] = s;
                else if (c < 44) Cso[(size_t)row * 16 + (c - 28)] = s;
            }
        }
    }
    __syncthreads();

    // phase B: delta = softplus(dblS @ dtw^T + dtb). d = tid (384 threads), 32 rows.
    const int d = tid;
    float wr_[12];
#pragma unroll
    for (int j = 0; j < 12; ++j) wr_[j] = dtw[(size_t)d * 12 + j];
    const float bias = dtb[d];
#pragma unroll 4
    for (int r = 0; r < 32; ++r) {
        const float* db = dblS + r * 13;
        float s = bias;
#pragma unroll
        for (int j = 0; j < 12; ++j) s = fmaf(db[j], wr_[j], s);
        float sp = (s > 20.f) ? s : log1pf(__expf(s));
        delta[(size_t)(row0 + r) * 384 + d] = sp;
    }
}

// ---------------- K3a: per-chunk local scan, lane=d, h[16] in registers ----------------
__global__ __launch_bounds__(384) void k3a_scan1(
    const float* __restrict__ delta, const float* __restrict__ u,
    const float* __restrict__ Bsv, const float* __restrict__ A_logs,
    float* __restrict__ hf, float* __restrict__ Ssum)
{
    const int tid = threadIdx.x;
    const int lane = tid & 63;
    const int wv = tid >> 6;
    const int c = blockIdx.x;
    const int b = blockIdx.y;
    const int d = wv * 64 + lane;
    const int t0 = c * CLEN;

    float Ac[16];
    {
#pragma unroll
        for (int q = 0; q < 4; ++q) {
            float4 v = *(const float4*)(A_logs + d * 16 + q * 4);
            Ac[q * 4 + 0] = -__expf(v.x) * LOG2E;
            Ac[q * 4 + 1] = -__expf(v.y) * LOG2E;
            Ac[q * 4 + 2] = -__expf(v.z) * LOG2E;
            Ac[q * 4 + 3] = -__expf(v.w) * LOG2E;
        }
    }

    const float* dp = delta + ((size_t)b * 2048 + t0) * 384 + d;
    const float* up = u     + ((size_t)b * 2048 + t0) * 384 + d;
    const float* Bp = Bsv   + ((size_t)b * 2048 + t0) * 16;

    float h[16];
#pragma unroll
    for (int n = 0; n < 16; ++n) h[n] = 0.f;
    float S = 0.f;

    float dv_n = dp[0], uv_n = up[0];
    float4 B0n = *(const float4*)(Bp + 0);
    float4 B1n = *(const float4*)(Bp + 4);
    float4 B2n = *(const float4*)(Bp + 8);
    float4 B3n = *(const float4*)(Bp + 12);

    for (int s = 0; s < CLEN; ++s) {
        float dv = dv_n, uv = uv_n;
        float4 B0 = B0n, B1 = B1n, B2 = B2n, B3 = B3n;
        if (s + 1 < CLEN) {
            dp += 384; up += 384; Bp += 16;
            dv_n = dp[0]; uv_n = up[0];
            B0n = *(const float4*)(Bp + 0);
            B1n = *(const float4*)(Bp + 4);
            B2n = *(const float4*)(Bp + 8);
            B3n = *(const float4*)(Bp + 12);
        }
        __builtin_amdgcn_sched_barrier(0);
        S += dv;
        float dvu = dv * uv;
        float Br[16] = {B0.x, B0.y, B0.z, B0.w, B1.x, B1.y, B1.z, B1.w,
                        B2.x, B2.y, B2.z, B2.w, B3.x, B3.y, B3.z, B3.w};
#pragma unroll
        for (int n = 0; n < 16; ++n) {
            float a = exp2f(dv * Ac[n]);
            h[n] = fmaf(a, h[n], dvu * Br[n]);
        }
    }

    const size_t ho = (((size_t)b * NCHUNK + c) * 384 + d) * 16;
#pragma unroll
    for (int q = 0; q < 4; ++q)
        *(float4*)(hf + ho + q * 4) = make_float4(h[q*4+0], h[q*4+1], h[q*4+2], h[q*4+3]);
    Ssum[((size_t)b * NCHUNK + c) * 384 + d] = S;
}

// ---------------- K3c: exclusive scan over chunk summaries (in-place hf -> hinit) ----------------
__global__ __launch_bounds__(256) void k3c_combine(
    float* __restrict__ hf, const float* __restrict__ Ssum,
    const float* __restrict__ A_logs)
{
    const int tid = threadIdx.x;
    const int n = tid & 15, dl = tid >> 4;
    const int d = blockIdx.x * 16 + dl;
    const int b = blockIdx.y;
    const float Ac = -__expf(A_logs[d * 16 + n]) * LOG2E;

    float h = 0.f;
    for (int c = 0; c < NCHUNK; ++c) {
        const size_t idx = (((size_t)b * NCHUNK + c) * 384 + d) * 16 + n;
        float hfv = hf[idx];
        float Sv  = Ssum[((size_t)b * NCHUNK + c) * 384 + d];
        hf[idx] = h;
        float P = exp2f(Ac * Sv);
        h = fmaf(P, h, hfv);
    }
}

// ---------------- K3b: rescan with correct h_init, emit y (in-place on delta) ----------------
__global__ __launch_bounds__(384) void k3b_scan2(
    float* __restrict__ dy, const float* __restrict__ u,
    const float* __restrict__ Bsv, const float* __restrict__ Csv,
    const float* __restrict__ A_logs, const float* __restrict__ Ds,
    const float* __restrict__ hf)
{
    const int tid = threadIdx.x;
    const int lane = tid & 63;
    const int wv = tid >> 6;
    const int c = blockIdx.x;
    const int b = blockIdx.y;
    const int d = wv * 64 + lane;
    const int t0 = c * CLEN;

    float Ac[16];
#pragma unroll
    for (int q = 0; q < 4; ++q) {
        float4 v = *(const float4*)(A_logs + d * 16 + q * 4);
        Ac[q * 4 + 0] = -__expf(v.x) * LOG2E;
        Ac[q * 4 + 1] = -__expf(v.y) * LOG2E;
        Ac[q * 4 + 2] = -__expf(v.z) * LOG2E;
        Ac[q * 4 + 3] = -__expf(v.w) * LOG2E;
    }
    const float Dd = Ds[d];

    float h[16];
    {
        const size_t ho = (((size_t)b * NCHUNK + c) * 384 + d) * 16;
#pragma unroll
        for (int q = 0; q < 4; ++q) {
            float4 v = *(const float4*)(hf + ho + q * 4);
            h[q * 4 + 0] = v.x; h[q * 4 + 1] = v.y;
            h[q * 4 + 2] = v.z; h[q * 4 + 3] = v.w;
        }
    }

    float* yp       = dy  + ((size_t)b * 2048 + t0) * 384 + d;
    const float* up = u   + ((size_t)b * 2048 + t0) * 384 + d;
    const float* Bp = Bsv + ((size_t)b * 2048 + t0) * 16;
    const float* Cp = Csv + ((size_t)b * 2048 + t0) * 16;

    float dv_n = yp[0], uv_n = up[0];
    float4 B0n = *(const float4*)(Bp + 0);
    float4 B1n = *(const float4*)(Bp + 4);
    float4 B2n = *(const float4*)(Bp + 8);
    float4 B3n = *(const float4*)(Bp + 12);
    float4 C0n = *(const float4*)(Cp + 0);
    float4 C1n = *(const float4*)(Cp + 4);
    float4 C2n = *(const float4*)(Cp + 8);
    float4 C3n = *(const float4*)(Cp + 12);
    const float* dpn = yp + 384;

    for (int s = 0; s < CLEN; ++s) {
        float dv = dv_n, uv = uv_n;
        float4 B0 = B0n, B1 = B1n, B2 = B2n, B3 = B3n;
        float4 C0 = C0n, C1 = C1n, C2 = C2n, C3 = C3n;
        if (s + 1 < CLEN) {
            up += 384; Bp += 16; Cp += 16;
            dv_n = dpn[0]; uv_n = up[0];
            B0n = *(const float4*)(Bp + 0);
            B1n = *(const float4*)(Bp + 4);
            B2n = *(const float4*)(Bp + 8);
            B3n = *(const float4*)(Bp + 12);
            C0n = *(const float4*)(Cp + 0);
            C1n = *(const float4*)(Cp + 4);
            C2n = *(const float4*)(Cp + 8);
            C3n = *(const float4*)(Cp + 12);
            dpn += 384;
        }
        __builtin_amdgcn_sched_barrier(0);
        float dvu = dv * uv;
        float Br[16] = {B0.x, B0.y, B0.z, B0.w, B1.x, B1.y, B1.z, B1.w,
                        B2.x, B2.y, B2.z, B2.w, B3.x, B3.y, B3.z, B3.w};
        float Cr[16] = {C0.x, C0.y, C0.z, C0.w, C1.x, C1.y, C1.z, C1.w,
                        C2.x, C2.y, C2.z, C2.w, C3.x, C3.y, C3.z, C3.w};
        float y = Dd * uv;
#pragma unroll
        for (int n = 0; n < 16; ++n) {
            float a = exp2f(dv * Ac[n]);
            h[n] = fmaf(a, h[n], dvu * Br[n]);
            y = fmaf(Cr[n], h[n], y);
        }
        yp[0] = y;
        yp += 384;
    }
}

// ---------------- K4: LayerNorm over DI, then * z (in place on y) ----------------
__global__ __launch_bounds__(256) void k4_ln_mul(
    float* __restrict__ y, const float* __restrict__ z,
    const float* __restrict__ gamma, const float* __restrict__ beta)
{
    const int tid = threadIdx.x;
    const int lane = tid & 63;
    const int w = tid >> 6;
    const size_t row = (size_t)blockIdx.x * 4 + w;
    float* yr = y + row * 384;
    const float* zr = z + row * 384;
    float v[6];
    float s1 = 0.f, s2 = 0.f;
#pragma unroll
    for (int j = 0; j < 6; ++j) {
        v[j] = yr[lane + j * 64];
        s1 += v[j];
        s2 = fmaf(v[j], v[j], s2);
    }
#pragma unroll
    for (int off = 32; off > 0; off >>= 1) {
        s1 += __shfl_xor(s1, off);
        s2 += __shfl_xor(s2, off);
    }
    float mu = s1 * (1.f / 384.f);
    float var = s2 * (1.f / 384.f) - mu * mu;
    float rs = rsqrtf(var + 1e-5f);
#pragma unroll
    for (int j = 0; j < 6; ++j) {
        int d = lane + j * 64;
        float o = (v[j] - mu) * rs * gamma[d] + beta[d];
        yr[d] = o * zr[d];
    }
}

// ---------------- K5: out = yn @ W_out^T (split-bf16 MFMA) ----------------
// grid = dim3(128, 3)
__global__ __launch_bounds__(256) void k5_gemm_out(
    const float* __restrict__ yn, const float* __restrict__ Wout,
    float* __restrict__ out)
{
    __shared__ short Ah[128 * LDK];
    __shared__ short Al[128 * LDK];
    __shared__ short Bh[64 * LDK];
    __shared__ short Bl[64 * LDK];
    const int tid = threadIdx.x;
    const int lane = tid & 63;
    const int w = tid >> 6;
    const int wr = w >> 1, wc = w & 1;
    const int bm = blockIdx.x * 128;
    const int bn = blockIdx.y * 64;

    f32x4 acc[4][2];
#pragma unroll
    for (int i = 0; i < 4; ++i)
#pragma unroll
        for (int j = 0; j < 2; ++j) acc[i][j] = (f32x4)0.f;

    const int r16 = lane & 15, q4 = lane >> 4;

    for (int k0 = 0; k0 < 384; k0 += 32) {
#pragma unroll
        for (int i = 0; i < 4; ++i) {
            int p = tid + i * 256;
            int r = p >> 3, k4 = (p & 7) * 4;
            float4 av = *(const float4*)(yn + (size_t)(bm + r) * 384 + k0 + k4);
            unsigned short hx = f2bf(av.x), hy = f2bf(av.y), hz = f2bf(av.z), hw = f2bf(av.w);
            unsigned hi0 = (unsigned)hx | ((unsigned)hy << 16);
            unsigned hi1 = (unsigned)hz | ((unsigned)hw << 16);
            unsigned short lx = f2bf(av.x - bf2f(hx)), ly = f2bf(av.y - bf2f(hy));
            unsigned short lz = f2bf(av.z - bf2f(hz)), lw = f2bf(av.w - bf2f(hw));
            unsigned lo0 = (unsigned)lx | ((unsigned)ly << 16);
            unsigned lo1 = (unsigned)lz | ((unsigned)lw << 16);
            int wi = r * (LDK / 2) + (k4 >> 1);
            ((unsigned*)Ah)[wi] = hi0; ((unsigned*)Ah)[wi + 1] = hi1;
            ((unsigned*)Al)[wi] = lo0; ((unsigned*)Al)[wi + 1] = lo1;
        }
#pragma unroll
        for (int i = 0; i < 2; ++i) {
            int p = tid + i * 256;
            int r = p >> 3, k4 = (p & 7) * 4;
            float4 bv = *(const float4*)(Wout + (size_t)(bn + r) * 384 + k0 + k4);
            unsigned short hx = f2bf(bv.x), hy = f2bf(bv.y), hz = f2bf(bv.z), hw = f2bf(bv.w);
            unsigned hi0 = (unsigned)hx | ((unsigned)hy << 16);
            unsigned hi1 = (unsigned)hz | ((unsigned)hw << 16);
            unsigned short lx = f2bf(bv.x - bf2f(hx)), ly = f2bf(bv.y - bf2f(hy));
            unsigned short lz = f2bf(bv.z - bf2f(hz)), lw = f2bf(bv.w - bf2f(hw));
            unsigned lo0 = (unsigned)lx | ((unsigned)ly << 16);
            unsigned lo1 = (unsigned)lz | ((unsigned)lw << 16);
            int wi = r * (LDK / 2) + (k4 >> 1);
            ((unsigned*)Bh)[wi] = hi0; ((unsigned*)Bh)[wi + 1] = hi1;
            ((unsigned*)Bl)[wi] = lo0; ((unsigned*)Bl)[wi + 1] = lo1;
        }
        __syncthreads();

        bf16x8 ah[4], al[4];
#pragma unroll
        for (int mt = 0; mt < 4; ++mt) {
            int off = (wr * 64 + mt * 16 + r16) * LDK + q4 * 8;
            ah[mt] = *(const bf16x8*)(Ah + off);
            al[mt] = *(const bf16x8*)(Al + off);
        }
#pragma unroll
        for (int nt = 0; nt < 2; ++nt) {
            int off = (wc * 32 + nt * 16 + r16) * LDK + q4 * 8;
            bf16x8 bh = *(const bf16x8*)(Bh + off);
            bf16x8 bl = *(const bf16x8*)(Bl + off);
#pragma unroll
            for (int mt = 0; mt < 4; ++mt) {
                acc[mt][nt] = __builtin_amdgcn_mfma_f32_16x16x32_bf16(ah[mt], bh, acc[mt][nt], 0, 0, 0);
                acc[mt][nt] = __builtin_amdgcn_mfma_f32_16x16x32_bf16(ah[mt], bl, acc[mt][nt], 0, 0, 0);
                acc[mt][nt] = __builtin_amdgcn_mfma_f32_16x16x32_bf16(al[mt], bh, acc[mt][nt], 0, 0, 0);
            }
        }
        __syncthreads();
    }

#pragma unroll
    for (int mt = 0; mt < 4; ++mt) {
#pragma unroll
        for (int nt = 0; nt < 2; ++nt) {
            int col = bn + wc * 32 + nt * 16 + r16;
#pragma unroll
            for (int r = 0; r < 4; ++r) {
                int row = bm + wr * 64 + mt * 16 + q4 * 4 + r;
                out[(size_t)row * 192 + col] = acc[mt][nt][r];
            }
        }
    }
}

extern "C" void kernel_launch(void* const* d_in, const int* in_sizes, int n_in,
                              void* d_out, int out_size, void* d_ws, size_t ws_size,
                              hipStream_t stream) {
    const float* x    = (const float*)d_in[0];
    const float* Win  = (const float*)d_in[1];
    const float* xpw  = (const float*)d_in[2];
    const float* dtw  = (const float*)d_in[3];
    const float* dtb  = (const float*)d_in[4];
    const float* Alog = (const float*)d_in[5];
    const float* Dsv  = (const float*)d_in[6];
    const float* lng  = (const float*)d_in[7];
    const float* lnb  = (const float*)d_in[8];
    const float* Wout = (const float*)d_in[9];
    float* out = (float*)d_out;

    const size_t nU  = (size_t)ROWS * 384;
    const size_t nBC = (size_t)ROWS * 16;
    const size_t nHF = (size_t)8 * NCHUNK * 384 * 16;
    const size_t nS  = (size_t)8 * NCHUNK * 384;
    const size_t nXW = (size_t)48 * 384;           // shorts per plane
    const size_t need = (nU * 3 + nBC * 2 + nHF + nS) * sizeof(float) + nXW * 2 * sizeof(short);
    if (ws_size < need) return;   // fail visibly (absmax) instead of faulting

    float* u    = (float*)d_ws;
    float* z    = u + nU;
    float* dl   = z + nU;          // delta -> y -> yn (in place)
    float* Bsv  = dl + nU;
    float* Csv  = Bsv + nBC;
    float* hf   = Csv + nBC;       // hf -> hinit (in place, k3c)
    float* Ssum = hf + nHF;
    short* xpwH = (short*)(Ssum + nS);
    short* xpwL = xpwH + nXW;

    k0_split<<<48, 384, 0, stream>>>(xpw, xpwH, xpwL);
    k1_gemm_silu<<<dim3(128, 6), 256, 0, stream>>>(x, Win, u, z);
    k2_proj<<<512, 384, 0, stream>>>(u, xpwH, xpwL, dtw, dtb, dl, Bsv, Csv);
    k3a_scan1<<<dim3(NCHUNK, 8), 384, 0, stream>>>(dl, u, Bsv, Alog, hf, Ssum);
    k3c_combine<<<dim3(24, 8), 256, 0, stream>>>(hf, Ssum, Alog);
    k3b_scan2<<<dim3(NCHUNK, 8), 384, 0, stream>>>(dl, u, Bsv, Csv, Alog, Dsv, hf);
    k4_ln_mul<<<4096, 256, 0, stream>>>(dl, z, lng, lnb);
    k5_gemm_out<<<dim3(128, 3), 256, 0, stream>>>(dl, Wout, out);
}

// Round 12
// 257.018 us; speedup vs baseline: 2.9495x; 1.0762x over previous
//
#include <hip/hip_runtime.h>
#include <hip/hip_bf16.h>
#include <math.h>

// SS1D (Mamba-like selective scan). GEMMs via split-bf16 MFMA (hi/lo, 3 MFMA).
// Scan: lane=channel packing, 16 states in registers, 128 chunks of 16 steps.
// k3b fuses LayerNorm*z (old k4). B=8, L=2048, DM=192, DI=384, N=16, R=12.

#define ROWS 16384
#define NCHUNK 128
#define CLEN 16

typedef short bf16x8 __attribute__((ext_vector_type(8)));
typedef float f32x4 __attribute__((ext_vector_type(4)));

__device__ __forceinline__ unsigned short f2bf(float f) {
    unsigned u = __float_as_uint(f);
    return (unsigned short)((u + 0x7fffu + ((u >> 16) & 1u)) >> 16);
}
__device__ __forceinline__ float bf2f(unsigned short h) {
    return __uint_as_float(((unsigned)h) << 16);
}
__device__ __forceinline__ void cvt8(float4 a0, float4 a1, bf16x8& hi, bf16x8& lo) {
    float v[8] = {a0.x, a0.y, a0.z, a0.w, a1.x, a1.y, a1.z, a1.w};
#pragma unroll
    for (int j = 0; j < 8; ++j) {
        unsigned short h = f2bf(v[j]);
        hi[j] = (short)h;
        lo[j] = (short)f2bf(v[j] - bf2f(h));
    }
}

#define LOG2E 1.44269504088896f

// ---------------- K0: pre-split xpw (44x384, pad to 48) into bf16 hi/lo planes ----------------
__global__ __launch_bounds__(384) void k0_split(
    const float* __restrict__ xpw, short* __restrict__ xpwH, short* __restrict__ xpwL)
{
    const int c = blockIdx.x, k = threadIdx.x;
    float v = (c < 44) ? xpw[(size_t)c * 384 + k] : 0.f;
    unsigned short h = f2bf(v);
    xpwH[(size_t)c * 384 + k] = (short)h;
    xpwL[(size_t)c * 384 + k] = (short)f2bf(v - bf2f(h));
}

// ---------------- K1: xz = silu(x @ W_in^T) -> u, z (split-bf16 MFMA) ----------------
#define LDK 40
__global__ __launch_bounds__(256) void k1_gemm_silu(
    const float* __restrict__ x, const float* __restrict__ Win,
    float* __restrict__ u, float* __restrict__ z)
{
    __shared__ short Ah[128 * LDK];
    __shared__ short Al[128 * LDK];
    __shared__ short Bh[128 * LDK];
    __shared__ short Bl[128 * LDK];
    const int tid = threadIdx.x;
    const int lane = tid & 63;
    const int w = tid >> 6;
    const int wr = w >> 1, wc = w & 1;
    const int bm = blockIdx.x * 128;
    const int bn = blockIdx.y * 128;

    f32x4 acc[4][4];
#pragma unroll
    for (int i = 0; i < 4; ++i)
#pragma unroll
        for (int j = 0; j < 4; ++j) acc[i][j] = (f32x4)0.f;

    const int r16 = lane & 15, q4 = lane >> 4;

    for (int k0 = 0; k0 < 192; k0 += 32) {
#pragma unroll
        for (int i = 0; i < 4; ++i) {
            int p = tid + i * 256;
            int r = p >> 3, k4 = (p & 7) * 4;
            float4 av = *(const float4*)(x + (size_t)(bm + r) * 192 + k0 + k4);
            unsigned short hx = f2bf(av.x), hy = f2bf(av.y), hz = f2bf(av.z), hw = f2bf(av.w);
            unsigned hi0 = (unsigned)hx | ((unsigned)hy << 16);
            unsigned hi1 = (unsigned)hz | ((unsigned)hw << 16);
            unsigned short lx = f2bf(av.x - bf2f(hx)), ly = f2bf(av.y - bf2f(hy));
            unsigned short lz = f2bf(av.z - bf2f(hz)), lw = f2bf(av.w - bf2f(hw));
            unsigned lo0 = (unsigned)lx | ((unsigned)ly << 16);
            unsigned lo1 = (unsigned)lz | ((unsigned)lw << 16);
            int wi = r * (LDK / 2) + (k4 >> 1);
            ((unsigned*)Ah)[wi] = hi0; ((unsigned*)Ah)[wi + 1] = hi1;
            ((unsigned*)Al)[wi] = lo0; ((unsigned*)Al)[wi + 1] = lo1;

            float4 bv = *(const float4*)(Win + (size_t)(bn + r) * 192 + k0 + k4);
            hx = f2bf(bv.x); hy = f2bf(bv.y); hz = f2bf(bv.z); hw = f2bf(bv.w);
            hi0 = (unsigned)hx | ((unsigned)hy << 16);
            hi1 = (unsigned)hz | ((unsigned)hw << 16);
            lx = f2bf(bv.x - bf2f(hx)); ly = f2bf(bv.y - bf2f(hy));
            lz = f2bf(bv.z - bf2f(hz)); lw = f2bf(bv.w - bf2f(hw));
            lo0 = (unsigned)lx | ((unsigned)ly << 16);
            lo1 = (unsigned)lz | ((unsigned)lw << 16);
            ((unsigned*)Bh)[wi] = hi0; ((unsigned*)Bh)[wi + 1] = hi1;
            ((unsigned*)Bl)[wi] = lo0; ((unsigned*)Bl)[wi + 1] = lo1;
        }
        __syncthreads();

        bf16x8 ah[4], al[4];
#pragma unroll
        for (int mt = 0; mt < 4; ++mt) {
            int off = (wr * 64 + mt * 16 + r16) * LDK + q4 * 8;
            ah[mt] = *(const bf16x8*)(Ah + off);
            al[mt] = *(const bf16x8*)(Al + off);
        }
#pragma unroll
        for (int nt = 0; nt < 4; ++nt) {
            int off = (wc * 64 + nt * 16 + r16) * LDK + q4 * 8;
            bf16x8 bh = *(const bf16x8*)(Bh + off);
            bf16x8 bl = *(const bf16x8*)(Bl + off);
#pragma unroll
            for (int mt = 0; mt < 4; ++mt) {
                acc[mt][nt] = __builtin_amdgcn_mfma_f32_16x16x32_bf16(ah[mt], bh, acc[mt][nt], 0, 0, 0);
                acc[mt][nt] = __builtin_amdgcn_mfma_f32_16x16x32_bf16(ah[mt], bl, acc[mt][nt], 0, 0, 0);
                acc[mt][nt] = __builtin_amdgcn_mfma_f32_16x16x32_bf16(al[mt], bh, acc[mt][nt], 0, 0, 0);
            }
        }
        __syncthreads();
    }

    float* dst = (bn < 384) ? u : z;
    const int col0 = (bn < 384) ? bn : (bn - 384);
#pragma unroll
    for (int mt = 0; mt < 4; ++mt) {
#pragma unroll
        for (int nt = 0; nt < 4; ++nt) {
            int col = col0 + wc * 64 + nt * 16 + r16;
#pragma unroll
            for (int r = 0; r < 4; ++r) {
                int row = bm + wr * 64 + mt * 16 + q4 * 4 + r;
                float s = acc[mt][nt][r];
                dst[(size_t)row * 384 + col] = s / (1.f + __expf(-s));
            }
        }
    }
}

// ------- K2: dbl = u @ xpw^T (44 cols, split-bf16 MFMA, no staging LDS) -------
__global__ __launch_bounds__(384) void k2_proj(
    const float* __restrict__ u, const short* __restrict__ xpwH,
    const short* __restrict__ xpwL,
    const float* __restrict__ dtw, const float* __restrict__ dtb,
    float* __restrict__ delta, float* __restrict__ Bso, float* __restrict__ Cso)
{
    __shared__ float red[2][2][16][49];
    __shared__ float dblS[32 * 13];
    const int tid = threadIdx.x;
    const int lane = tid & 63;
    const int w = tid >> 6;
    const int mt = w & 1, ks = w >> 1;
    const int r16 = lane & 15, q4 = lane >> 4;
    const int row0 = blockIdx.x * 32;
    const int arow = row0 + mt * 16 + r16;

    f32x4 acc[3];
#pragma unroll
    for (int j = 0; j < 3; ++j) acc[j] = (f32x4)0.f;

#pragma unroll
    for (int ck = 0; ck < 4; ++ck) {
        const int kb = ks * 128 + ck * 32 + q4 * 8;
        const float* ap = u + (size_t)arow * 384 + kb;
        float4 a0 = *(const float4*)(ap);
        float4 a1 = *(const float4*)(ap + 4);
        bf16x8 ah, al;
        cvt8(a0, a1, ah, al);
#pragma unroll
        for (int nt = 0; nt < 3; ++nt) {
            const int col = nt * 16 + r16;
            bf16x8 bh = *(const bf16x8*)(xpwH + (size_t)col * 384 + kb);
            bf16x8 bl = *(const bf16x8*)(xpwL + (size_t)col * 384 + kb);
            acc[nt] = __builtin_amdgcn_mfma_f32_16x16x32_bf16(ah, bh, acc[nt], 0, 0, 0);
            acc[nt] = __builtin_amdgcn_mfma_f32_16x16x32_bf16(ah, bl, acc[nt], 0, 0, 0);
            acc[nt] = __builtin_amdgcn_mfma_f32_16x16x32_bf16(al, bh, acc[nt], 0, 0, 0);
        }
    }

    if (ks > 0) {
#pragma unroll
        for (int nt = 0; nt < 3; ++nt)
#pragma unroll
            for (int r = 0; r < 4; ++r)
                red[ks - 1][mt][q4 * 4 + r][nt * 16 + r16] = acc[nt][r];
    }
    __syncthreads();
    if (ks == 0) {
#pragma unroll
        for (int nt = 0; nt < 3; ++nt)
#pragma unroll
            for (int r = 0; r < 4; ++r)
                acc[nt][r] += red[0][mt][q4 * 4 + r][nt * 16 + r16]
                            + red[1][mt][q4 * 4 + r][nt * 16 + r16];

#pragma unroll
        for (int nt = 0; nt < 3; ++nt) {
            int c = nt * 16 + r16;
#pragma unroll
            for (int r = 0; r < 4; ++r) {
                int lr = mt * 16 + q4 * 4 + r;
                int row = row0 + lr;
                float s = acc[nt][r];
                if (c < 12)      dblS[lr * 13 + c] = s;
                else if (c < 28) Bso[(size_t)row * 16 + (c - 12)] = s;
                else if (c < 44) Cso[(size_t)row * 16 + (c - 28)] = s;
            }
        }
    }
    __syncthreads();

    const int d = tid;
    float wr_[12];
#pragma unroll
    for (int j = 0; j < 12; ++j) wr_[j] = dtw[(size_t)d * 12 + j];
    const float bias = dtb[d];
#pragma unroll 4
    for (int r = 0; r < 32; ++r) {
        const float* db = dblS + r * 13;
        float s = bias;
#pragma unroll
        for (int j = 0; j < 12; ++j) s = fmaf(db[j], wr_[j], s);
        float sp = (s > 20.f) ? s : log1pf(__expf(s));
        delta[(size_t)(row0 + r) * 384 + d] = sp;
    }
}

// ---------------- K3a: per-chunk local scan, lane=d, h[16] in registers ----------------
// grid = (NCHUNK, B), block = 384 (6 waves x 64 d).
__global__ __launch_bounds__(384) void k3a_scan1(
    const float* __restrict__ delta, const float* __restrict__ u,
    const float* __restrict__ Bsv, const float* __restrict__ A_logs,
    float* __restrict__ hf, float* __restrict__ Ssum)
{
    const int tid = threadIdx.x;
    const int lane = tid & 63;
    const int wv = tid >> 6;
    const int c = blockIdx.x;
    const int b = blockIdx.y;
    const int d = wv * 64 + lane;
    const int t0 = c * CLEN;

    float Ac[16];
    {
#pragma unroll
        for (int q = 0; q < 4; ++q) {
            float4 v = *(const float4*)(A_logs + d * 16 + q * 4);
            Ac[q * 4 + 0] = -__expf(v.x) * LOG2E;
            Ac[q * 4 + 1] = -__expf(v.y) * LOG2E;
            Ac[q * 4 + 2] = -__expf(v.z) * LOG2E;
            Ac[q * 4 + 3] = -__expf(v.w) * LOG2E;
        }
    }

    const float* dp = delta + ((size_t)b * 2048 + t0) * 384 + d;
    const float* up = u     + ((size_t)b * 2048 + t0) * 384 + d;
    const float* Bp = Bsv   + ((size_t)b * 2048 + t0) * 16;

    float h[16];
#pragma unroll
    for (int n = 0; n < 16; ++n) h[n] = 0.f;
    float S = 0.f;

    float dv_n = dp[0], uv_n = up[0];
    float4 B0n = *(const float4*)(Bp + 0);
    float4 B1n = *(const float4*)(Bp + 4);
    float4 B2n = *(const float4*)(Bp + 8);
    float4 B3n = *(const float4*)(Bp + 12);

    for (int s = 0; s < CLEN; ++s) {
        float dv = dv_n, uv = uv_n;
        float4 B0 = B0n, B1 = B1n, B2 = B2n, B3 = B3n;
        if (s + 1 < CLEN) {
            dp += 384; up += 384; Bp += 16;
            dv_n = dp[0]; uv_n = up[0];
            B0n = *(const float4*)(Bp + 0);
            B1n = *(const float4*)(Bp + 4);
            B2n = *(const float4*)(Bp + 8);
            B3n = *(const float4*)(Bp + 12);
        }
        __builtin_amdgcn_sched_barrier(0);
        S += dv;
        float dvu = dv * uv;
        float Br[16] = {B0.x, B0.y, B0.z, B0.w, B1.x, B1.y, B1.z, B1.w,
                        B2.x, B2.y, B2.z, B2.w, B3.x, B3.y, B3.z, B3.w};
#pragma unroll
        for (int n = 0; n < 16; ++n) {
            float a = exp2f(dv * Ac[n]);
            h[n] = fmaf(a, h[n], dvu * Br[n]);
        }
    }

    const size_t ho = (((size_t)b * NCHUNK + c) * 384 + d) * 16;
#pragma unroll
    for (int q = 0; q < 4; ++q)
        *(float4*)(hf + ho + q * 4) = make_float4(h[q*4+0], h[q*4+1], h[q*4+2], h[q*4+3]);
    Ssum[((size_t)b * NCHUNK + c) * 384 + d] = S;
}

// ---------------- K3c: exclusive scan over chunk summaries (in-place hf -> hinit) ----------------
__global__ __launch_bounds__(256) void k3c_combine(
    float* __restrict__ hf, const float* __restrict__ Ssum,
    const float* __restrict__ A_logs)
{
    const int tid = threadIdx.x;
    const int n = tid & 15, dl = tid >> 4;
    const int d = blockIdx.x * 16 + dl;
    const int b = blockIdx.y;
    const float Ac = -__expf(A_logs[d * 16 + n]) * LOG2E;

    float h = 0.f;
    for (int c = 0; c < NCHUNK; ++c) {
        const size_t idx = (((size_t)b * NCHUNK + c) * 384 + d) * 16 + n;
        float hfv = hf[idx];
        float Sv  = Ssum[((size_t)b * NCHUNK + c) * 384 + d];
        hf[idx] = h;
        float P = exp2f(Ac * Sv);
        h = fmaf(P, h, hfv);
    }
}

// ---------------- K3b: rescan + fused LayerNorm*z. dy: delta in, final yn out ----------------
__global__ __launch_bounds__(384) void k3b_scan2(
    float* __restrict__ dy, const float* __restrict__ u,
    const float* __restrict__ Bsv, const float* __restrict__ Csv,
    const float* __restrict__ A_logs, const float* __restrict__ Ds,
    const float* __restrict__ hf, const float* __restrict__ zbuf,
    const float* __restrict__ gamma, const float* __restrict__ beta)
{
    __shared__ float yS[CLEN * 384];
    const int tid = threadIdx.x;
    const int lane = tid & 63;
    const int wv = tid >> 6;
    const int c = blockIdx.x;
    const int b = blockIdx.y;
    const int d = wv * 64 + lane;
    const int t0 = c * CLEN;

    float Ac[16];
#pragma unroll
    for (int q = 0; q < 4; ++q) {
        float4 v = *(const float4*)(A_logs + d * 16 + q * 4);
        Ac[q * 4 + 0] = -__expf(v.x) * LOG2E;
        Ac[q * 4 + 1] = -__expf(v.y) * LOG2E;
        Ac[q * 4 + 2] = -__expf(v.z) * LOG2E;
        Ac[q * 4 + 3] = -__expf(v.w) * LOG2E;
    }
    const float Dd = Ds[d];

    float h[16];
    {
        const size_t ho = (((size_t)b * NCHUNK + c) * 384 + d) * 16;
#pragma unroll
        for (int q = 0; q < 4; ++q) {
            float4 v = *(const float4*)(hf + ho + q * 4);
            h[q * 4 + 0] = v.x; h[q * 4 + 1] = v.y;
            h[q * 4 + 2] = v.z; h[q * 4 + 3] = v.w;
        }
    }

    const float* dp = dy  + ((size_t)b * 2048 + t0) * 384 + d;
    const float* up = u   + ((size_t)b * 2048 + t0) * 384 + d;
    const float* Bp = Bsv + ((size_t)b * 2048 + t0) * 16;
    const float* Cp = Csv + ((size_t)b * 2048 + t0) * 16;

    float dv_n = dp[0], uv_n = up[0];
    float4 B0n = *(const float4*)(Bp + 0);
    float4 B1n = *(const float4*)(Bp + 4);
    float4 B2n = *(const float4*)(Bp + 8);
    float4 B3n = *(const float4*)(Bp + 12);
    float4 C0n = *(const float4*)(Cp + 0);
    float4 C1n = *(const float4*)(Cp + 4);
    float4 C2n = *(const float4*)(Cp + 8);
    float4 C3n = *(const float4*)(Cp + 12);

    for (int s = 0; s < CLEN; ++s) {
        float dv = dv_n, uv = uv_n;
        float4 B0 = B0n, B1 = B1n, B2 = B2n, B3 = B3n;
        float4 C0 = C0n, C1 = C1n, C2 = C2n, C3 = C3n;
        if (s + 1 < CLEN) {
            dp += 384; up += 384; Bp += 16; Cp += 16;
            dv_n = dp[0]; uv_n = up[0];
            B0n = *(const float4*)(Bp + 0);
            B1n = *(const float4*)(Bp + 4);
            B2n = *(const float4*)(Bp + 8);
            B3n = *(const float4*)(Bp + 12);
            C0n = *(const float4*)(Cp + 0);
            C1n = *(const float4*)(Cp + 4);
            C2n = *(const float4*)(Cp + 8);
            C3n = *(const float4*)(Cp + 12);
        }
        __builtin_amdgcn_sched_barrier(0);
        float dvu = dv * uv;
        float Br[16] = {B0.x, B0.y, B0.z, B0.w, B1.x, B1.y, B1.z, B1.w,
                        B2.x, B2.y, B2.z, B2.w, B3.x, B3.y, B3.z, B3.w};
        float Cr[16] = {C0.x, C0.y, C0.z, C0.w, C1.x, C1.y, C1.z, C1.w,
                        C2.x, C2.y, C2.z, C2.w, C3.x, C3.y, C3.z, C3.w};
        float y = Dd * uv;
#pragma unroll
        for (int n = 0; n < 16; ++n) {
            float a = exp2f(dv * Ac[n]);
            h[n] = fmaf(a, h[n], dvu * Br[n]);
            y = fmaf(Cr[n], h[n], y);
        }
        yS[s * 384 + d] = y;
    }
    __syncthreads();

    // fused LayerNorm over d (384) then * z; rows r = wv, wv+6, ...
    for (int r = wv; r < CLEN; r += 6) {
        const float* ys = yS + r * 384;
        float v[6];
        float s1 = 0.f, s2 = 0.f;
#pragma unroll
        for (int j = 0; j < 6; ++j) {
            v[j] = ys[j * 64 + lane];
            s1 += v[j];
            s2 = fmaf(v[j], v[j], s2);
        }
#pragma unroll
        for (int off = 32; off > 0; off >>= 1) {
            s1 += __shfl_xor(s1, off);
            s2 += __shfl_xor(s2, off);
        }
        float mu = s1 * (1.f / 384.f);
        float var = s2 * (1.f / 384.f) - mu * mu;
        float rs = rsqrtf(var + 1e-5f);
        const size_t row = (size_t)b * 2048 + t0 + r;
        float* yr = dy + row * 384;
        const float* zr = zbuf + row * 384;
#pragma unroll
        for (int j = 0; j < 6; ++j) {
            int dd = j * 64 + lane;
            float o = (v[j] - mu) * rs * gamma[dd] + beta[dd];
            yr[dd] = o * zr[dd];
        }
    }
}

// ---------------- K5: out = yn @ W_out^T (split-bf16 MFMA) ----------------
// grid = dim3(128, 3)
__global__ __launch_bounds__(256) void k5_gemm_out(
    const float* __restrict__ yn, const float* __restrict__ Wout,
    float* __restrict__ out)
{
    __shared__ short Ah[128 * LDK];
    __shared__ short Al[128 * LDK];
    __shared__ short Bh[64 * LDK];
    __shared__ short Bl[64 * LDK];
    const int tid = threadIdx.x;
    const int lane = tid & 63;
    const int w = tid >> 6;
    const int wr = w >> 1, wc = w & 1;
    const int bm = blockIdx.x * 128;
    const int bn = blockIdx.y * 64;

    f32x4 acc[4][2];
#pragma unroll
    for (int i = 0; i < 4; ++i)
#pragma unroll
        for (int j = 0; j < 2; ++j) acc[i][j] = (f32x4)0.f;

    const int r16 = lane & 15, q4 = lane >> 4;

    for (int k0 = 0; k0 < 384; k0 += 32) {
#pragma unroll
        for (int i = 0; i < 4; ++i) {
            int p = tid + i * 256;
            int r = p >> 3, k4 = (p & 7) * 4;
            float4 av = *(const float4*)(yn + (size_t)(bm + r) * 384 + k0 + k4);
            unsigned short hx = f2bf(av.x), hy = f2bf(av.y), hz = f2bf(av.z), hw = f2bf(av.w);
            unsigned hi0 = (unsigned)hx | ((unsigned)hy << 16);
            unsigned hi1 = (unsigned)hz | ((unsigned)hw << 16);
            unsigned short lx = f2bf(av.x - bf2f(hx)), ly = f2bf(av.y - bf2f(hy));
            unsigned short lz = f2bf(av.z - bf2f(hz)), lw = f2bf(av.w - bf2f(hw));
            unsigned lo0 = (unsigned)lx | ((unsigned)ly << 16);
            unsigned lo1 = (unsigned)lz | ((unsigned)lw << 16);
            int wi = r * (LDK / 2) + (k4 >> 1);
            ((unsigned*)Ah)[wi] = hi0; ((unsigned*)Ah)[wi + 1] = hi1;
            ((unsigned*)Al)[wi] = lo0; ((unsigned*)Al)[wi + 1] = lo1;
        }
#pragma unroll
        for (int i = 0; i < 2; ++i) {
            int p = tid + i * 256;
            int r = p >> 3, k4 = (p & 7) * 4;
            float4 bv = *(const float4*)(Wout + (size_t)(bn + r) * 384 + k0 + k4);
            unsigned short hx = f2bf(bv.x), hy = f2bf(bv.y), hz = f2bf(bv.z), hw = f2bf(bv.w);
            unsigned hi0 = (unsigned)hx | ((unsigned)hy << 16);
            unsigned hi1 = (unsigned)hz | ((unsigned)hw << 16);
            unsigned short lx = f2bf(bv.x - bf2f(hx)), ly = f2bf(bv.y - bf2f(hy));
            unsigned short lz = f2bf(bv.z - bf2f(hz)), lw = f2bf(bv.w - bf2f(hw));
            unsigned lo0 = (unsigned)lx | ((unsigned)ly << 16);
            unsigned lo1 = (unsigned)lz | ((unsigned)lw << 16);
            int wi = r * (LDK / 2) + (k4 >> 1);
            ((unsigned*)Bh)[wi] = hi0; ((unsigned*)Bh)[wi + 1] = hi1;
            ((unsigned*)Bl)[wi] = lo0; ((unsigned*)Bl)[wi + 1] = lo1;
        }
        __syncthreads();

        bf16x8 ah[4], al[4];
#pragma unroll
        for (int mt = 0; mt < 4; ++mt) {
            int off = (wr * 64 + mt * 16 + r16) * LDK + q4 * 8;
            ah[mt] = *(const bf16x8*)(Ah + off);
            al[mt] = *(const bf16x8*)(Al + off);
        }
#pragma unroll
        for (int nt = 0; nt < 2; ++nt) {
            int off = (wc * 32 + nt * 16 + r16) * LDK + q4 * 8;
            bf16x8 bh = *(const bf16x8*)(Bh + off);
            bf16x8 bl = *(const bf16x8*)(Bl + off);
#pragma unroll
            for (int mt = 0; mt < 4; ++mt) {
                acc[mt][nt] = __builtin_amdgcn_mfma_f32_16x16x32_bf16(ah[mt], bh, acc[mt][nt], 0, 0, 0);
                acc[mt][nt] = __builtin_amdgcn_mfma_f32_16x16x32_bf16(ah[mt], bl, acc[mt][nt], 0, 0, 0);
                acc[mt][nt] = __builtin_amdgcn_mfma_f32_16x16x32_bf16(al[mt], bh, acc[mt][nt], 0, 0, 0);
            }
        }
        __syncthreads();
    }

#pragma unroll
    for (int mt = 0; mt < 4; ++mt) {
#pragma unroll
        for (int nt = 0; nt < 2; ++nt) {
            int col = bn + wc * 32 + nt * 16 + r16;
#pragma unroll
            for (int r = 0; r < 4; ++r) {
                int row = bm + wr * 64 + mt * 16 + q4 * 4 + r;
                out[(size_t)row * 192 + col] = acc[mt][nt][r];
            }
        }
    }
}

extern "C" void kernel_launch(void* const* d_in, const int* in_sizes, int n_in,
                              void* d_out, int out_size, void* d_ws, size_t ws_size,
                              hipStream_t stream) {
    const float* x    = (const float*)d_in[0];
    const float* Win  = (const float*)d_in[1];
    const float* xpw  = (const float*)d_in[2];
    const float* dtw  = (const float*)d_in[3];
    const float* dtb  = (const float*)d_in[4];
    const float* Alog = (const float*)d_in[5];
    const float* Dsv  = (const float*)d_in[6];
    const float* lng  = (const float*)d_in[7];
    const float* lnb  = (const float*)d_in[8];
    const float* Wout = (const float*)d_in[9];
    float* out = (float*)d_out;

    const size_t nU  = (size_t)ROWS * 384;
    const size_t nBC = (size_t)ROWS * 16;
    const size_t nHF = (size_t)8 * NCHUNK * 384 * 16;
    const size_t nS  = (size_t)8 * NCHUNK * 384;
    const size_t nXW = (size_t)48 * 384;           // shorts per plane
    const size_t need = (nU * 3 + nBC * 2 + nHF + nS) * sizeof(float) + nXW * 2 * sizeof(short);
    if (ws_size < need) return;   // fail visibly (absmax) instead of faulting

    float* u    = (float*)d_ws;
    float* z    = u + nU;
    float* dl   = z + nU;          // delta -> yn (in place)
    float* Bsv  = dl + nU;
    float* Csv  = Bsv + nBC;
    float* hf   = Csv + nBC;       // hf -> hinit (in place, k3c)
    float* Ssum = hf + nHF;
    short* xpwH = (short*)(Ssum + nS);
    short* xpwL = xpwH + nXW;

    k0_split<<<48, 384, 0, stream>>>(xpw, xpwH, xpwL);
    k1_gemm_silu<<<dim3(128, 6), 256, 0, stream>>>(x, Win, u, z);
    k2_proj<<<512, 384, 0, stream>>>(u, xpwH, xpwL, dtw, dtb, dl, Bsv, Csv);
    k3a_scan1<<<dim3(NCHUNK, 8), 384, 0, stream>>>(dl, u, Bsv, Alog, hf, Ssum);
    k3c_combine<<<dim3(24, 8), 256, 0, stream>>>(hf, Ssum, Alog);
    k3b_scan2<<<dim3(NCHUNK, 8), 384, 0, stream>>>(dl, u, Bsv, Csv, Alog, Dsv, hf, z, lng, lnb);
    k5_gemm_out<<<dim3(128, 3), 256, 0, stream>>>(dl, Wout, out);
}